// Round 12
// baseline (2022.248 us; speedup 1.0000x reference)
//
#include <hip/hip_runtime.h>
#include <math.h>

#define FLAG_ACC     1
#define FLAG_RELU    2
#define FLAG_GELU    4
#define FLAG_ABF16   8
#define FLAG_OBF16  16
#define FLAG_RESB16 32

typedef __attribute__((ext_vector_type(8))) short short8;
typedef __attribute__((ext_vector_type(4))) short short4v;
typedef __attribute__((ext_vector_type(4))) float f32x4;

__device__ __forceinline__ short f2bf(float f) {
  unsigned u = __builtin_bit_cast(unsigned, f);
  unsigned r = u + 0x7fffu + ((u >> 16) & 1u);
  return (short)(r >> 16);
}
__device__ __forceinline__ float bf2f(short s) {
  unsigned u = ((unsigned)(unsigned short)s) << 16;
  return __builtin_bit_cast(float, u);
}
__device__ __forceinline__ void load_lds16(const void* g, void* lds) {
  __builtin_amdgcn_global_load_lds(
      (const __attribute__((address_space(1))) void*)g,
      (__attribute__((address_space(3))) void*)lds, 16, 0, 0);
}

// ---------------- generic fp32 tiled GEMM (head + W_vo prep) ----------------
__global__ __launch_bounds__(256) void gemm_f32(
    const float* __restrict__ A, const float* __restrict__ B, float* __restrict__ C,
    int M, int N, int K, int a_shift,
    const float* __restrict__ bias, const float* __restrict__ residual, int flags)
{
  __shared__ float As[16][65];
  __shared__ float Bs[16][64];
  const int tid = threadIdx.x;
  const int tx = tid & 15, ty = tid >> 4;
  const int row0 = blockIdx.y * 64;
  const int col0 = blockIdx.x * 64;
  int kbeg = 0, kend = K;
  if ((int)gridDim.z > 1) {
    int kchunk = ((K + (int)gridDim.z - 1) / (int)gridDim.z + 15) & ~15;
    kbeg = (int)blockIdx.z * kchunk;
    kend = min(K, kbeg + kchunk);
  }
  float acc[4][4] = {};
  const int a_m = tid >> 2;
  const int a_k = (tid & 3) << 2;
  const int b_n = (tid & 15) << 2;
  const int b_k = tid >> 4;
  for (int k0 = kbeg; k0 < kend; k0 += 16) {
    int srow = row0 + a_m + a_shift;
    float4 av = make_float4(0.f, 0.f, 0.f, 0.f);
    if (srow >= 0 && srow < M)
      av = *reinterpret_cast<const float4*>(A + (long long)srow * K + (k0 + a_k));
    As[a_k + 0][a_m] = av.x; As[a_k + 1][a_m] = av.y;
    As[a_k + 2][a_m] = av.z; As[a_k + 3][a_m] = av.w;
    float4 bv = make_float4(0.f, 0.f, 0.f, 0.f);
    int brow = k0 + b_k;
    if (brow < K)
      bv = *reinterpret_cast<const float4*>(B + (long long)brow * N + (col0 + b_n));
    Bs[b_k][b_n + 0] = bv.x; Bs[b_k][b_n + 1] = bv.y;
    Bs[b_k][b_n + 2] = bv.z; Bs[b_k][b_n + 3] = bv.w;
    __syncthreads();
#pragma unroll
    for (int kk = 0; kk < 16; kk++) {
      float ar[4], br[4];
#pragma unroll
      for (int i = 0; i < 4; i++) ar[i] = As[kk][ty * 4 + i];
#pragma unroll
      for (int j = 0; j < 4; j++) br[j] = Bs[kk][tx * 4 + j];
#pragma unroll
      for (int i = 0; i < 4; i++)
#pragma unroll
        for (int j = 0; j < 4; j++)
          acc[i][j] += ar[i] * br[j];
    }
    __syncthreads();
  }
  if ((int)gridDim.z > 1) {
#pragma unroll
    for (int i = 0; i < 4; i++) {
      int r = row0 + ty * 4 + i; if (r >= M) continue;
#pragma unroll
      for (int j = 0; j < 4; j++) {
        int c = col0 + tx * 4 + j; if (c >= N) continue;
        atomicAdd(&C[(long long)r * N + c], acc[i][j]);
      }
    }
    return;
  }
#pragma unroll
  for (int i = 0; i < 4; i++) {
    int r = row0 + ty * 4 + i; if (r >= M) continue;
#pragma unroll
    for (int j = 0; j < 4; j++) {
      int c = col0 + tx * 4 + j; if (c >= N) continue;
      float v = acc[i][j];
      if (bias)     v += bias[c];
      if (residual) v += residual[(long long)r * N + c];
      if (flags & FLAG_ACC)  v += C[(long long)r * N + c];
      if (flags & FLAG_RELU) v = fmaxf(v, 0.f);
      if (flags & FLAG_GELU) v = 0.5f * v * (1.f + erff(v * 0.70710678118654752f));
      C[(long long)r * N + c] = v;
    }
  }
}

// ---------------- bf16 MFMA GEMM: C[M,N] = A[M,K] @ Btb[N,K]^T (B pre-bf16) --------
// residual2: if non-null with RESB16, residual is an h/l bf16 pair.
__global__ __launch_bounds__(256) void gemm_bf16_bt(
    const void* __restrict__ Av, const short* __restrict__ Btb, void* __restrict__ Cv,
    const float* __restrict__ residual, const short* __restrict__ residual2,
    const float* __restrict__ bias,
    int M, int N, int K, int lda, int flags, int tapped)
{
  __shared__ __align__(16) short Asl[4096];
  __shared__ __align__(16) short Bsl[4096];
  const int tid = threadIdx.x;
  const int row0 = blockIdx.x * 128;
  const int col0 = blockIdx.y * 128;
  const int lane = tid & 63;
  const int wave = tid >> 6;
  const int wm = (wave >> 1) * 64;
  const int wn = (wave & 1) * 64;
  const int fm = lane & 15;
  const int k8c = lane >> 4;
  const int mr = tid >> 1;
  const int mkc = (tid & 1) * 2;
  const int msw = (mr >> 1) & 3;
  const bool a_dma = (flags & FLAG_ABF16) && !tapped;

  f32x4 acc[4][4] = {};
  for (int k0 = 0; k0 < K; k0 += 32) {
    __syncthreads();
#pragma unroll
    for (int u = 0; u < 2; u++) {
      int p = (wave + u * 4) * 64 + lane;
      int r = p >> 2;
      int kc = (p & 3) ^ ((r >> 1) & 3);
      load_lds16(Btb + (long long)(col0 + r) * K + k0 + kc * 8,
                 (char*)Bsl + (wave + u * 4) * 1024);
    }
    if (a_dma) {
      const short* Ab = (const short*)Av;
#pragma unroll
      for (int u = 0; u < 2; u++) {
        int p = (wave + u * 4) * 64 + lane;
        int r = p >> 2;
        int kc = (p & 3) ^ ((r >> 1) & 3);
        load_lds16(Ab + (long long)(row0 + r) * lda + k0 + kc * 8,
                   (char*)Asl + (wave + u * 4) * 1024);
      }
    } else {
      int arow = row0 + mr + (tapped ? (k0 >> 8) - 1 : 0);
      int acol = tapped ? (k0 & 255) : k0;
      bool ok = (arow >= 0 && arow < M);
      short8 v0, v1;
      if (flags & FLAG_ABF16) {
        const short* ga = (const short*)Av + (long long)arow * lda + acol + mkc * 8;
        short8 z;
#pragma unroll
        for (int u = 0; u < 8; u++) z[u] = 0;
        v0 = ok ? *(const short8*)(ga) : z;
        v1 = ok ? *(const short8*)(ga + 8) : z;
      } else {
        const float* ga = (const float*)Av + (long long)arow * lda + acol + mkc * 8;
        float4 f0 = make_float4(0.f,0.f,0.f,0.f), f1 = f0, f2 = f0, f3 = f0;
        if (ok) {
          f0 = *(const float4*)(ga);     f1 = *(const float4*)(ga + 4);
          f2 = *(const float4*)(ga + 8); f3 = *(const float4*)(ga + 12);
        }
        v0[0]=f2bf(f0.x); v0[1]=f2bf(f0.y); v0[2]=f2bf(f0.z); v0[3]=f2bf(f0.w);
        v0[4]=f2bf(f1.x); v0[5]=f2bf(f1.y); v0[6]=f2bf(f1.z); v0[7]=f2bf(f1.w);
        v1[0]=f2bf(f2.x); v1[1]=f2bf(f2.y); v1[2]=f2bf(f2.z); v1[3]=f2bf(f2.w);
        v1[4]=f2bf(f3.x); v1[5]=f2bf(f3.y); v1[6]=f2bf(f3.z); v1[7]=f2bf(f3.w);
      }
      *(short8*)&Asl[(mr * 4 + (mkc ^ msw)) * 8] = v0;
      *(short8*)&Asl[(mr * 4 + ((mkc + 1) ^ msw)) * 8] = v1;
    }
    __syncthreads();
    short8 af[4], bf[4];
#pragma unroll
    for (int i = 0; i < 4; i++) {
      int r = wm + i * 16 + fm;
      af[i] = *(short8*)&Asl[(r * 4 + (k8c ^ ((r >> 1) & 3))) * 8];
    }
#pragma unroll
    for (int j = 0; j < 4; j++) {
      int r = wn + j * 16 + fm;
      bf[j] = *(short8*)&Bsl[(r * 4 + (k8c ^ ((r >> 1) & 3))) * 8];
    }
#pragma unroll
    for (int i = 0; i < 4; i++)
#pragma unroll
      for (int j = 0; j < 4; j++)
        acc[i][j] = __builtin_amdgcn_mfma_f32_16x16x32_bf16(af[i], bf[j], acc[i][j], 0, 0, 0);
  }
#pragma unroll
  for (int i = 0; i < 4; i++) {
    const int mbase = row0 + wm + i * 16 + (lane >> 4) * 4;
#pragma unroll
    for (int j = 0; j < 4; j++) {
      const int n = col0 + wn + j * 16 + fm;
      const float bs = bias ? bias[n] : 0.f;
#pragma unroll
      for (int r = 0; r < 4; r++) {
        long long idx = (long long)(mbase + r) * N + n;
        float v = acc[i][j][r] + bs;
        if (residual) {
          if (flags & FLAG_RESB16) {
            v += bf2f(((const short*)residual)[idx]);
            if (residual2) v += bf2f(residual2[idx]);
          } else v += residual[idx];
        }
        if (flags & FLAG_ACC)  v += ((const float*)Cv)[idx];
        if (flags & FLAG_RELU) v = fmaxf(v, 0.f);
        if (flags & FLAG_GELU) v = 0.5f * v * (1.f + erff(v * 0.70710678118654752f));
        if (flags & FLAG_OBF16) ((short*)Cv)[idx] = f2bf(v);
        else                    ((float*)Cv)[idx] = v;
      }
    }
  }
}

// ---------------- q+k fused bf16x3 GEMM, ALL operands pre-split bf16 + DMA ---------
// A = ench/encl [M][256], B = QKT hi/lo [N][K]. Output split-bf16 pairs.
__global__ __launch_bounds__(256) void gemm_qk(
    const short* __restrict__ Ah, const short* __restrict__ Al,
    const short* __restrict__ Bth, const short* __restrict__ Btl,
    short* __restrict__ Ch, short* __restrict__ Cl,
    const float* __restrict__ bias, int M, int N, int K)
{
  __shared__ __align__(16) char smem[32768];
  short* Ahi = (short*)smem;
  short* Alo = (short*)(smem + 8192);
  short* Bhi = (short*)(smem + 16384);
  short* Blo = (short*)(smem + 24576);
  const int tid = threadIdx.x;
  const int row0 = blockIdx.x * 128;
  const int col0 = blockIdx.y * 128;
  const int lane = tid & 63;
  const int wave = tid >> 6;
  const int wm = (wave >> 1) * 64;
  const int wn = (wave & 1) * 64;
  const int fm = lane & 15;
  const int k8c = lane >> 4;

  f32x4 acc[4][4] = {};
  for (int k0 = 0; k0 < K; k0 += 32) {
    __syncthreads();
#pragma unroll
    for (int u = 0; u < 2; u++) {
      int p = (wave + u * 4) * 64 + lane;
      int r = p >> 2;
      int kc = (p & 3) ^ ((r >> 1) & 3);
      long long ao = (long long)(row0 + r) * 256 + k0 + kc * 8;
      long long go = (long long)(col0 + r) * K + k0 + kc * 8;
      int lo = (wave + u * 4) * 1024;
      load_lds16(Ah + ao, (char*)Ahi + lo);
      load_lds16(Al + ao, (char*)Alo + lo);
      load_lds16(Bth + go, (char*)Bhi + lo);
      load_lds16(Btl + go, (char*)Blo + lo);
    }
    __syncthreads();
    short8 ah[4], al[4], bh[4], bl[4];
#pragma unroll
    for (int i = 0; i < 4; i++) {
      int r = wm + i * 16 + fm;
      int p = (r * 4 + (k8c ^ ((r >> 1) & 3))) * 8;
      ah[i] = *(short8*)&Ahi[p];
      al[i] = *(short8*)&Alo[p];
    }
#pragma unroll
    for (int j = 0; j < 4; j++) {
      int r = wn + j * 16 + fm;
      int p = (r * 4 + (k8c ^ ((r >> 1) & 3))) * 8;
      bh[j] = *(short8*)&Bhi[p];
      bl[j] = *(short8*)&Blo[p];
    }
#pragma unroll
    for (int i = 0; i < 4; i++)
#pragma unroll
      for (int j = 0; j < 4; j++) {
        acc[i][j] = __builtin_amdgcn_mfma_f32_16x16x32_bf16(ah[i], bh[j], acc[i][j], 0, 0, 0);
        acc[i][j] = __builtin_amdgcn_mfma_f32_16x16x32_bf16(ah[i], bl[j], acc[i][j], 0, 0, 0);
        acc[i][j] = __builtin_amdgcn_mfma_f32_16x16x32_bf16(al[i], bh[j], acc[i][j], 0, 0, 0);
      }
  }
#pragma unroll
  for (int i = 0; i < 4; i++) {
    const int mbase = row0 + wm + i * 16 + (lane >> 4) * 4;
#pragma unroll
    for (int j = 0; j < 4; j++) {
      const int n = col0 + wn + j * 16 + fm;
      const float bs = bias ? bias[n] : 0.f;
#pragma unroll
      for (int r = 0; r < 4; r++) {
        long long idx = (long long)(mbase + r) * N + n;
        float v = acc[i][j][r] + bs;
        short h = f2bf(v);
        short l = f2bf(v - bf2f(h));
        Ch[idx] = h; Cl[idx] = l;
      }
    }
  }
}

// ------------- circular-correlation mean: 32 KB LDS, two-phase skewed reduction ----
__global__ __launch_bounds__(256) void corr_mfma2(
    const short* __restrict__ qkh, const short* __restrict__ qkl, float* __restrict__ mv)
{
  __shared__ __align__(16) char smem[32768];
  short* Ahi = (short*)smem;
  short* Alo = (short*)(smem + 8192);
  short* Bhi = (short*)(smem + 16384);
  short* Blo = (short*)(smem + 24576);
  float* Sf = (float*)smem;   // 64 x 128 fp32 (one half at a time)

  const int id = blockIdx.x;
  const int b  = (id & 7) + 8 * (id >> 9);
  const int tile = (id >> 3) & 63;
  const int t0 = (tile >> 3) * 128;
  const int s0 = (tile & 7) * 128;
  const int tid = threadIdx.x;
  const int lane = tid & 63;
  const int wave = tid >> 6;
  const int wm = (wave >> 1) * 64;
  const int wn = (wave & 1) * 64;
  const int fm = lane & 15;
  const int k8c = lane >> 4;
  const long long bb = (long long)b * 524288;

  f32x4 acc[4][4] = {};
  for (int k0 = 0; k0 < 256; k0 += 32) {
    __syncthreads();
#pragma unroll
    for (int u = 0; u < 2; u++) {
      int p = (wave + u * 4) * 64 + lane;
      int r = p >> 2;
      int kc = (p & 3) ^ ((r >> 1) & 3);
      long long qo = bb + (long long)(t0 + r) * 512 + k0 + kc * 8;
      long long ko = bb + (long long)(s0 + r) * 512 + 256 + k0 + kc * 8;
      int lo = (wave + u * 4) * 1024;
      load_lds16(qkh + qo, (char*)Ahi + lo);
      load_lds16(qkl + qo, (char*)Alo + lo);
      load_lds16(qkh + ko, (char*)Bhi + lo);
      load_lds16(qkl + ko, (char*)Blo + lo);
    }
    __syncthreads();
    short8 ah[4], al[4], bh[4], bl[4];
#pragma unroll
    for (int i = 0; i < 4; i++) {
      int r = wm + i * 16 + fm;
      int p = (r * 4 + (k8c ^ ((r >> 1) & 3))) * 8;
      ah[i] = *(short8*)&Ahi[p];
      al[i] = *(short8*)&Alo[p];
    }
#pragma unroll
    for (int j = 0; j < 4; j++) {
      int r = wn + j * 16 + fm;
      int p = (r * 4 + (k8c ^ ((r >> 1) & 3))) * 8;
      bh[j] = *(short8*)&Bhi[p];
      bl[j] = *(short8*)&Blo[p];
    }
#pragma unroll
    for (int i = 0; i < 4; i++)
#pragma unroll
      for (int j = 0; j < 4; j++) {
        acc[i][j] = __builtin_amdgcn_mfma_f32_16x16x32_bf16(ah[i], bh[j], acc[i][j], 0, 0, 0);
        acc[i][j] = __builtin_amdgcn_mfma_f32_16x16x32_bf16(ah[i], bl[j], acc[i][j], 0, 0, 0);
        acc[i][j] = __builtin_amdgcn_mfma_f32_16x16x32_bf16(al[i], bh[j], acc[i][j], 0, 0, 0);
      }
  }
  // two-phase skewed diagonal reduction (S rows 0-63, then 64-127)
  const int dd = tid & 127;
  const int mb = (tid >> 7) * 32;
  float s_ge = 0.f, s_lt = 0.f;
#pragma unroll
  for (int ph = 0; ph < 2; ph++) {
    __syncthreads();
    if ((wave >> 1) == ph) {
#pragma unroll
      for (int i = 0; i < 4; i++) {
        const int row = wm + i * 16 + (lane >> 4) * 4;   // global row
#pragma unroll
        for (int j = 0; j < 4; j++) {
          const int col = wn + j * 16 + fm;
#pragma unroll
          for (int r = 0; r < 4; r++)
            Sf[(row + r - ph * 64) * 128 + ((2 * (row + r) - col) & 127)] =
                acc[i][j][r] * (1.f / 256.f);
        }
      }
    }
    __syncthreads();
    for (int mm = 0; mm < 32; mm++) {
      int mloc = mb + mm;
      int m = ph * 64 + mloc;
      float v = Sf[mloc * 128 + ((dd + m) & 127)];
      if (m >= dd) s_ge += v; else s_lt += v;
    }
  }
  atomicAdd(&mv[b * 1024 + ((t0 - s0 + dd) & 1023)], s_ge);
  atomicAdd(&mv[b * 1024 + ((t0 - s0 + dd - 128) & 1023)], s_lt);
}

// ------------- one-shot weight prep -------------
__global__ void prep_weights(
    const float* __restrict__ conv2_w, const float* __restrict__ Wq,
    const float* __restrict__ Wk, const float* __restrict__ Wff1,
    const float* __restrict__ Wff2,
    const float* __restrict__ bq, const float* __restrict__ bk,
    short* __restrict__ CB2Tb, short* __restrict__ QKTH, short* __restrict__ QKTL,
    short* __restrict__ WFF1b, short* __restrict__ WFF2b, float* __restrict__ BQK)
{
  const int total = 196608 + 262144 + 524288 + 524288 + 1024;
  for (int idx = blockIdx.x * 256 + threadIdx.x; idx < total;
       idx += gridDim.x * 256) {
    int t = idx;
    if (t < 196608) {
      int o = t / 768, rem = t % 768, kk = rem >> 8, i = rem & 255;
      CB2Tb[t] = f2bf(conv2_w[(o * 256 + i) * 3 + kk]);
    } else if ((t -= 196608) < 262144) {
      int L = t >> 17, rem = t & 131071, r = rem >> 8, k = rem & 255;
      float val = (r < 256) ? Wq[L * 65536 + k * 256 + r]
                            : Wk[L * 65536 + k * 256 + (r - 256)];
      short h = f2bf(val);
      QKTH[t] = h;
      QKTL[t] = f2bf(val - bf2f(h));
    } else if ((t -= 262144) < 524288) {
      WFF1b[t] = f2bf(Wff1[t]);
    } else if ((t -= 524288) < 524288) {
      WFF2b[t] = f2bf(Wff2[t]);
    } else {
      t -= 524288;
      int L = t >> 9, j = t & 511;
      BQK[t] = (j < 256) ? bq[L * 256 + j] : bk[L * 256 + (j - 256)];
    }
  }
}

// ------------- W_vo finish -------------
__global__ void vo_finish(const float* __restrict__ WVO, const float* __restrict__ Wo,
                          const float* __restrict__ bv, const float* __restrict__ bo,
                          short* __restrict__ WVOTb, float* __restrict__ BVO)
{
  const int total = 131072 + 512;
  for (int idx = blockIdx.x * 256 + threadIdx.x; idx < total;
       idx += gridDim.x * 256) {
    if (idx < 131072) {
      int L = idx >> 16, rem = idx & 65535, n = rem >> 8, k = rem & 255;
      WVOTb[idx] = f2bf(WVO[L * 65536 + k * 256 + n]);
    } else {
      int j = idx - 131072;
      int L = j >> 8, n = j & 255;
      float acc = bo[L * 256 + n];
      for (int k = 0; k < 256; k++)
        acc += bv[L * 256 + k] * Wo[(long long)L * 65536 + k * 256 + n];
      BVO[j] = acc;
    }
  }
}

// ------------- conv1 direct -> bf16 out -------------
__global__ __launch_bounds__(256) void conv1_direct(
    const float* __restrict__ x, const float* __restrict__ w,
    const float* __restrict__ bias, short* __restrict__ out)
{
  __shared__ float xs[66][16];
  const int b = blockIdx.y, lg = blockIdx.x, tid = threadIdx.x;
  const int l0 = lg * 64;
  for (int idx = tid; idx < 1056; idx += 256) {
    int r = idx >> 4, c = idx & 15;
    int l = l0 + r - 1;
    xs[r][c] = (l >= 0 && l < 1024) ? x[((long long)b * 1024 + l) * 16 + c] : 0.f;
  }
  float wr[48];
#pragma unroll
  for (int u = 0; u < 48; u++) wr[u] = w[tid * 48 + u];
  const float bs = bias[tid];
  __syncthreads();
  for (int r = 0; r < 64; r++) {
    float acc = bs;
#pragma unroll
    for (int i = 0; i < 16; i++) {
      acc += xs[r + 0][i] * wr[i * 3 + 0];
      acc += xs[r + 1][i] * wr[i * 3 + 1];
      acc += xs[r + 2][i] * wr[i * 3 + 2];
    }
    out[((long long)b * 1024 + l0 + r) * 256 + tid] = f2bf(fmaxf(acc, 0.f));
  }
}

// ------------- conv2 batch-edge fixup (bf16 src rows) -------------
__global__ void fixup_conv_b(float* __restrict__ h, const short* __restrict__ src,
                             const float* __restrict__ w, const float* __restrict__ bias)
{
  int b = blockIdx.x >> 1;
  int l = (blockIdx.x & 1) ? 1023 : 0;
  int o = threadIdx.x;
  float acc = bias[o];
  for (int kk = 0; kk < 3; kk++) {
    int t = l + kk - 1;
    if (t < 0 || t > 1023) continue;
    const short* srow = src + ((long long)b * 1024 + t) * 256;
    const float* wrow = w + (long long)o * 256 * 3 + kk;
    for (int i = 0; i < 256; i++) acc += bf2f(srow[i]) * wrow[(long long)i * 3];
  }
  h[((long long)b * 1024 + l) * 256 + o] = fmaxf(acc, 0.f);
}

// ------------- LayerNorm fp32 out (head path) -------------
__global__ __launch_bounds__(256) void ln_rows4(
    const float* __restrict__ in, float* __restrict__ out,
    const float* __restrict__ g, const float* __restrict__ b,
    int prerelu, int out_stride, int out_off)
{
  const int row = blockIdx.x * 4 + (threadIdx.x >> 6);
  const int lane = threadIdx.x & 63;
  float4 x = ((const float4*)(in + (long long)row * 256))[lane];
  if (prerelu) {
    x.x = fmaxf(x.x, 0.f); x.y = fmaxf(x.y, 0.f);
    x.z = fmaxf(x.z, 0.f); x.w = fmaxf(x.w, 0.f);
  }
  float s = x.x + x.y + x.z + x.w;
#pragma unroll
  for (int o = 32; o > 0; o >>= 1) s += __shfl_xor(s, o, 64);
  float mean = s * (1.f / 256.f);
  float4 d = make_float4(x.x - mean, x.y - mean, x.z - mean, x.w - mean);
  float s2 = d.x * d.x + d.y * d.y + d.z * d.z + d.w * d.w;
#pragma unroll
  for (int o = 32; o > 0; o >>= 1) s2 += __shfl_xor(s2, o, 64);
  float rsd = rsqrtf(s2 * (1.f / 256.f) + 1e-5f);
  float4 gg = ((const float4*)g)[lane];
  float4 bb = ((const float4*)b)[lane];
  float4 o4 = make_float4(d.x * rsd * gg.x + bb.x, d.y * rsd * gg.y + bb.y,
                          d.z * rsd * gg.z + bb.z, d.w * rsd * gg.w + bb.w);
  ((float4*)(out + (long long)row * out_stride + out_off))[lane] = o4;
}

// ------------- LayerNorm with split-bf16 output (enc producer) -------------
__global__ __launch_bounds__(256) void ln_rows4s(
    const float* __restrict__ in, short* __restrict__ oh, short* __restrict__ ol,
    const float* __restrict__ g, const float* __restrict__ b)
{
  const int row = blockIdx.x * 4 + (threadIdx.x >> 6);
  const int lane = threadIdx.x & 63;
  float4 x = ((const float4*)(in + (long long)row * 256))[lane];
  float s = x.x + x.y + x.z + x.w;
#pragma unroll
  for (int o = 32; o > 0; o >>= 1) s += __shfl_xor(s, o, 64);
  float mean = s * (1.f / 256.f);
  float4 d = make_float4(x.x - mean, x.y - mean, x.z - mean, x.w - mean);
  float s2 = d.x * d.x + d.y * d.y + d.z * d.z + d.w * d.w;
#pragma unroll
  for (int o = 32; o > 0; o >>= 1) s2 += __shfl_xor(s2, o, 64);
  float rsd = rsqrtf(s2 * (1.f / 256.f) + 1e-5f);
  float4 gg = ((const float4*)g)[lane];
  float4 bb = ((const float4*)b)[lane];
  float4 o4 = make_float4(d.x * rsd * gg.x + bb.x, d.y * rsd * gg.y + bb.y,
                          d.z * rsd * gg.z + bb.z, d.w * rsd * gg.w + bb.w);
  short4v h, l;
  h[0] = f2bf(o4.x); l[0] = f2bf(o4.x - bf2f(h[0]));
  h[1] = f2bf(o4.y); l[1] = f2bf(o4.y - bf2f(h[1]));
  h[2] = f2bf(o4.z); l[2] = f2bf(o4.z - bf2f(h[2]));
  h[3] = f2bf(o4.w); l[3] = f2bf(o4.w - bf2f(h[3]));
  ((short4v*)oh)[(long long)row * 64 + lane] = h;
  ((short4v*)ol)[(long long)row * 64 + lane] = l;
}

// ------------- series_decomp fp32 -> split-bf16 enc (+FIN pool row), XCD-clustered -
__global__ void decomp4s(const float* __restrict__ in, short* __restrict__ oh,
                         short* __restrict__ ol, float* __restrict__ fin, int finoff)
{
  const int id = blockIdx.x;
  const int c = id & 7;
  const int s = id >> 3;
  const int b = c + 8 * (s >> 8);
  const int lg = s & 255;
  const int l = lg * 4 + (threadIdx.x >> 6);
  const int c4 = threadIdx.x & 63;
  const float4* base = (const float4*)(in + (long long)b * 262144);
  float4 acc = make_float4(0.f, 0.f, 0.f, 0.f);
#pragma unroll
  for (int j = -12; j <= 12; j++) {
    int t = l + j;
    t = t < 0 ? 0 : (t > 1023 ? 1023 : t);
    float4 x = base[t * 64 + c4];
    acc.x += x.x; acc.y += x.y; acc.z += x.z; acc.w += x.w;
  }
  float4 x0 = base[l * 64 + c4];
  float4 o = make_float4(x0.x - acc.x * (1.f / 25.f), x0.y - acc.y * (1.f / 25.f),
                         x0.z - acc.z * (1.f / 25.f), x0.w - acc.w * (1.f / 25.f));
  short4v h, lo;
  h[0] = f2bf(o.x); lo[0] = f2bf(o.x - bf2f(h[0]));
  h[1] = f2bf(o.y); lo[1] = f2bf(o.y - bf2f(h[1]));
  h[2] = f2bf(o.z); lo[2] = f2bf(o.z - bf2f(h[2]));
  h[3] = f2bf(o.w); lo[3] = f2bf(o.w - bf2f(h[3]));
  ((short4v*)oh)[((long long)b * 1024 + l) * 64 + c4] = h;
  ((short4v*)ol)[((long long)b * 1024 + l) * 64 + c4] = lo;
  if (l == 1023) {
    float* f = fin + (long long)b * 768 + finoff + c4 * 4;
    f[0] = o.x; f[1] = o.y; f[2] = o.z; f[3] = o.w;
  }
}

// ------------- series_decomp bf16->bf16, XCD-clustered -------------
__global__ void decomp4b(const short* __restrict__ in, short* __restrict__ out)
{
  const int id = blockIdx.x;
  const int c = id & 7;
  const int s = id >> 3;
  const int b = c + 8 * (s >> 8);
  const int lg = s & 255;
  const int l = lg * 4 + (threadIdx.x >> 6);
  const int c4 = threadIdx.x & 63;
  const short4v* base = (const short4v*)(in + (long long)b * 262144);
  float4 acc = make_float4(0.f, 0.f, 0.f, 0.f);
#pragma unroll
  for (int j = -12; j <= 12; j++) {
    int t = l + j;
    t = t < 0 ? 0 : (t > 1023 ? 1023 : t);
    short4v x = base[t * 64 + c4];
    acc.x += bf2f(x[0]); acc.y += bf2f(x[1]);
    acc.z += bf2f(x[2]); acc.w += bf2f(x[3]);
  }
  short4v x0 = base[l * 64 + c4];
  short4v o;
  o[0] = f2bf(bf2f(x0[0]) - acc.x * (1.f / 25.f));
  o[1] = f2bf(bf2f(x0[1]) - acc.y * (1.f / 25.f));
  o[2] = f2bf(bf2f(x0[2]) - acc.z * (1.f / 25.f));
  o[3] = f2bf(bf2f(x0[3]) - acc.w * (1.f / 25.f));
  ((short4v*)(out + (long long)b * 262144))[l * 64 + c4] = o;
}

// ------------- top-20 + softmax, one wave per batch -------------
__global__ __launch_bounds__(64) void topk_softmax_wave(
    const float* __restrict__ mv, float* __restrict__ wts, int* __restrict__ dly)
{
  const int b = blockIdx.x, lane = threadIdx.x;
  float v[16];
#pragma unroll
  for (int j = 0; j < 16; j++) v[j] = mv[b * 1024 + lane + 64 * j];
  float selv = 0.f; int seli = 0;
  for (int it = 0; it < 20; it++) {
    float bv = -1e30f; int bi = 0x7fffffff;
#pragma unroll
    for (int j = 0; j < 16; j++) {
      float x = v[j]; int idx = lane + 64 * j;
      if (x > bv || (x == bv && idx < bi)) { bv = x; bi = idx; }
    }
#pragma unroll
    for (int off = 32; off > 0; off >>= 1) {
      float ov = __shfl_xor(bv, off, 64);
      int   oi = __shfl_xor(bi, off, 64);
      if (ov > bv || (ov == bv && oi < bi)) { bv = ov; bi = oi; }
    }
    if (lane == it) { selv = bv; seli = bi; }
    if ((bi & 63) == lane) v[bi >> 6] = -1e30f;
  }
  const float w0 = __shfl(selv, 0, 64);
  float e = (lane < 20) ? __expf(selv - w0) : 0.f;
  float s = e;
#pragma unroll
  for (int off = 32; off > 0; off >>= 1) s += __shfl_xor(s, off, 64);
  if (lane < 20) {
    wts[b * 20 + lane] = e / s;
    dly[b * 20 + lane] = seli;
  }
}

// ------------- delay aggregation on split enc -> bf16 out, XCD-clustered -----------
__global__ void agg4s(const short* __restrict__ eh, const short* __restrict__ el,
                      const float* __restrict__ wts, const int* __restrict__ dly,
                      short* __restrict__ out)
{
  const int id = blockIdx.x;
  const int c = id & 7;
  const int s = id >> 3;
  const int b = c + 8 * (s >> 8);
  const int lg = s & 255;
  const int l = lg * 4 + (threadIdx.x >> 6);
  const int c4 = threadIdx.x & 63;
  const short4v* vh = (const short4v*)(eh + (long long)b * 262144);
  const short4v* vl = (const short4v*)(el + (long long)b * 262144);
  float4 acc = make_float4(0.f, 0.f, 0.f, 0.f);
  for (int kk = 0; kk < 20; kk++) {
    int d = dly[b * 20 + kk];
    float w = wts[b * 20 + kk];
    int p = ((l + d) & 1023) * 64 + c4;
    short4v xh = vh[p], xl = vl[p];
    acc.x += w * (bf2f(xh[0]) + bf2f(xl[0]));
    acc.y += w * (bf2f(xh[1]) + bf2f(xl[1]));
    acc.z += w * (bf2f(xh[2]) + bf2f(xl[2]));
    acc.w += w * (bf2f(xh[3]) + bf2f(xl[3]));
  }
  short4v o;
  o[0] = f2bf(acc.x); o[1] = f2bf(acc.y); o[2] = f2bf(acc.z); o[3] = f2bf(acc.w);
  ((short4v*)(out + (long long)b * 262144))[l * 64 + c4] = o;
}

// ------------- small helpers -------------
__global__ void init_bias(float* __restrict__ C, const float* __restrict__ bias)
{
  C[(long long)blockIdx.x * 256 + threadIdx.x] = bias[threadIdx.x];
}

__global__ void rp2_kernel(const float* __restrict__ x, const float* __restrict__ w,
                           const float* __restrict__ bias, float* __restrict__ out)
{
  __shared__ float red[4];
  int b = blockIdx.x, tid = threadIdx.x;
  float p = x[b * 256 + tid] * w[tid];
#pragma unroll
  for (int o = 32; o > 0; o >>= 1) p += __shfl_down(p, o, 64);
  if ((tid & 63) == 0) red[tid >> 6] = p;
  __syncthreads();
  if (tid == 0) out[b] = red[0] + red[1] + red[2] + red[3] + bias[0];
}

// =========================== host launch ===========================
static inline void gemm(hipStream_t s, const float* A, const float* B, float* C,
                        int M, int N, int K, int shift, const float* bias,
                        const float* res, int flags, int splitz = 1)
{
  dim3 g((N + 63) / 64, (M + 63) / 64, splitz);
  gemm_f32<<<g, dim3(256), 0, s>>>(A, B, C, M, N, K, shift, bias, res, flags);
}

extern "C" void kernel_launch(void* const* d_in, const int* in_sizes, int n_in,
                              void* d_out, int out_size, void* d_ws, size_t ws_size,
                              hipStream_t stream)
{
  const float* x_enc  = (const float*)d_in[0];
  const float* conv1_w= (const float*)d_in[1];
  const float* conv1_b= (const float*)d_in[2];
  const float* conv2_w= (const float*)d_in[3];
  const float* conv2_b= (const float*)d_in[4];
  const float* cnn_g  = (const float*)d_in[5];
  const float* cnn_b  = (const float*)d_in[6];
  const float* proj_w = (const float*)d_in[7];
  const float* proj_b = (const float*)d_in[8];
  const float* pln_g  = (const float*)d_in[9];
  const float* pln_b  = (const float*)d_in[10];
  const float* Wq     = (const float*)d_in[11];
  const float* bq     = (const float*)d_in[12];
  const float* Wk     = (const float*)d_in[13];
  const float* bk     = (const float*)d_in[14];
  const float* Wv     = (const float*)d_in[15];
  const float* bv     = (const float*)d_in[16];
  const float* Wo     = (const float*)d_in[17];
  const float* bo     = (const float*)d_in[18];
  const float* Wff1   = (const float*)d_in[19];
  const float* Wff2   = (const float*)d_in[20];
  const float* rp1_w  = (const float*)d_in[21];
  const float* rp1_b  = (const float*)d_in[22];
  const float* rln_g  = (const float*)d_in[23];
  const float* rln_b  = (const float*)d_in[24];
  const float* rp2_w  = (const float*)d_in[25];
  const float* rp2_b  = (const float*)d_in[26];
  (void)in_sizes; (void)n_in;

  const size_t BLD = 64ull * 1024 * 256;
  size_t need;
  {
    size_t o = 3 * BLD
             + 98304 + 131072 + 131072 + 262144 + 262144
             + 65536 + 512 + 1024
             + 65536 + 1280 + 1280 + 16384 + 49152 + 16384 + 16384;
    need = o * sizeof(float);
  }
  if (ws_size < need) {
    hipMemsetAsync(d_out, 0, (size_t)out_size * sizeof(float), stream);
    return;
  }

  float* ws = (float*)d_ws;
  size_t off = 0;
  auto alloc = [&](size_t n) { float* p = ws + off; off += n; return p; };
  float* BUF0 = alloc(BLD);   // conv1(bf16)/QKH/agg(bf16)/xd(bf16); WVO scratch
  float* BUF1 = alloc(BLD);   // conv2(fp32)/QKL/x(bf16)/ffn out(fp32)
  float* BUF2 = alloc(BLD);   // ench+encl (split bf16) / ffn hidden (bf16)
  short* CB2Tb = (short*)alloc(98304);
  short* QKTH  = (short*)alloc(131072);
  short* QKTL  = (short*)alloc(131072);
  short* WFF1b = (short*)alloc(262144);
  short* WFF2b = (short*)alloc(262144);
  short* WVOTb = (short*)alloc(65536);
  float* BVO  = alloc(512);
  float* BQK  = alloc(1024);
  float* MV   = alloc(65536);
  float* WTS  = alloc(1280);
  int*   DLY  = (int*)alloc(1280);
  float* PE   = alloc(16384);
  float* FIN  = alloc(49152);
  float* O1   = alloc(16384);
  float* O2   = alloc(16384);
  float* WVO  = BUF0;   // scratch, dead before conv1 writes BUF0
  short* ench = (short*)BUF2;
  short* encl = ench + BLD;

  const int M = 65536;
  dim3 blk(256);

  prep_weights<<<1024, blk, 0, stream>>>(conv2_w, Wq, Wk, Wff1, Wff2, bq, bk,
                                         CB2Tb, QKTH, QKTL, WFF1b, WFF2b, BQK);
  for (int i = 0; i < 2; i++)
    gemm(stream, Wv + (size_t)i * 65536, Wo + (size_t)i * 65536,
         WVO + (size_t)i * 65536, 256, 256, 256, 0, nullptr, nullptr, 0);
  vo_finish<<<516, blk, 0, stream>>>(WVO, Wo, bv, bo, WVOTb, BVO);

  // --- CNN frontend ---
  conv1_direct<<<dim3(16, 64), blk, 0, stream>>>(x_enc, conv1_w, conv1_b, (short*)BUF0);
  gemm_bf16_bt<<<dim3(512, 2), blk, 0, stream>>>(
      BUF0, CB2Tb, BUF1, nullptr, nullptr, conv2_b, M, 256, 768, 256,
      FLAG_ABF16 | FLAG_RELU, 1);
  fixup_conv_b<<<128, blk, 0, stream>>>(BUF1, (const short*)BUF0, conv2_w, conv2_b);
  ln_rows4s<<<16384, blk, 0, stream>>>(BUF1, ench, encl, cnn_g, cnn_b);

  // --- encoder layers (enc split-bf16 in BUF2) ---
  for (int i = 0; i < 2; i++) {
    short* QKH = (short*)BUF0;
    short* QKL = (short*)BUF1;
    gemm_qk<<<dim3(512, 4), blk, 0, stream>>>(
        ench, encl, QKTH + (size_t)i * 131072, QKTL + (size_t)i * 131072,
        QKH, QKL, BQK + i * 512, M, 512, 256);
    hipMemsetAsync(MV, 0, 64 * 1024 * sizeof(float), stream);
    corr_mfma2<<<dim3(4096), blk, 0, stream>>>(QKH, QKL, MV);
    topk_softmax_wave<<<64, dim3(64), 0, stream>>>(MV, WTS, DLY);
    // fused v+o: x = enc + agg(enc) @ W_vo + b_vo  (x stored bf16)
    agg4s<<<dim3(16384), blk, 0, stream>>>(ench, encl, WTS, DLY, (short*)BUF0);
    gemm_bf16_bt<<<dim3(512, 2), blk, 0, stream>>>(
        BUF0, WVOTb + (size_t)i * 65536, BUF1, (const float*)ench, encl,
        BVO + i * 256, M, 256, 256, 256,
        FLAG_ABF16 | FLAG_OBF16 | FLAG_RESB16, 0);
    decomp4b<<<16384, blk, 0, stream>>>((const short*)BUF1, (short*)BUF0); // xd bf16
    // FFN: 2 chunks of 32768 rows; hidden bf16 in BUF2 (enc dead); out fp32 BUF1
    for (int c = 0; c < 2; c++) {
      const short* xd = (const short*)BUF0 + (size_t)c * 32768 * 256;
      gemm_bf16_bt<<<dim3(256, 8), blk, 0, stream>>>(
          xd, WFF1b + (size_t)i * 262144, BUF2, nullptr, nullptr, nullptr,
          32768, 1024, 256, 256, FLAG_ABF16 | FLAG_GELU | FLAG_OBF16, 0);
      gemm_bf16_bt<<<dim3(256, 2), blk, 0, stream>>>(
          BUF2, WFF2b + (size_t)i * 262144, BUF1 + (size_t)c * 32768 * 256,
          (const float*)xd, nullptr, nullptr,
          32768, 256, 1024, 1024, FLAG_ABF16 | FLAG_RESB16, 0);
    }
    decomp4s<<<16384, blk, 0, stream>>>(BUF1, ench, encl, FIN, i * 256);
  }

  // --- head (fp32, exact) ---
  init_bias<<<64, blk, 0, stream>>>(PE, proj_b);
  gemm(stream, x_enc, proj_w, PE, 64, 256, 16384, 0, nullptr, nullptr, 0, 32);
  ln_rows4<<<16, blk, 0, stream>>>(PE, FIN, pln_g, pln_b, 1, 768, 512);
  init_bias<<<64, blk, 0, stream>>>(O1, rp1_b);
  gemm(stream, FIN, rp1_w, O1, 64, 256, 768, 0, nullptr, nullptr, 0, 4);
  ln_rows4<<<16, blk, 0, stream>>>(O1, O2, rln_g, rln_b, 1, 256, 0);
  rp2_kernel<<<64, blk, 0, stream>>>(O2, rp2_w, rp2_b, (float*)d_out);
}

// Round 13
// 1861.481 us; speedup vs baseline: 1.0864x; 1.0864x over previous
//
#include <hip/hip_runtime.h>
#include <math.h>

#define FLAG_ACC     1
#define FLAG_RELU    2
#define FLAG_GELU    4
#define FLAG_ABF16   8
#define FLAG_OBF16  16
#define FLAG_RESB16 32

typedef __attribute__((ext_vector_type(8))) short short8;
typedef __attribute__((ext_vector_type(4))) short short4v;
typedef __attribute__((ext_vector_type(4))) float f32x4;

__device__ __forceinline__ short f2bf(float f) {
  unsigned u = __builtin_bit_cast(unsigned, f);
  unsigned r = u + 0x7fffu + ((u >> 16) & 1u);
  return (short)(r >> 16);
}
__device__ __forceinline__ float bf2f(short s) {
  unsigned u = ((unsigned)(unsigned short)s) << 16;
  return __builtin_bit_cast(float, u);
}
__device__ __forceinline__ void load_lds16(const void* g, void* lds) {
  __builtin_amdgcn_global_load_lds(
      (const __attribute__((address_space(1))) void*)g,
      (__attribute__((address_space(3))) void*)lds, 16, 0, 0);
}

// ---------------- generic fp32 tiled GEMM (head + W_vo prep) ----------------
__global__ __launch_bounds__(256) void gemm_f32(
    const float* __restrict__ A, const float* __restrict__ B, float* __restrict__ C,
    int M, int N, int K, int a_shift,
    const float* __restrict__ bias, const float* __restrict__ residual, int flags)
{
  __shared__ float As[16][65];
  __shared__ float Bs[16][64];
  const int tid = threadIdx.x;
  const int tx = tid & 15, ty = tid >> 4;
  const int row0 = blockIdx.y * 64;
  const int col0 = blockIdx.x * 64;
  int kbeg = 0, kend = K;
  if ((int)gridDim.z > 1) {
    int kchunk = ((K + (int)gridDim.z - 1) / (int)gridDim.z + 15) & ~15;
    kbeg = (int)blockIdx.z * kchunk;
    kend = min(K, kbeg + kchunk);
  }
  float acc[4][4] = {};
  const int a_m = tid >> 2;
  const int a_k = (tid & 3) << 2;
  const int b_n = (tid & 15) << 2;
  const int b_k = tid >> 4;
  for (int k0 = kbeg; k0 < kend; k0 += 16) {
    int srow = row0 + a_m + a_shift;
    float4 av = make_float4(0.f, 0.f, 0.f, 0.f);
    if (srow >= 0 && srow < M)
      av = *reinterpret_cast<const float4*>(A + (long long)srow * K + (k0 + a_k));
    As[a_k + 0][a_m] = av.x; As[a_k + 1][a_m] = av.y;
    As[a_k + 2][a_m] = av.z; As[a_k + 3][a_m] = av.w;
    float4 bv = make_float4(0.f, 0.f, 0.f, 0.f);
    int brow = k0 + b_k;
    if (brow < K)
      bv = *reinterpret_cast<const float4*>(B + (long long)brow * N + (col0 + b_n));
    Bs[b_k][b_n + 0] = bv.x; Bs[b_k][b_n + 1] = bv.y;
    Bs[b_k][b_n + 2] = bv.z; Bs[b_k][b_n + 3] = bv.w;
    __syncthreads();
#pragma unroll
    for (int kk = 0; kk < 16; kk++) {
      float ar[4], br[4];
#pragma unroll
      for (int i = 0; i < 4; i++) ar[i] = As[kk][ty * 4 + i];
#pragma unroll
      for (int j = 0; j < 4; j++) br[j] = Bs[kk][tx * 4 + j];
#pragma unroll
      for (int i = 0; i < 4; i++)
#pragma unroll
        for (int j = 0; j < 4; j++)
          acc[i][j] += ar[i] * br[j];
    }
    __syncthreads();
  }
  if ((int)gridDim.z > 1) {
#pragma unroll
    for (int i = 0; i < 4; i++) {
      int r = row0 + ty * 4 + i; if (r >= M) continue;
#pragma unroll
      for (int j = 0; j < 4; j++) {
        int c = col0 + tx * 4 + j; if (c >= N) continue;
        atomicAdd(&C[(long long)r * N + c], acc[i][j]);
      }
    }
    return;
  }
#pragma unroll
  for (int i = 0; i < 4; i++) {
    int r = row0 + ty * 4 + i; if (r >= M) continue;
#pragma unroll
    for (int j = 0; j < 4; j++) {
      int c = col0 + tx * 4 + j; if (c >= N) continue;
      float v = acc[i][j];
      if (bias)     v += bias[c];
      if (residual) v += residual[(long long)r * N + c];
      if (flags & FLAG_ACC)  v += C[(long long)r * N + c];
      if (flags & FLAG_RELU) v = fmaxf(v, 0.f);
      if (flags & FLAG_GELU) v = 0.5f * v * (1.f + erff(v * 0.70710678118654752f));
      C[(long long)r * N + c] = v;
    }
  }
}

// ---------------- bf16 MFMA GEMM: C[M,N] = A[M,K] @ Btb[N,K]^T (B pre-bf16) --------
// residual2: if non-null with RESB16, residual is an h/l bf16 pair.
__global__ __launch_bounds__(256) void gemm_bf16_bt(
    const void* __restrict__ Av, const short* __restrict__ Btb, void* __restrict__ Cv,
    const float* __restrict__ residual, const short* __restrict__ residual2,
    const float* __restrict__ bias,
    int M, int N, int K, int lda, int flags, int tapped)
{
  __shared__ __align__(16) short Asl[4096];
  __shared__ __align__(16) short Bsl[4096];
  const int tid = threadIdx.x;
  const int row0 = blockIdx.x * 128;
  const int col0 = blockIdx.y * 128;
  const int lane = tid & 63;
  const int wave = tid >> 6;
  const int wm = (wave >> 1) * 64;
  const int wn = (wave & 1) * 64;
  const int fm = lane & 15;
  const int k8c = lane >> 4;
  const int mr = tid >> 1;
  const int mkc = (tid & 1) * 2;
  const int msw = (mr >> 1) & 3;
  const bool a_dma = (flags & FLAG_ABF16) && !tapped;

  f32x4 acc[4][4] = {};
  for (int k0 = 0; k0 < K; k0 += 32) {
    __syncthreads();
#pragma unroll
    for (int u = 0; u < 2; u++) {
      int p = (wave + u * 4) * 64 + lane;
      int r = p >> 2;
      int kc = (p & 3) ^ ((r >> 1) & 3);
      load_lds16(Btb + (long long)(col0 + r) * K + k0 + kc * 8,
                 (char*)Bsl + (wave + u * 4) * 1024);
    }
    if (a_dma) {
      const short* Ab = (const short*)Av;
#pragma unroll
      for (int u = 0; u < 2; u++) {
        int p = (wave + u * 4) * 64 + lane;
        int r = p >> 2;
        int kc = (p & 3) ^ ((r >> 1) & 3);
        load_lds16(Ab + (long long)(row0 + r) * lda + k0 + kc * 8,
                   (char*)Asl + (wave + u * 4) * 1024);
      }
    } else {
      int arow = row0 + mr + (tapped ? (k0 >> 8) - 1 : 0);
      int acol = tapped ? (k0 & 255) : k0;
      bool ok = (arow >= 0 && arow < M);
      short8 v0, v1;
      if (flags & FLAG_ABF16) {
        const short* ga = (const short*)Av + (long long)arow * lda + acol + mkc * 8;
        short8 z;
#pragma unroll
        for (int u = 0; u < 8; u++) z[u] = 0;
        v0 = ok ? *(const short8*)(ga) : z;
        v1 = ok ? *(const short8*)(ga + 8) : z;
      } else {
        const float* ga = (const float*)Av + (long long)arow * lda + acol + mkc * 8;
        float4 f0 = make_float4(0.f,0.f,0.f,0.f), f1 = f0, f2 = f0, f3 = f0;
        if (ok) {
          f0 = *(const float4*)(ga);     f1 = *(const float4*)(ga + 4);
          f2 = *(const float4*)(ga + 8); f3 = *(const float4*)(ga + 12);
        }
        v0[0]=f2bf(f0.x); v0[1]=f2bf(f0.y); v0[2]=f2bf(f0.z); v0[3]=f2bf(f0.w);
        v0[4]=f2bf(f1.x); v0[5]=f2bf(f1.y); v0[6]=f2bf(f1.z); v0[7]=f2bf(f1.w);
        v1[0]=f2bf(f2.x); v1[1]=f2bf(f2.y); v1[2]=f2bf(f2.z); v1[3]=f2bf(f2.w);
        v1[4]=f2bf(f3.x); v1[5]=f2bf(f3.y); v1[6]=f2bf(f3.z); v1[7]=f2bf(f3.w);
      }
      *(short8*)&Asl[(mr * 4 + (mkc ^ msw)) * 8] = v0;
      *(short8*)&Asl[(mr * 4 + ((mkc + 1) ^ msw)) * 8] = v1;
    }
    __syncthreads();
    short8 af[4], bf[4];
#pragma unroll
    for (int i = 0; i < 4; i++) {
      int r = wm + i * 16 + fm;
      af[i] = *(short8*)&Asl[(r * 4 + (k8c ^ ((r >> 1) & 3))) * 8];
    }
#pragma unroll
    for (int j = 0; j < 4; j++) {
      int r = wn + j * 16 + fm;
      bf[j] = *(short8*)&Bsl[(r * 4 + (k8c ^ ((r >> 1) & 3))) * 8];
    }
#pragma unroll
    for (int i = 0; i < 4; i++)
#pragma unroll
      for (int j = 0; j < 4; j++)
        acc[i][j] = __builtin_amdgcn_mfma_f32_16x16x32_bf16(af[i], bf[j], acc[i][j], 0, 0, 0);
  }
#pragma unroll
  for (int i = 0; i < 4; i++) {
    const int mbase = row0 + wm + i * 16 + (lane >> 4) * 4;
#pragma unroll
    for (int j = 0; j < 4; j++) {
      const int n = col0 + wn + j * 16 + fm;
      const float bs = bias ? bias[n] : 0.f;
#pragma unroll
      for (int r = 0; r < 4; r++) {
        long long idx = (long long)(mbase + r) * N + n;
        float v = acc[i][j][r] + bs;
        if (residual) {
          if (flags & FLAG_RESB16) {
            v += bf2f(((const short*)residual)[idx]);
            if (residual2) v += bf2f(residual2[idx]);
          } else v += residual[idx];
        }
        if (flags & FLAG_ACC)  v += ((const float*)Cv)[idx];
        if (flags & FLAG_RELU) v = fmaxf(v, 0.f);
        if (flags & FLAG_GELU) v = 0.5f * v * (1.f + erff(v * 0.70710678118654752f));
        if (flags & FLAG_OBF16) ((short*)Cv)[idx] = f2bf(v);
        else                    ((float*)Cv)[idx] = v;
      }
    }
  }
}

// ---------------- q+k fused bf16x3 GEMM, ALL operands pre-split bf16 + DMA ---------
__global__ __launch_bounds__(256) void gemm_qk(
    const short* __restrict__ Ah, const short* __restrict__ Al,
    const short* __restrict__ Bth, const short* __restrict__ Btl,
    short* __restrict__ Ch, short* __restrict__ Cl,
    const float* __restrict__ bias, int M, int N, int K)
{
  __shared__ __align__(16) char smem[32768];
  short* Ahi = (short*)smem;
  short* Alo = (short*)(smem + 8192);
  short* Bhi = (short*)(smem + 16384);
  short* Blo = (short*)(smem + 24576);
  const int tid = threadIdx.x;
  const int row0 = blockIdx.x * 128;
  const int col0 = blockIdx.y * 128;
  const int lane = tid & 63;
  const int wave = tid >> 6;
  const int wm = (wave >> 1) * 64;
  const int wn = (wave & 1) * 64;
  const int fm = lane & 15;
  const int k8c = lane >> 4;

  f32x4 acc[4][4] = {};
  for (int k0 = 0; k0 < K; k0 += 32) {
    __syncthreads();
#pragma unroll
    for (int u = 0; u < 2; u++) {
      int p = (wave + u * 4) * 64 + lane;
      int r = p >> 2;
      int kc = (p & 3) ^ ((r >> 1) & 3);
      long long ao = (long long)(row0 + r) * 256 + k0 + kc * 8;
      long long go = (long long)(col0 + r) * K + k0 + kc * 8;
      int lo = (wave + u * 4) * 1024;
      load_lds16(Ah + ao, (char*)Ahi + lo);
      load_lds16(Al + ao, (char*)Alo + lo);
      load_lds16(Bth + go, (char*)Bhi + lo);
      load_lds16(Btl + go, (char*)Blo + lo);
    }
    __syncthreads();
    short8 ah[4], al[4], bh[4], bl[4];
#pragma unroll
    for (int i = 0; i < 4; i++) {
      int r = wm + i * 16 + fm;
      int p = (r * 4 + (k8c ^ ((r >> 1) & 3))) * 8;
      ah[i] = *(short8*)&Ahi[p];
      al[i] = *(short8*)&Alo[p];
    }
#pragma unroll
    for (int j = 0; j < 4; j++) {
      int r = wn + j * 16 + fm;
      int p = (r * 4 + (k8c ^ ((r >> 1) & 3))) * 8;
      bh[j] = *(short8*)&Bhi[p];
      bl[j] = *(short8*)&Blo[p];
    }
#pragma unroll
    for (int i = 0; i < 4; i++)
#pragma unroll
      for (int j = 0; j < 4; j++) {
        acc[i][j] = __builtin_amdgcn_mfma_f32_16x16x32_bf16(ah[i], bh[j], acc[i][j], 0, 0, 0);
        acc[i][j] = __builtin_amdgcn_mfma_f32_16x16x32_bf16(ah[i], bl[j], acc[i][j], 0, 0, 0);
        acc[i][j] = __builtin_amdgcn_mfma_f32_16x16x32_bf16(al[i], bh[j], acc[i][j], 0, 0, 0);
      }
  }
#pragma unroll
  for (int i = 0; i < 4; i++) {
    const int mbase = row0 + wm + i * 16 + (lane >> 4) * 4;
#pragma unroll
    for (int j = 0; j < 4; j++) {
      const int n = col0 + wn + j * 16 + fm;
      const float bs = bias ? bias[n] : 0.f;
#pragma unroll
      for (int r = 0; r < 4; r++) {
        long long idx = (long long)(mbase + r) * N + n;
        float v = acc[i][j][r] + bs;
        short h = f2bf(v);
        short l = f2bf(v - bf2f(h));
        Ch[idx] = h; Cl[idx] = l;
      }
    }
  }
}

// ------------- circular-correlation mean: 64 KB LDS overlay, single-phase skew -----
// (R11 shape: acc dies at the skewed store; VGPR ~92.)
__global__ __launch_bounds__(256) void corr_mfma2(
    const short* __restrict__ qkh, const short* __restrict__ qkl, float* __restrict__ mv)
{
  __shared__ __align__(16) char smem[65536];
  short* Ahi = (short*)smem;
  short* Alo = (short*)(smem + 8192);
  short* Bhi = (short*)(smem + 16384);
  short* Blo = (short*)(smem + 24576);
  float* Sf = (float*)smem;

  const int id = blockIdx.x;
  const int b  = (id & 7) + 8 * (id >> 9);
  const int tile = (id >> 3) & 63;
  const int t0 = (tile >> 3) * 128;
  const int s0 = (tile & 7) * 128;
  const int tid = threadIdx.x;
  const int lane = tid & 63;
  const int wave = tid >> 6;
  const int wm = (wave >> 1) * 64;
  const int wn = (wave & 1) * 64;
  const int fm = lane & 15;
  const int k8c = lane >> 4;
  const long long bb = (long long)b * 524288;

  f32x4 acc[4][4] = {};
  for (int k0 = 0; k0 < 256; k0 += 32) {
    __syncthreads();
#pragma unroll
    for (int u = 0; u < 2; u++) {
      int p = (wave + u * 4) * 64 + lane;
      int r = p >> 2;
      int kc = (p & 3) ^ ((r >> 1) & 3);
      long long qo = bb + (long long)(t0 + r) * 512 + k0 + kc * 8;
      long long ko = bb + (long long)(s0 + r) * 512 + 256 + k0 + kc * 8;
      int lo = (wave + u * 4) * 1024;
      load_lds16(qkh + qo, (char*)Ahi + lo);
      load_lds16(qkl + qo, (char*)Alo + lo);
      load_lds16(qkh + ko, (char*)Bhi + lo);
      load_lds16(qkl + ko, (char*)Blo + lo);
    }
    __syncthreads();
    short8 ah[4], al[4], bh[4], bl[4];
#pragma unroll
    for (int i = 0; i < 4; i++) {
      int r = wm + i * 16 + fm;
      int p = (r * 4 + (k8c ^ ((r >> 1) & 3))) * 8;
      ah[i] = *(short8*)&Ahi[p];
      al[i] = *(short8*)&Alo[p];
    }
#pragma unroll
    for (int j = 0; j < 4; j++) {
      int r = wn + j * 16 + fm;
      int p = (r * 4 + (k8c ^ ((r >> 1) & 3))) * 8;
      bh[j] = *(short8*)&Bhi[p];
      bl[j] = *(short8*)&Blo[p];
    }
#pragma unroll
    for (int i = 0; i < 4; i++)
#pragma unroll
      for (int j = 0; j < 4; j++) {
        acc[i][j] = __builtin_amdgcn_mfma_f32_16x16x32_bf16(ah[i], bh[j], acc[i][j], 0, 0, 0);
        acc[i][j] = __builtin_amdgcn_mfma_f32_16x16x32_bf16(ah[i], bl[j], acc[i][j], 0, 0, 0);
        acc[i][j] = __builtin_amdgcn_mfma_f32_16x16x32_bf16(al[i], bh[j], acc[i][j], 0, 0, 0);
      }
  }
  __syncthreads();   // staging reads done; reuse LDS as skewed S
#pragma unroll
  for (int i = 0; i < 4; i++) {
    const int row = wm + i * 16 + (lane >> 4) * 4;
#pragma unroll
    for (int j = 0; j < 4; j++) {
      const int col = wn + j * 16 + fm;
#pragma unroll
      for (int r = 0; r < 4; r++)
        Sf[(row + r) * 128 + ((2 * (row + r) - col) & 127)] =
            acc[i][j][r] * (1.f / 256.f);
    }
  }
  __syncthreads();
  {
    const int dd = tid & 127;
    const int mb = (tid >> 7) * 64;
    float s_ge = 0.f, s_lt = 0.f;
    for (int mm = 0; mm < 64; mm++) {
      int m = mb + mm;
      float v = Sf[m * 128 + ((dd + m) & 127)];
      if (m >= dd) s_ge += v; else s_lt += v;
    }
    atomicAdd(&mv[b * 1024 + ((t0 - s0 + dd) & 1023)], s_ge);
    atomicAdd(&mv[b * 1024 + ((t0 - s0 + dd - 128) & 1023)], s_lt);
  }
}

// ------------- one-shot weight prep -------------
__global__ void prep_weights(
    const float* __restrict__ conv2_w, const float* __restrict__ Wq,
    const float* __restrict__ Wk, const float* __restrict__ Wff1,
    const float* __restrict__ Wff2,
    const float* __restrict__ bq, const float* __restrict__ bk,
    short* __restrict__ CB2Tb, short* __restrict__ QKTH, short* __restrict__ QKTL,
    short* __restrict__ WFF1b, short* __restrict__ WFF2b, float* __restrict__ BQK)
{
  const int total = 196608 + 262144 + 524288 + 524288 + 1024;
  for (int idx = blockIdx.x * 256 + threadIdx.x; idx < total;
       idx += gridDim.x * 256) {
    int t = idx;
    if (t < 196608) {
      int o = t / 768, rem = t % 768, kk = rem >> 8, i = rem & 255;
      CB2Tb[t] = f2bf(conv2_w[(o * 256 + i) * 3 + kk]);
    } else if ((t -= 196608) < 262144) {
      int L = t >> 17, rem = t & 131071, r = rem >> 8, k = rem & 255;
      float val = (r < 256) ? Wq[L * 65536 + k * 256 + r]
                            : Wk[L * 65536 + k * 256 + (r - 256)];
      short h = f2bf(val);
      QKTH[t] = h;
      QKTL[t] = f2bf(val - bf2f(h));
    } else if ((t -= 262144) < 524288) {
      WFF1b[t] = f2bf(Wff1[t]);
    } else if ((t -= 524288) < 524288) {
      WFF2b[t] = f2bf(Wff2[t]);
    } else {
      t -= 524288;
      int L = t >> 9, j = t & 511;
      BQK[t] = (j < 256) ? bq[L * 256 + j] : bk[L * 256 + (j - 256)];
    }
  }
}

// ------------- W_vo finish -------------
__global__ void vo_finish(const float* __restrict__ WVO, const float* __restrict__ Wo,
                          const float* __restrict__ bv, const float* __restrict__ bo,
                          short* __restrict__ WVOTb, float* __restrict__ BVO)
{
  const int total = 131072 + 512;
  for (int idx = blockIdx.x * 256 + threadIdx.x; idx < total;
       idx += gridDim.x * 256) {
    if (idx < 131072) {
      int L = idx >> 16, rem = idx & 65535, n = rem >> 8, k = rem & 255;
      WVOTb[idx] = f2bf(WVO[L * 65536 + k * 256 + n]);
    } else {
      int j = idx - 131072;
      int L = j >> 8, n = j & 255;
      float acc = bo[L * 256 + n];
      for (int k = 0; k < 256; k++)
        acc += bv[L * 256 + k] * Wo[(long long)L * 65536 + k * 256 + n];
      BVO[j] = acc;
    }
  }
}

// ------------- conv1 direct -> bf16 out -------------
__global__ __launch_bounds__(256) void conv1_direct(
    const float* __restrict__ x, const float* __restrict__ w,
    const float* __restrict__ bias, short* __restrict__ out)
{
  __shared__ float xs[66][16];
  const int b = blockIdx.y, lg = blockIdx.x, tid = threadIdx.x;
  const int l0 = lg * 64;
  for (int idx = tid; idx < 1056; idx += 256) {
    int r = idx >> 4, c = idx & 15;
    int l = l0 + r - 1;
    xs[r][c] = (l >= 0 && l < 1024) ? x[((long long)b * 1024 + l) * 16 + c] : 0.f;
  }
  float wr[48];
#pragma unroll
  for (int u = 0; u < 48; u++) wr[u] = w[tid * 48 + u];
  const float bs = bias[tid];
  __syncthreads();
  for (int r = 0; r < 64; r++) {
    float acc = bs;
#pragma unroll
    for (int i = 0; i < 16; i++) {
      acc += xs[r + 0][i] * wr[i * 3 + 0];
      acc += xs[r + 1][i] * wr[i * 3 + 1];
      acc += xs[r + 2][i] * wr[i * 3 + 2];
    }
    out[((long long)b * 1024 + l0 + r) * 256 + tid] = f2bf(fmaxf(acc, 0.f));
  }
}

// ------------- conv2 batch-edge fixup (bf16 src rows) -------------
__global__ void fixup_conv_b(float* __restrict__ h, const short* __restrict__ src,
                             const float* __restrict__ w, const float* __restrict__ bias)
{
  int b = blockIdx.x >> 1;
  int l = (blockIdx.x & 1) ? 1023 : 0;
  int o = threadIdx.x;
  float acc = bias[o];
  for (int kk = 0; kk < 3; kk++) {
    int t = l + kk - 1;
    if (t < 0 || t > 1023) continue;
    const short* srow = src + ((long long)b * 1024 + t) * 256;
    const float* wrow = w + (long long)o * 256 * 3 + kk;
    for (int i = 0; i < 256; i++) acc += bf2f(srow[i]) * wrow[(long long)i * 3];
  }
  h[((long long)b * 1024 + l) * 256 + o] = fmaxf(acc, 0.f);
}

// ------------- LayerNorm fp32 out (head path) -------------
__global__ __launch_bounds__(256) void ln_rows4(
    const float* __restrict__ in, float* __restrict__ out,
    const float* __restrict__ g, const float* __restrict__ b,
    int prerelu, int out_stride, int out_off)
{
  const int row = blockIdx.x * 4 + (threadIdx.x >> 6);
  const int lane = threadIdx.x & 63;
  float4 x = ((const float4*)(in + (long long)row * 256))[lane];
  if (prerelu) {
    x.x = fmaxf(x.x, 0.f); x.y = fmaxf(x.y, 0.f);
    x.z = fmaxf(x.z, 0.f); x.w = fmaxf(x.w, 0.f);
  }
  float s = x.x + x.y + x.z + x.w;
#pragma unroll
  for (int o = 32; o > 0; o >>= 1) s += __shfl_xor(s, o, 64);
  float mean = s * (1.f / 256.f);
  float4 d = make_float4(x.x - mean, x.y - mean, x.z - mean, x.w - mean);
  float s2 = d.x * d.x + d.y * d.y + d.z * d.z + d.w * d.w;
#pragma unroll
  for (int o = 32; o > 0; o >>= 1) s2 += __shfl_xor(s2, o, 64);
  float rsd = rsqrtf(s2 * (1.f / 256.f) + 1e-5f);
  float4 gg = ((const float4*)g)[lane];
  float4 bb = ((const float4*)b)[lane];
  float4 o4 = make_float4(d.x * rsd * gg.x + bb.x, d.y * rsd * gg.y + bb.y,
                          d.z * rsd * gg.z + bb.z, d.w * rsd * gg.w + bb.w);
  ((float4*)(out + (long long)row * out_stride + out_off))[lane] = o4;
}

// ------------- LayerNorm with split-bf16 output (enc producer) -------------
__global__ __launch_bounds__(256) void ln_rows4s(
    const float* __restrict__ in, short* __restrict__ oh, short* __restrict__ ol,
    const float* __restrict__ g, const float* __restrict__ b)
{
  const int row = blockIdx.x * 4 + (threadIdx.x >> 6);
  const int lane = threadIdx.x & 63;
  float4 x = ((const float4*)(in + (long long)row * 256))[lane];
  float s = x.x + x.y + x.z + x.w;
#pragma unroll
  for (int o = 32; o > 0; o >>= 1) s += __shfl_xor(s, o, 64);
  float mean = s * (1.f / 256.f);
  float4 d = make_float4(x.x - mean, x.y - mean, x.z - mean, x.w - mean);
  float s2 = d.x * d.x + d.y * d.y + d.z * d.z + d.w * d.w;
#pragma unroll
  for (int o = 32; o > 0; o >>= 1) s2 += __shfl_xor(s2, o, 64);
  float rsd = rsqrtf(s2 * (1.f / 256.f) + 1e-5f);
  float4 gg = ((const float4*)g)[lane];
  float4 bb = ((const float4*)b)[lane];
  float4 o4 = make_float4(d.x * rsd * gg.x + bb.x, d.y * rsd * gg.y + bb.y,
                          d.z * rsd * gg.z + bb.z, d.w * rsd * gg.w + bb.w);
  short4v h, l;
  h[0] = f2bf(o4.x); l[0] = f2bf(o4.x - bf2f(h[0]));
  h[1] = f2bf(o4.y); l[1] = f2bf(o4.y - bf2f(h[1]));
  h[2] = f2bf(o4.z); l[2] = f2bf(o4.z - bf2f(h[2]));
  h[3] = f2bf(o4.w); l[3] = f2bf(o4.w - bf2f(h[3]));
  ((short4v*)oh)[(long long)row * 64 + lane] = h;
  ((short4v*)ol)[(long long)row * 64 + lane] = l;
}

// ------------- series_decomp fp32 -> split-bf16 enc (+FIN pool row), XCD-clustered -
__global__ void decomp4s(const float* __restrict__ in, short* __restrict__ oh,
                         short* __restrict__ ol, float* __restrict__ fin, int finoff)
{
  const int id = blockIdx.x;
  const int c = id & 7;
  const int s = id >> 3;
  const int b = c + 8 * (s >> 8);
  const int lg = s & 255;
  const int l = lg * 4 + (threadIdx.x >> 6);
  const int c4 = threadIdx.x & 63;
  const float4* base = (const float4*)(in + (long long)b * 262144);
  float4 acc = make_float4(0.f, 0.f, 0.f, 0.f);
#pragma unroll
  for (int j = -12; j <= 12; j++) {
    int t = l + j;
    t = t < 0 ? 0 : (t > 1023 ? 1023 : t);
    float4 x = base[t * 64 + c4];
    acc.x += x.x; acc.y += x.y; acc.z += x.z; acc.w += x.w;
  }
  float4 x0 = base[l * 64 + c4];
  float4 o = make_float4(x0.x - acc.x * (1.f / 25.f), x0.y - acc.y * (1.f / 25.f),
                         x0.z - acc.z * (1.f / 25.f), x0.w - acc.w * (1.f / 25.f));
  short4v h, lo;
  h[0] = f2bf(o.x); lo[0] = f2bf(o.x - bf2f(h[0]));
  h[1] = f2bf(o.y); lo[1] = f2bf(o.y - bf2f(h[1]));
  h[2] = f2bf(o.z); lo[2] = f2bf(o.z - bf2f(h[2]));
  h[3] = f2bf(o.w); lo[3] = f2bf(o.w - bf2f(h[3]));
  ((short4v*)oh)[((long long)b * 1024 + l) * 64 + c4] = h;
  ((short4v*)ol)[((long long)b * 1024 + l) * 64 + c4] = lo;
  if (l == 1023) {
    float* f = fin + (long long)b * 768 + finoff + c4 * 4;
    f[0] = o.x; f[1] = o.y; f[2] = o.z; f[3] = o.w;
  }
}

// ------------- series_decomp bf16->bf16, XCD-clustered -------------
__global__ void decomp4b(const short* __restrict__ in, short* __restrict__ out)
{
  const int id = blockIdx.x;
  const int c = id & 7;
  const int s = id >> 3;
  const int b = c + 8 * (s >> 8);
  const int lg = s & 255;
  const int l = lg * 4 + (threadIdx.x >> 6);
  const int c4 = threadIdx.x & 63;
  const short4v* base = (const short4v*)(in + (long long)b * 262144);
  float4 acc = make_float4(0.f, 0.f, 0.f, 0.f);
#pragma unroll
  for (int j = -12; j <= 12; j++) {
    int t = l + j;
    t = t < 0 ? 0 : (t > 1023 ? 1023 : t);
    short4v x = base[t * 64 + c4];
    acc.x += bf2f(x[0]); acc.y += bf2f(x[1]);
    acc.z += bf2f(x[2]); acc.w += bf2f(x[3]);
  }
  short4v x0 = base[l * 64 + c4];
  short4v o;
  o[0] = f2bf(bf2f(x0[0]) - acc.x * (1.f / 25.f));
  o[1] = f2bf(bf2f(x0[1]) - acc.y * (1.f / 25.f));
  o[2] = f2bf(bf2f(x0[2]) - acc.z * (1.f / 25.f));
  o[3] = f2bf(bf2f(x0[3]) - acc.w * (1.f / 25.f));
  ((short4v*)(out + (long long)b * 262144))[l * 64 + c4] = o;
}

// ------------- top-20 + softmax, one wave per batch -------------
__global__ __launch_bounds__(64) void topk_softmax_wave(
    const float* __restrict__ mv, float* __restrict__ wts, int* __restrict__ dly)
{
  const int b = blockIdx.x, lane = threadIdx.x;
  float v[16];
#pragma unroll
  for (int j = 0; j < 16; j++) v[j] = mv[b * 1024 + lane + 64 * j];
  float selv = 0.f; int seli = 0;
  for (int it = 0; it < 20; it++) {
    float bv = -1e30f; int bi = 0x7fffffff;
#pragma unroll
    for (int j = 0; j < 16; j++) {
      float x = v[j]; int idx = lane + 64 * j;
      if (x > bv || (x == bv && idx < bi)) { bv = x; bi = idx; }
    }
#pragma unroll
    for (int off = 32; off > 0; off >>= 1) {
      float ov = __shfl_xor(bv, off, 64);
      int   oi = __shfl_xor(bi, off, 64);
      if (ov > bv || (ov == bv && oi < bi)) { bv = ov; bi = oi; }
    }
    if (lane == it) { selv = bv; seli = bi; }
    if ((bi & 63) == lane) v[bi >> 6] = -1e30f;
  }
  const float w0 = __shfl(selv, 0, 64);
  float e = (lane < 20) ? __expf(selv - w0) : 0.f;
  float s = e;
#pragma unroll
  for (int off = 32; off > 0; off >>= 1) s += __shfl_xor(s, off, 64);
  if (lane < 20) {
    wts[b * 20 + lane] = e / s;
    dly[b * 20 + lane] = seli;
  }
}

// ------------- delay aggregation on split enc -> bf16 out, XCD-clustered -----------
__global__ void agg4s(const short* __restrict__ eh, const short* __restrict__ el,
                      const float* __restrict__ wts, const int* __restrict__ dly,
                      short* __restrict__ out)
{
  const int id = blockIdx.x;
  const int c = id & 7;
  const int s = id >> 3;
  const int b = c + 8 * (s >> 8);
  const int lg = s & 255;
  const int l = lg * 4 + (threadIdx.x >> 6);
  const int c4 = threadIdx.x & 63;
  const short4v* vh = (const short4v*)(eh + (long long)b * 262144);
  const short4v* vl = (const short4v*)(el + (long long)b * 262144);
  float4 acc = make_float4(0.f, 0.f, 0.f, 0.f);
  for (int kk = 0; kk < 20; kk++) {
    int d = dly[b * 20 + kk];
    float w = wts[b * 20 + kk];
    int p = ((l + d) & 1023) * 64 + c4;
    short4v xh = vh[p], xl = vl[p];
    acc.x += w * (bf2f(xh[0]) + bf2f(xl[0]));
    acc.y += w * (bf2f(xh[1]) + bf2f(xl[1]));
    acc.z += w * (bf2f(xh[2]) + bf2f(xl[2]));
    acc.w += w * (bf2f(xh[3]) + bf2f(xl[3]));
  }
  short4v o;
  o[0] = f2bf(acc.x); o[1] = f2bf(acc.y); o[2] = f2bf(acc.z); o[3] = f2bf(acc.w);
  ((short4v*)(out + (long long)b * 262144))[l * 64 + c4] = o;
}

// ------------- small helpers -------------
__global__ void init_bias(float* __restrict__ C, const float* __restrict__ bias)
{
  C[(long long)blockIdx.x * 256 + threadIdx.x] = bias[threadIdx.x];
}

__global__ void rp2_kernel(const float* __restrict__ x, const float* __restrict__ w,
                           const float* __restrict__ bias, float* __restrict__ out)
{
  __shared__ float red[4];
  int b = blockIdx.x, tid = threadIdx.x;
  float p = x[b * 256 + tid] * w[tid];
#pragma unroll
  for (int o = 32; o > 0; o >>= 1) p += __shfl_down(p, o, 64);
  if ((tid & 63) == 0) red[tid >> 6] = p;
  __syncthreads();
  if (tid == 0) out[b] = red[0] + red[1] + red[2] + red[3] + bias[0];
}

// =========================== host launch ===========================
static inline void gemm(hipStream_t s, const float* A, const float* B, float* C,
                        int M, int N, int K, int shift, const float* bias,
                        const float* res, int flags, int splitz = 1)
{
  dim3 g((N + 63) / 64, (M + 63) / 64, splitz);
  gemm_f32<<<g, dim3(256), 0, s>>>(A, B, C, M, N, K, shift, bias, res, flags);
}

extern "C" void kernel_launch(void* const* d_in, const int* in_sizes, int n_in,
                              void* d_out, int out_size, void* d_ws, size_t ws_size,
                              hipStream_t stream)
{
  const float* x_enc  = (const float*)d_in[0];
  const float* conv1_w= (const float*)d_in[1];
  const float* conv1_b= (const float*)d_in[2];
  const float* conv2_w= (const float*)d_in[3];
  const float* conv2_b= (const float*)d_in[4];
  const float* cnn_g  = (const float*)d_in[5];
  const float* cnn_b  = (const float*)d_in[6];
  const float* proj_w = (const float*)d_in[7];
  const float* proj_b = (const float*)d_in[8];
  const float* pln_g  = (const float*)d_in[9];
  const float* pln_b  = (const float*)d_in[10];
  const float* Wq     = (const float*)d_in[11];
  const float* bq     = (const float*)d_in[12];
  const float* Wk     = (const float*)d_in[13];
  const float* bk     = (const float*)d_in[14];
  const float* Wv     = (const float*)d_in[15];
  const float* bv     = (const float*)d_in[16];
  const float* Wo     = (const float*)d_in[17];
  const float* bo     = (const float*)d_in[18];
  const float* Wff1   = (const float*)d_in[19];
  const float* Wff2   = (const float*)d_in[20];
  const float* rp1_w  = (const float*)d_in[21];
  const float* rp1_b  = (const float*)d_in[22];
  const float* rln_g  = (const float*)d_in[23];
  const float* rln_b  = (const float*)d_in[24];
  const float* rp2_w  = (const float*)d_in[25];
  const float* rp2_b  = (const float*)d_in[26];
  (void)in_sizes; (void)n_in;

  const size_t BLD = 64ull * 1024 * 256;
  size_t need;
  {
    size_t o = 3 * BLD
             + 98304 + 131072 + 131072 + 262144 + 262144
             + 65536 + 512 + 1024
             + 65536 + 1280 + 1280 + 16384 + 49152 + 16384 + 16384;
    need = o * sizeof(float);
  }
  if (ws_size < need) {
    hipMemsetAsync(d_out, 0, (size_t)out_size * sizeof(float), stream);
    return;
  }

  float* ws = (float*)d_ws;
  size_t off = 0;
  auto alloc = [&](size_t n) { float* p = ws + off; off += n; return p; };
  float* BUF0 = alloc(BLD);   // conv1(bf16)/QKH/agg(bf16)/xd(bf16); WVO scratch
  float* BUF1 = alloc(BLD);   // conv2(fp32)/QKL/x(bf16)/ffn out(fp32)
  float* BUF2 = alloc(BLD);   // ench+encl (split bf16) / ffn hidden (bf16)
  short* CB2Tb = (short*)alloc(98304);
  short* QKTH  = (short*)alloc(131072);
  short* QKTL  = (short*)alloc(131072);
  short* WFF1b = (short*)alloc(262144);
  short* WFF2b = (short*)alloc(262144);
  short* WVOTb = (short*)alloc(65536);
  float* BVO  = alloc(512);
  float* BQK  = alloc(1024);
  float* MV   = alloc(65536);
  float* WTS  = alloc(1280);
  int*   DLY  = (int*)alloc(1280);
  float* PE   = alloc(16384);
  float* FIN  = alloc(49152);
  float* O1   = alloc(16384);
  float* O2   = alloc(16384);
  float* WVO  = BUF0;   // scratch, dead before conv1 writes BUF0
  short* ench = (short*)BUF2;
  short* encl = ench + BLD;

  const int M = 65536;
  dim3 blk(256);

  prep_weights<<<1024, blk, 0, stream>>>(conv2_w, Wq, Wk, Wff1, Wff2, bq, bk,
                                         CB2Tb, QKTH, QKTL, WFF1b, WFF2b, BQK);
  for (int i = 0; i < 2; i++)
    gemm(stream, Wv + (size_t)i * 65536, Wo + (size_t)i * 65536,
         WVO + (size_t)i * 65536, 256, 256, 256, 0, nullptr, nullptr, 0);
  vo_finish<<<516, blk, 0, stream>>>(WVO, Wo, bv, bo, WVOTb, BVO);

  // --- CNN frontend ---
  conv1_direct<<<dim3(16, 64), blk, 0, stream>>>(x_enc, conv1_w, conv1_b, (short*)BUF0);
  gemm_bf16_bt<<<dim3(512, 2), blk, 0, stream>>>(
      BUF0, CB2Tb, BUF1, nullptr, nullptr, conv2_b, M, 256, 768, 256,
      FLAG_ABF16 | FLAG_RELU, 1);
  fixup_conv_b<<<128, blk, 0, stream>>>(BUF1, (const short*)BUF0, conv2_w, conv2_b);
  ln_rows4s<<<16384, blk, 0, stream>>>(BUF1, ench, encl, cnn_g, cnn_b);

  // --- encoder layers (enc split-bf16 in BUF2) ---
  for (int i = 0; i < 2; i++) {
    short* QKH = (short*)BUF0;
    short* QKL = (short*)BUF1;
    gemm_qk<<<dim3(512, 4), blk, 0, stream>>>(
        ench, encl, QKTH + (size_t)i * 131072, QKTL + (size_t)i * 131072,
        QKH, QKL, BQK + i * 512, M, 512, 256);
    hipMemsetAsync(MV, 0, 64 * 1024 * sizeof(float), stream);
    corr_mfma2<<<dim3(4096), blk, 0, stream>>>(QKH, QKL, MV);
    topk_softmax_wave<<<64, dim3(64), 0, stream>>>(MV, WTS, DLY);
    // fused v+o: x = enc + agg(enc) @ W_vo + b_vo  (x stored bf16)
    agg4s<<<dim3(16384), blk, 0, stream>>>(ench, encl, WTS, DLY, (short*)BUF0);
    gemm_bf16_bt<<<dim3(512, 2), blk, 0, stream>>>(
        BUF0, WVOTb + (size_t)i * 65536, BUF1, (const float*)ench, encl,
        BVO + i * 256, M, 256, 256, 256,
        FLAG_ABF16 | FLAG_OBF16 | FLAG_RESB16, 0);
    decomp4b<<<16384, blk, 0, stream>>>((const short*)BUF1, (short*)BUF0); // xd bf16
    // FFN: 2 chunks of 32768 rows; hidden bf16 in BUF2 (enc dead); out fp32 BUF1
    for (int c = 0; c < 2; c++) {
      const short* xd = (const short*)BUF0 + (size_t)c * 32768 * 256;
      gemm_bf16_bt<<<dim3(256, 8), blk, 0, stream>>>(
          xd, WFF1b + (size_t)i * 262144, BUF2, nullptr, nullptr, nullptr,
          32768, 1024, 256, 256, FLAG_ABF16 | FLAG_GELU | FLAG_OBF16, 0);
      gemm_bf16_bt<<<dim3(256, 2), blk, 0, stream>>>(
          BUF2, WFF2b + (size_t)i * 262144, BUF1 + (size_t)c * 32768 * 256,
          (const float*)xd, nullptr, nullptr,
          32768, 256, 1024, 1024, FLAG_ABF16 | FLAG_RESB16, 0);
    }
    decomp4s<<<16384, blk, 0, stream>>>(BUF1, ench, encl, FIN, i * 256);
  }

  // --- head (fp32, exact) ---
  init_bias<<<64, blk, 0, stream>>>(PE, proj_b);
  gemm(stream, x_enc, proj_w, PE, 64, 256, 16384, 0, nullptr, nullptr, 0, 32);
  ln_rows4<<<16, blk, 0, stream>>>(PE, FIN, pln_g, pln_b, 1, 768, 512);
  init_bias<<<64, blk, 0, stream>>>(O1, rp1_b);
  gemm(stream, FIN, rp1_w, O1, 64, 256, 768, 0, nullptr, nullptr, 0, 4);
  ln_rows4<<<16, blk, 0, stream>>>(O1, O2, rln_g, rln_b, 1, 256, 0);
  rp2_kernel<<<64, blk, 0, stream>>>(O2, rp2_w, rp2_b, (float*)d_out);
}

// Round 14
// 1752.942 us; speedup vs baseline: 1.1536x; 1.0619x over previous
//
#include <hip/hip_runtime.h>
#include <math.h>

#define FLAG_ACC     1
#define FLAG_RELU    2
#define FLAG_GELU    4
#define FLAG_ABF16   8
#define FLAG_OBF16  16
#define FLAG_RESB16 32

typedef __attribute__((ext_vector_type(8))) short short8;
typedef __attribute__((ext_vector_type(4))) short short4v;
typedef __attribute__((ext_vector_type(4))) float f32x4;

__device__ __forceinline__ short f2bf(float f) {
  unsigned u = __builtin_bit_cast(unsigned, f);
  unsigned r = u + 0x7fffu + ((u >> 16) & 1u);
  return (short)(r >> 16);
}
__device__ __forceinline__ float bf2f(short s) {
  unsigned u = ((unsigned)(unsigned short)s) << 16;
  return __builtin_bit_cast(float, u);
}
__device__ __forceinline__ void load_lds16(const void* g, void* lds) {
  __builtin_amdgcn_global_load_lds(
      (const __attribute__((address_space(1))) void*)g,
      (__attribute__((address_space(3))) void*)lds, 16, 0, 0);
}

// ---------------- generic fp32 tiled GEMM (head + W_vo prep) ----------------
__global__ __launch_bounds__(256) void gemm_f32(
    const float* __restrict__ A, const float* __restrict__ B, float* __restrict__ C,
    int M, int N, int K, int a_shift,
    const float* __restrict__ bias, const float* __restrict__ residual, int flags)
{
  __shared__ float As[16][65];
  __shared__ float Bs[16][64];
  const int tid = threadIdx.x;
  const int tx = tid & 15, ty = tid >> 4;
  const int row0 = blockIdx.y * 64;
  const int col0 = blockIdx.x * 64;
  int kbeg = 0, kend = K;
  if ((int)gridDim.z > 1) {
    int kchunk = ((K + (int)gridDim.z - 1) / (int)gridDim.z + 15) & ~15;
    kbeg = (int)blockIdx.z * kchunk;
    kend = min(K, kbeg + kchunk);
  }
  float acc[4][4] = {};
  const int a_m = tid >> 2;
  const int a_k = (tid & 3) << 2;
  const int b_n = (tid & 15) << 2;
  const int b_k = tid >> 4;
  for (int k0 = kbeg; k0 < kend; k0 += 16) {
    int srow = row0 + a_m + a_shift;
    float4 av = make_float4(0.f, 0.f, 0.f, 0.f);
    if (srow >= 0 && srow < M)
      av = *reinterpret_cast<const float4*>(A + (long long)srow * K + (k0 + a_k));
    As[a_k + 0][a_m] = av.x; As[a_k + 1][a_m] = av.y;
    As[a_k + 2][a_m] = av.z; As[a_k + 3][a_m] = av.w;
    float4 bv = make_float4(0.f, 0.f, 0.f, 0.f);
    int brow = k0 + b_k;
    if (brow < K)
      bv = *reinterpret_cast<const float4*>(B + (long long)brow * N + (col0 + b_n));
    Bs[b_k][b_n + 0] = bv.x; Bs[b_k][b_n + 1] = bv.y;
    Bs[b_k][b_n + 2] = bv.z; Bs[b_k][b_n + 3] = bv.w;
    __syncthreads();
#pragma unroll
    for (int kk = 0; kk < 16; kk++) {
      float ar[4], br[4];
#pragma unroll
      for (int i = 0; i < 4; i++) ar[i] = As[kk][ty * 4 + i];
#pragma unroll
      for (int j = 0; j < 4; j++) br[j] = Bs[kk][tx * 4 + j];
#pragma unroll
      for (int i = 0; i < 4; i++)
#pragma unroll
        for (int j = 0; j < 4; j++)
          acc[i][j] += ar[i] * br[j];
    }
    __syncthreads();
  }
  if ((int)gridDim.z > 1) {
#pragma unroll
    for (int i = 0; i < 4; i++) {
      int r = row0 + ty * 4 + i; if (r >= M) continue;
#pragma unroll
      for (int j = 0; j < 4; j++) {
        int c = col0 + tx * 4 + j; if (c >= N) continue;
        atomicAdd(&C[(long long)r * N + c], acc[i][j]);
      }
    }
    return;
  }
#pragma unroll
  for (int i = 0; i < 4; i++) {
    int r = row0 + ty * 4 + i; if (r >= M) continue;
#pragma unroll
    for (int j = 0; j < 4; j++) {
      int c = col0 + tx * 4 + j; if (c >= N) continue;
      float v = acc[i][j];
      if (bias)     v += bias[c];
      if (residual) v += residual[(long long)r * N + c];
      if (flags & FLAG_ACC)  v += C[(long long)r * N + c];
      if (flags & FLAG_RELU) v = fmaxf(v, 0.f);
      if (flags & FLAG_GELU) v = 0.5f * v * (1.f + erff(v * 0.70710678118654752f));
      C[(long long)r * N + c] = v;
    }
  }
}

// ---------------- bf16 MFMA GEMM: C[M,N] = A[M,K] @ Btb[N,K]^T (B pre-bf16) --------
__global__ __launch_bounds__(256) void gemm_bf16_bt(
    const void* __restrict__ Av, const short* __restrict__ Btb, void* __restrict__ Cv,
    const float* __restrict__ residual, const float* __restrict__ bias,
    int M, int N, int K, int lda, int flags, int tapped)
{
  __shared__ __align__(16) short Asl[4096];
  __shared__ __align__(16) short Bsl[4096];
  const int tid = threadIdx.x;
  const int row0 = blockIdx.x * 128;
  const int col0 = blockIdx.y * 128;
  const int lane = tid & 63;
  const int wave = tid >> 6;
  const int wm = (wave >> 1) * 64;
  const int wn = (wave & 1) * 64;
  const int fm = lane & 15;
  const int k8c = lane >> 4;
  const int mr = tid >> 1;
  const int mkc = (tid & 1) * 2;
  const int msw = (mr >> 1) & 3;
  const bool a_dma = (flags & FLAG_ABF16) && !tapped;

  f32x4 acc[4][4] = {};
  for (int k0 = 0; k0 < K; k0 += 32) {
    __syncthreads();
#pragma unroll
    for (int u = 0; u < 2; u++) {
      int p = (wave + u * 4) * 64 + lane;
      int r = p >> 2;
      int kc = (p & 3) ^ ((r >> 1) & 3);
      load_lds16(Btb + (long long)(col0 + r) * K + k0 + kc * 8,
                 (char*)Bsl + (wave + u * 4) * 1024);
    }
    if (a_dma) {
      const short* Ab = (const short*)Av;
#pragma unroll
      for (int u = 0; u < 2; u++) {
        int p = (wave + u * 4) * 64 + lane;
        int r = p >> 2;
        int kc = (p & 3) ^ ((r >> 1) & 3);
        load_lds16(Ab + (long long)(row0 + r) * lda + k0 + kc * 8,
                   (char*)Asl + (wave + u * 4) * 1024);
      }
    } else {
      int arow = row0 + mr + (tapped ? (k0 >> 8) - 1 : 0);
      int acol = tapped ? (k0 & 255) : k0;
      bool ok = (arow >= 0 && arow < M);
      short8 v0, v1;
      if (flags & FLAG_ABF16) {
        const short* ga = (const short*)Av + (long long)arow * lda + acol + mkc * 8;
        short8 z;
#pragma unroll
        for (int u = 0; u < 8; u++) z[u] = 0;
        v0 = ok ? *(const short8*)(ga) : z;
        v1 = ok ? *(const short8*)(ga + 8) : z;
      } else {
        const float* ga = (const float*)Av + (long long)arow * lda + acol + mkc * 8;
        float4 f0 = make_float4(0.f,0.f,0.f,0.f), f1 = f0, f2 = f0, f3 = f0;
        if (ok) {
          f0 = *(const float4*)(ga);     f1 = *(const float4*)(ga + 4);
          f2 = *(const float4*)(ga + 8); f3 = *(const float4*)(ga + 12);
        }
        v0[0]=f2bf(f0.x); v0[1]=f2bf(f0.y); v0[2]=f2bf(f0.z); v0[3]=f2bf(f0.w);
        v0[4]=f2bf(f1.x); v0[5]=f2bf(f1.y); v0[6]=f2bf(f1.z); v0[7]=f2bf(f1.w);
        v1[0]=f2bf(f2.x); v1[1]=f2bf(f2.y); v1[2]=f2bf(f2.z); v1[3]=f2bf(f2.w);
        v1[4]=f2bf(f3.x); v1[5]=f2bf(f3.y); v1[6]=f2bf(f3.z); v1[7]=f2bf(f3.w);
      }
      *(short8*)&Asl[(mr * 4 + (mkc ^ msw)) * 8] = v0;
      *(short8*)&Asl[(mr * 4 + ((mkc + 1) ^ msw)) * 8] = v1;
    }
    __syncthreads();
    short8 af[4], bf[4];
#pragma unroll
    for (int i = 0; i < 4; i++) {
      int r = wm + i * 16 + fm;
      af[i] = *(short8*)&Asl[(r * 4 + (k8c ^ ((r >> 1) & 3))) * 8];
    }
#pragma unroll
    for (int j = 0; j < 4; j++) {
      int r = wn + j * 16 + fm;
      bf[j] = *(short8*)&Bsl[(r * 4 + (k8c ^ ((r >> 1) & 3))) * 8];
    }
#pragma unroll
    for (int i = 0; i < 4; i++)
#pragma unroll
      for (int j = 0; j < 4; j++)
        acc[i][j] = __builtin_amdgcn_mfma_f32_16x16x32_bf16(af[i], bf[j], acc[i][j], 0, 0, 0);
  }
#pragma unroll
  for (int i = 0; i < 4; i++) {
    const int mbase = row0 + wm + i * 16 + (lane >> 4) * 4;
#pragma unroll
    for (int j = 0; j < 4; j++) {
      const int n = col0 + wn + j * 16 + fm;
      const float bs = bias ? bias[n] : 0.f;
#pragma unroll
      for (int r = 0; r < 4; r++) {
        long long idx = (long long)(mbase + r) * N + n;
        float v = acc[i][j][r] + bs;
        if (residual) {
          if (flags & FLAG_RESB16) v += bf2f(((const short*)residual)[idx]);
          else                     v += residual[idx];
        }
        if (flags & FLAG_ACC)  v += ((const float*)Cv)[idx];
        if (flags & FLAG_RELU) v = fmaxf(v, 0.f);
        if (flags & FLAG_GELU) v = 0.5f * v * (1.f + erff(v * 0.70710678118654752f));
        if (flags & FLAG_OBF16) ((short*)Cv)[idx] = f2bf(v);
        else                    ((float*)Cv)[idx] = v;
      }
    }
  }
}

// ---------------- q+k fused bf16x3 GEMM, B pre-split+DMA, split-bf16 output --------
__global__ __launch_bounds__(256) void gemm_qk(
    const float* __restrict__ A, const short* __restrict__ Bth,
    const short* __restrict__ Btl,
    short* __restrict__ Ch, short* __restrict__ Cl,
    const float* __restrict__ bias, int M, int N, int K)
{
  __shared__ __align__(16) char smem[32768];
  short* Ahi = (short*)smem;
  short* Alo = (short*)(smem + 8192);
  short* Bhi = (short*)(smem + 16384);
  short* Blo = (short*)(smem + 24576);
  const int tid = threadIdx.x;
  const int row0 = blockIdx.x * 128;
  const int col0 = blockIdx.y * 128;
  const int lane = tid & 63;
  const int wave = tid >> 6;
  const int wm = (wave >> 1) * 64;
  const int wn = (wave & 1) * 64;
  const int fm = lane & 15;
  const int k8c = lane >> 4;
  const int mr = tid >> 1;
  const int mkc = (tid & 1) * 2;
  const int msw = (mr >> 1) & 3;

  f32x4 acc[4][4] = {};
  for (int k0 = 0; k0 < K; k0 += 32) {
    __syncthreads();
#pragma unroll
    for (int u = 0; u < 2; u++) {
      int p = (wave + u * 4) * 64 + lane;
      int r = p >> 2;
      int kc = (p & 3) ^ ((r >> 1) & 3);
      long long go = (long long)(col0 + r) * K + k0 + kc * 8;
      int lo = (wave + u * 4) * 1024;
      load_lds16(Bth + go, (char*)Bhi + lo);
      load_lds16(Btl + go, (char*)Blo + lo);
    }
    {
      const float* ga = A + (long long)(row0 + mr) * K + k0 + mkc * 8;
      float4 f0 = *(const float4*)(ga),     f1 = *(const float4*)(ga + 4);
      float4 f2 = *(const float4*)(ga + 8), f3 = *(const float4*)(ga + 12);
      short8 h0, l0, h1, l1;
      h0[0]=f2bf(f0.x); h0[1]=f2bf(f0.y); h0[2]=f2bf(f0.z); h0[3]=f2bf(f0.w);
      h0[4]=f2bf(f1.x); h0[5]=f2bf(f1.y); h0[6]=f2bf(f1.z); h0[7]=f2bf(f1.w);
      l0[0]=f2bf(f0.x-bf2f(h0[0])); l0[1]=f2bf(f0.y-bf2f(h0[1]));
      l0[2]=f2bf(f0.z-bf2f(h0[2])); l0[3]=f2bf(f0.w-bf2f(h0[3]));
      l0[4]=f2bf(f1.x-bf2f(h0[4])); l0[5]=f2bf(f1.y-bf2f(h0[5]));
      l0[6]=f2bf(f1.z-bf2f(h0[6])); l0[7]=f2bf(f1.w-bf2f(h0[7]));
      h1[0]=f2bf(f2.x); h1[1]=f2bf(f2.y); h1[2]=f2bf(f2.z); h1[3]=f2bf(f2.w);
      h1[4]=f2bf(f3.x); h1[5]=f2bf(f3.y); h1[6]=f2bf(f3.z); h1[7]=f2bf(f3.w);
      l1[0]=f2bf(f2.x-bf2f(h1[0])); l1[1]=f2bf(f2.y-bf2f(h1[1]));
      l1[2]=f2bf(f2.z-bf2f(h1[2])); l1[3]=f2bf(f2.w-bf2f(h1[3]));
      l1[4]=f2bf(f3.x-bf2f(h1[4])); l1[5]=f2bf(f3.y-bf2f(h1[5]));
      l1[6]=f2bf(f3.z-bf2f(h1[6])); l1[7]=f2bf(f3.w-bf2f(h1[7]));
      int p0 = (mr * 4 + (mkc ^ msw)) * 8;
      int p1 = (mr * 4 + ((mkc + 1) ^ msw)) * 8;
      *(short8*)&Ahi[p0] = h0; *(short8*)&Ahi[p1] = h1;
      *(short8*)&Alo[p0] = l0; *(short8*)&Alo[p1] = l1;
    }
    __syncthreads();
    short8 ah[4], al[4], bh[4], bl[4];
#pragma unroll
    for (int i = 0; i < 4; i++) {
      int r = wm + i * 16 + fm;
      int p = (r * 4 + (k8c ^ ((r >> 1) & 3))) * 8;
      ah[i] = *(short8*)&Ahi[p];
      al[i] = *(short8*)&Alo[p];
    }
#pragma unroll
    for (int j = 0; j < 4; j++) {
      int r = wn + j * 16 + fm;
      int p = (r * 4 + (k8c ^ ((r >> 1) & 3))) * 8;
      bh[j] = *(short8*)&Bhi[p];
      bl[j] = *(short8*)&Blo[p];
    }
#pragma unroll
    for (int i = 0; i < 4; i++)
#pragma unroll
      for (int j = 0; j < 4; j++) {
        acc[i][j] = __builtin_amdgcn_mfma_f32_16x16x32_bf16(ah[i], bh[j], acc[i][j], 0, 0, 0);
        acc[i][j] = __builtin_amdgcn_mfma_f32_16x16x32_bf16(ah[i], bl[j], acc[i][j], 0, 0, 0);
        acc[i][j] = __builtin_amdgcn_mfma_f32_16x16x32_bf16(al[i], bh[j], acc[i][j], 0, 0, 0);
      }
  }
#pragma unroll
  for (int i = 0; i < 4; i++) {
    const int mbase = row0 + wm + i * 16 + (lane >> 4) * 4;
#pragma unroll
    for (int j = 0; j < 4; j++) {
      const int n = col0 + wn + j * 16 + fm;
      const float bs = bias ? bias[n] : 0.f;
#pragma unroll
      for (int r = 0; r < 4; r++) {
        long long idx = (long long)(mbase + r) * N + n;
        float v = acc[i][j][r] + bs;
        short h = f2bf(v);
        short l = f2bf(v - bf2f(h));
        Ch[idx] = h; Cl[idx] = l;
      }
    }
  }
}

// ------------- circular-correlation mean: 64 KB LDS overlay, single-phase skew -----
__global__ __launch_bounds__(256) void corr_mfma2(
    const short* __restrict__ qkh, const short* __restrict__ qkl, float* __restrict__ mv)
{
  __shared__ __align__(16) char smem[65536];
  short* Ahi = (short*)smem;
  short* Alo = (short*)(smem + 8192);
  short* Bhi = (short*)(smem + 16384);
  short* Blo = (short*)(smem + 24576);
  float* Sf = (float*)smem;

  const int id = blockIdx.x;
  const int b  = (id & 7) + 8 * (id >> 9);
  const int tile = (id >> 3) & 63;
  const int t0 = (tile >> 3) * 128;
  const int s0 = (tile & 7) * 128;
  const int tid = threadIdx.x;
  const int lane = tid & 63;
  const int wave = tid >> 6;
  const int wm = (wave >> 1) * 64;
  const int wn = (wave & 1) * 64;
  const int fm = lane & 15;
  const int k8c = lane >> 4;
  const long long bb = (long long)b * 524288;

  f32x4 acc[4][4] = {};
  for (int k0 = 0; k0 < 256; k0 += 32) {
    __syncthreads();
#pragma unroll
    for (int u = 0; u < 2; u++) {
      int p = (wave + u * 4) * 64 + lane;
      int r = p >> 2;
      int kc = (p & 3) ^ ((r >> 1) & 3);
      long long qo = bb + (long long)(t0 + r) * 512 + k0 + kc * 8;
      long long ko = bb + (long long)(s0 + r) * 512 + 256 + k0 + kc * 8;
      int lo = (wave + u * 4) * 1024;
      load_lds16(qkh + qo, (char*)Ahi + lo);
      load_lds16(qkl + qo, (char*)Alo + lo);
      load_lds16(qkh + ko, (char*)Bhi + lo);
      load_lds16(qkl + ko, (char*)Blo + lo);
    }
    __syncthreads();
    short8 ah[4], al[4], bh[4], bl[4];
#pragma unroll
    for (int i = 0; i < 4; i++) {
      int r = wm + i * 16 + fm;
      int p = (r * 4 + (k8c ^ ((r >> 1) & 3))) * 8;
      ah[i] = *(short8*)&Ahi[p];
      al[i] = *(short8*)&Alo[p];
    }
#pragma unroll
    for (int j = 0; j < 4; j++) {
      int r = wn + j * 16 + fm;
      int p = (r * 4 + (k8c ^ ((r >> 1) & 3))) * 8;
      bh[j] = *(short8*)&Bhi[p];
      bl[j] = *(short8*)&Blo[p];
    }
#pragma unroll
    for (int i = 0; i < 4; i++)
#pragma unroll
      for (int j = 0; j < 4; j++) {
        acc[i][j] = __builtin_amdgcn_mfma_f32_16x16x32_bf16(ah[i], bh[j], acc[i][j], 0, 0, 0);
        acc[i][j] = __builtin_amdgcn_mfma_f32_16x16x32_bf16(ah[i], bl[j], acc[i][j], 0, 0, 0);
        acc[i][j] = __builtin_amdgcn_mfma_f32_16x16x32_bf16(al[i], bh[j], acc[i][j], 0, 0, 0);
      }
  }
  __syncthreads();   // staging reads done; reuse LDS as skewed S
#pragma unroll
  for (int i = 0; i < 4; i++) {
    const int row = wm + i * 16 + (lane >> 4) * 4;
#pragma unroll
    for (int j = 0; j < 4; j++) {
      const int col = wn + j * 16 + fm;
#pragma unroll
      for (int r = 0; r < 4; r++)
        Sf[(row + r) * 128 + ((2 * (row + r) - col) & 127)] =
            acc[i][j][r] * (1.f / 256.f);
    }
  }
  __syncthreads();
  {
    const int dd = tid & 127;
    const int mb = (tid >> 7) * 64;
    float s_ge = 0.f, s_lt = 0.f;
    for (int mm = 0; mm < 64; mm++) {
      int m = mb + mm;
      float v = Sf[m * 128 + ((dd + m) & 127)];
      if (m >= dd) s_ge += v; else s_lt += v;
    }
    atomicAdd(&mv[b * 1024 + ((t0 - s0 + dd) & 1023)], s_ge);
    atomicAdd(&mv[b * 1024 + ((t0 - s0 + dd - 128) & 1023)], s_lt);
  }
}

// ------------- one-shot weight prep -------------
__global__ void prep_weights(
    const float* __restrict__ conv2_w, const float* __restrict__ Wq,
    const float* __restrict__ Wk, const float* __restrict__ Wff1,
    const float* __restrict__ Wff2,
    const float* __restrict__ bq, const float* __restrict__ bk,
    short* __restrict__ CB2Tb, short* __restrict__ QKTH, short* __restrict__ QKTL,
    short* __restrict__ WFF1b, short* __restrict__ WFF2b, float* __restrict__ BQK)
{
  const int total = 196608 + 262144 + 524288 + 524288 + 1024;
  for (int idx = blockIdx.x * 256 + threadIdx.x; idx < total;
       idx += gridDim.x * 256) {
    int t = idx;
    if (t < 196608) {
      int o = t / 768, rem = t % 768, kk = rem >> 8, i = rem & 255;
      CB2Tb[t] = f2bf(conv2_w[(o * 256 + i) * 3 + kk]);
    } else if ((t -= 196608) < 262144) {
      int L = t >> 17, rem = t & 131071, r = rem >> 8, k = rem & 255;
      float val = (r < 256) ? Wq[L * 65536 + k * 256 + r]
                            : Wk[L * 65536 + k * 256 + (r - 256)];
      short h = f2bf(val);
      QKTH[t] = h;
      QKTL[t] = f2bf(val - bf2f(h));
    } else if ((t -= 262144) < 524288) {
      WFF1b[t] = f2bf(Wff1[t]);
    } else if ((t -= 524288) < 524288) {
      WFF2b[t] = f2bf(Wff2[t]);
    } else {
      t -= 524288;
      int L = t >> 9, j = t & 511;
      BQK[t] = (j < 256) ? bq[L * 256 + j] : bk[L * 256 + (j - 256)];
    }
  }
}

// ------------- W_vo finish -------------
__global__ void vo_finish(const float* __restrict__ WVO, const float* __restrict__ Wo,
                          const float* __restrict__ bv, const float* __restrict__ bo,
                          short* __restrict__ WVOTb, float* __restrict__ BVO)
{
  const int total = 131072 + 512;
  for (int idx = blockIdx.x * 256 + threadIdx.x; idx < total;
       idx += gridDim.x * 256) {
    if (idx < 131072) {
      int L = idx >> 16, rem = idx & 65535, n = rem >> 8, k = rem & 255;
      WVOTb[idx] = f2bf(WVO[L * 65536 + k * 256 + n]);
    } else {
      int j = idx - 131072;
      int L = j >> 8, n = j & 255;
      float acc = bo[L * 256 + n];
      for (int k = 0; k < 256; k++)
        acc += bv[L * 256 + k] * Wo[(long long)L * 65536 + k * 256 + n];
      BVO[j] = acc;
    }
  }
}

// ------------- conv1 direct -> bf16 out -------------
__global__ __launch_bounds__(256) void conv1_direct(
    const float* __restrict__ x, const float* __restrict__ w,
    const float* __restrict__ bias, short* __restrict__ out)
{
  __shared__ float xs[66][16];
  const int b = blockIdx.y, lg = blockIdx.x, tid = threadIdx.x;
  const int l0 = lg * 64;
  for (int idx = tid; idx < 1056; idx += 256) {
    int r = idx >> 4, c = idx & 15;
    int l = l0 + r - 1;
    xs[r][c] = (l >= 0 && l < 1024) ? x[((long long)b * 1024 + l) * 16 + c] : 0.f;
  }
  float wr[48];
#pragma unroll
  for (int u = 0; u < 48; u++) wr[u] = w[tid * 48 + u];
  const float bs = bias[tid];
  __syncthreads();
  for (int r = 0; r < 64; r++) {
    float acc = bs;
#pragma unroll
    for (int i = 0; i < 16; i++) {
      acc += xs[r + 0][i] * wr[i * 3 + 0];
      acc += xs[r + 1][i] * wr[i * 3 + 1];
      acc += xs[r + 2][i] * wr[i * 3 + 2];
    }
    out[((long long)b * 1024 + l0 + r) * 256 + tid] = f2bf(fmaxf(acc, 0.f));
  }
}

// ------------- conv2 batch-edge fixup (bf16 src rows) -------------
__global__ void fixup_conv_b(float* __restrict__ h, const short* __restrict__ src,
                             const float* __restrict__ w, const float* __restrict__ bias)
{
  int b = blockIdx.x >> 1;
  int l = (blockIdx.x & 1) ? 1023 : 0;
  int o = threadIdx.x;
  float acc = bias[o];
  for (int kk = 0; kk < 3; kk++) {
    int t = l + kk - 1;
    if (t < 0 || t > 1023) continue;
    const short* srow = src + ((long long)b * 1024 + t) * 256;
    const float* wrow = w + (long long)o * 256 * 3 + kk;
    for (int i = 0; i < 256; i++) acc += bf2f(srow[i]) * wrow[(long long)i * 3];
  }
  h[((long long)b * 1024 + l) * 256 + o] = fmaxf(acc, 0.f);
}

// ------------- LayerNorm, one wave per row, float4 -------------
__global__ __launch_bounds__(256) void ln_rows4(
    const float* __restrict__ in, float* __restrict__ out,
    const float* __restrict__ g, const float* __restrict__ b,
    int prerelu, int out_stride, int out_off)
{
  const int row = blockIdx.x * 4 + (threadIdx.x >> 6);
  const int lane = threadIdx.x & 63;
  float4 x = ((const float4*)(in + (long long)row * 256))[lane];
  if (prerelu) {
    x.x = fmaxf(x.x, 0.f); x.y = fmaxf(x.y, 0.f);
    x.z = fmaxf(x.z, 0.f); x.w = fmaxf(x.w, 0.f);
  }
  float s = x.x + x.y + x.z + x.w;
#pragma unroll
  for (int o = 32; o > 0; o >>= 1) s += __shfl_xor(s, o, 64);
  float mean = s * (1.f / 256.f);
  float4 d = make_float4(x.x - mean, x.y - mean, x.z - mean, x.w - mean);
  float s2 = d.x * d.x + d.y * d.y + d.z * d.z + d.w * d.w;
#pragma unroll
  for (int o = 32; o > 0; o >>= 1) s2 += __shfl_xor(s2, o, 64);
  float rsd = rsqrtf(s2 * (1.f / 256.f) + 1e-5f);
  float4 gg = ((const float4*)g)[lane];
  float4 bb = ((const float4*)b)[lane];
  float4 o4 = make_float4(d.x * rsd * gg.x + bb.x, d.y * rsd * gg.y + bb.y,
                          d.z * rsd * gg.z + bb.z, d.w * rsd * gg.w + bb.w);
  ((float4*)(out + (long long)row * out_stride + out_off))[lane] = o4;
}

// ------------- series_decomp fp32->fp32 (+FIN pool row), XCD-clustered -------------
__global__ void decomp4(const float* __restrict__ in, float* __restrict__ out,
                        float* __restrict__ fin, int finoff)
{
  const int id = blockIdx.x;
  const int c = id & 7;
  const int s = id >> 3;
  const int b = c + 8 * (s >> 8);
  const int lg = s & 255;
  const int l = lg * 4 + (threadIdx.x >> 6);
  const int c4 = threadIdx.x & 63;
  const float4* base = (const float4*)(in + (long long)b * 262144);
  float4 acc = make_float4(0.f, 0.f, 0.f, 0.f);
#pragma unroll
  for (int j = -12; j <= 12; j++) {
    int t = l + j;
    t = t < 0 ? 0 : (t > 1023 ? 1023 : t);
    float4 x = base[t * 64 + c4];
    acc.x += x.x; acc.y += x.y; acc.z += x.z; acc.w += x.w;
  }
  float4 x0 = base[l * 64 + c4];
  float4 o = make_float4(x0.x - acc.x * (1.f / 25.f), x0.y - acc.y * (1.f / 25.f),
                         x0.z - acc.z * (1.f / 25.f), x0.w - acc.w * (1.f / 25.f));
  ((float4*)(out + (long long)b * 262144))[l * 64 + c4] = o;
  if (fin && l == 1023) {
    float* f = fin + (long long)b * 768 + finoff + c4 * 4;
    f[0] = o.x; f[1] = o.y; f[2] = o.z; f[3] = o.w;
  }
}

// ------------- series_decomp bf16->bf16, XCD-clustered -------------
__global__ void decomp4b(const short* __restrict__ in, short* __restrict__ out)
{
  const int id = blockIdx.x;
  const int c = id & 7;
  const int s = id >> 3;
  const int b = c + 8 * (s >> 8);
  const int lg = s & 255;
  const int l = lg * 4 + (threadIdx.x >> 6);
  const int c4 = threadIdx.x & 63;
  const short4v* base = (const short4v*)(in + (long long)b * 262144);
  float4 acc = make_float4(0.f, 0.f, 0.f, 0.f);
#pragma unroll
  for (int j = -12; j <= 12; j++) {
    int t = l + j;
    t = t < 0 ? 0 : (t > 1023 ? 1023 : t);
    short4v x = base[t * 64 + c4];
    acc.x += bf2f(x[0]); acc.y += bf2f(x[1]);
    acc.z += bf2f(x[2]); acc.w += bf2f(x[3]);
  }
  short4v x0 = base[l * 64 + c4];
  short4v o;
  o[0] = f2bf(bf2f(x0[0]) - acc.x * (1.f / 25.f));
  o[1] = f2bf(bf2f(x0[1]) - acc.y * (1.f / 25.f));
  o[2] = f2bf(bf2f(x0[2]) - acc.z * (1.f / 25.f));
  o[3] = f2bf(bf2f(x0[3]) - acc.w * (1.f / 25.f));
  ((short4v*)(out + (long long)b * 262144))[l * 64 + c4] = o;
}

// ------------- top-20 + softmax, one wave per batch -------------
__global__ __launch_bounds__(64) void topk_softmax_wave(
    const float* __restrict__ mv, float* __restrict__ wts, int* __restrict__ dly)
{
  const int b = blockIdx.x, lane = threadIdx.x;
  float v[16];
#pragma unroll
  for (int j = 0; j < 16; j++) v[j] = mv[b * 1024 + lane + 64 * j];
  float selv = 0.f; int seli = 0;
  for (int it = 0; it < 20; it++) {
    float bv = -1e30f; int bi = 0x7fffffff;
#pragma unroll
    for (int j = 0; j < 16; j++) {
      float x = v[j]; int idx = lane + 64 * j;
      if (x > bv || (x == bv && idx < bi)) { bv = x; bi = idx; }
    }
#pragma unroll
    for (int off = 32; off > 0; off >>= 1) {
      float ov = __shfl_xor(bv, off, 64);
      int   oi = __shfl_xor(bi, off, 64);
      if (ov > bv || (ov == bv && oi < bi)) { bv = ov; bi = oi; }
    }
    if (lane == it) { selv = bv; seli = bi; }
    if ((bi & 63) == lane) v[bi >> 6] = -1e30f;
  }
  const float w0 = __shfl(selv, 0, 64);
  float e = (lane < 20) ? __expf(selv - w0) : 0.f;
  float s = e;
#pragma unroll
  for (int off = 32; off > 0; off >>= 1) s += __shfl_xor(s, off, 64);
  if (lane < 20) {
    wts[b * 20 + lane] = e / s;
    dly[b * 20 + lane] = seli;
  }
}

// ------------- delay aggregation on enc (fp32 in, bf16 out), XCD-clustered ---------
__global__ void agg4e(const float* __restrict__ enc, const float* __restrict__ wts,
                      const int* __restrict__ dly, short* __restrict__ out)
{
  const int id = blockIdx.x;
  const int c = id & 7;
  const int s = id >> 3;
  const int b = c + 8 * (s >> 8);
  const int lg = s & 255;
  const int l = lg * 4 + (threadIdx.x >> 6);
  const int c4 = threadIdx.x & 63;
  const float4* vb = (const float4*)(enc + (long long)b * 262144);
  float4 acc = make_float4(0.f, 0.f, 0.f, 0.f);
  for (int kk = 0; kk < 20; kk++) {
    int d = dly[b * 20 + kk];
    float w = wts[b * 20 + kk];
    float4 x = vb[((l + d) & 1023) * 64 + c4];
    acc.x += w * x.x; acc.y += w * x.y; acc.z += w * x.z; acc.w += w * x.w;
  }
  short4v o;
  o[0] = f2bf(acc.x); o[1] = f2bf(acc.y); o[2] = f2bf(acc.z); o[3] = f2bf(acc.w);
  ((short4v*)(out + (long long)b * 262144))[l * 64 + c4] = o;
}

// ------------- small helpers -------------
__global__ void init_bias(float* __restrict__ C, const float* __restrict__ bias)
{
  C[(long long)blockIdx.x * 256 + threadIdx.x] = bias[threadIdx.x];
}

__global__ void rp2_kernel(const float* __restrict__ x, const float* __restrict__ w,
                           const float* __restrict__ bias, float* __restrict__ out)
{
  __shared__ float red[4];
  int b = blockIdx.x, tid = threadIdx.x;
  float p = x[b * 256 + tid] * w[tid];
#pragma unroll
  for (int o = 32; o > 0; o >>= 1) p += __shfl_down(p, o, 64);
  if ((tid & 63) == 0) red[tid >> 6] = p;
  __syncthreads();
  if (tid == 0) out[b] = red[0] + red[1] + red[2] + red[3] + bias[0];
}

// =========================== host launch ===========================
static inline void gemm(hipStream_t s, const float* A, const float* B, float* C,
                        int M, int N, int K, int shift, const float* bias,
                        const float* res, int flags, int splitz = 1)
{
  dim3 g((N + 63) / 64, (M + 63) / 64, splitz);
  gemm_f32<<<g, dim3(256), 0, s>>>(A, B, C, M, N, K, shift, bias, res, flags);
}

extern "C" void kernel_launch(void* const* d_in, const int* in_sizes, int n_in,
                              void* d_out, int out_size, void* d_ws, size_t ws_size,
                              hipStream_t stream)
{
  const float* x_enc  = (const float*)d_in[0];
  const float* conv1_w= (const float*)d_in[1];
  const float* conv1_b= (const float*)d_in[2];
  const float* conv2_w= (const float*)d_in[3];
  const float* conv2_b= (const float*)d_in[4];
  const float* cnn_g  = (const float*)d_in[5];
  const float* cnn_b  = (const float*)d_in[6];
  const float* proj_w = (const float*)d_in[7];
  const float* proj_b = (const float*)d_in[8];
  const float* pln_g  = (const float*)d_in[9];
  const float* pln_b  = (const float*)d_in[10];
  const float* Wq     = (const float*)d_in[11];
  const float* bq     = (const float*)d_in[12];
  const float* Wk     = (const float*)d_in[13];
  const float* bk     = (const float*)d_in[14];
  const float* Wv     = (const float*)d_in[15];
  const float* bv     = (const float*)d_in[16];
  const float* Wo     = (const float*)d_in[17];
  const float* bo     = (const float*)d_in[18];
  const float* Wff1   = (const float*)d_in[19];
  const float* Wff2   = (const float*)d_in[20];
  const float* rp1_w  = (const float*)d_in[21];
  const float* rp1_b  = (const float*)d_in[22];
  const float* rln_g  = (const float*)d_in[23];
  const float* rln_b  = (const float*)d_in[24];
  const float* rp2_w  = (const float*)d_in[25];
  const float* rp2_b  = (const float*)d_in[26];
  (void)in_sizes; (void)n_in;

  const size_t BLD = 64ull * 1024 * 256;
  size_t need;
  {
    size_t o = 3 * BLD
             + 98304 + 131072 + 131072 + 262144 + 262144
             + 65536 + 512 + 1024
             + 65536 + 1280 + 1280 + 16384 + 49152 + 16384 + 16384;
    need = o * sizeof(float);
  }
  if (ws_size < need) {
    hipMemsetAsync(d_out, 0, (size_t)out_size * sizeof(float), stream);
    return;
  }

  float* ws = (float*)d_ws;
  size_t off = 0;
  auto alloc = [&](size_t n) { float* p = ws + off; off += n; return p; };
  float* BUF0 = alloc(BLD);   // conv1(bf16)/QKH/agg(bf16)/xd(bf16); WVO scratch
  float* BUF1 = alloc(BLD);   // conv2(fp32)/QKL/x(bf16)/ffn out(fp32)
  float* BUF2 = alloc(BLD);   // enc(fp32) / ffn hidden (bf16)
  short* CB2Tb = (short*)alloc(98304);
  short* QKTH  = (short*)alloc(131072);
  short* QKTL  = (short*)alloc(131072);
  short* WFF1b = (short*)alloc(262144);
  short* WFF2b = (short*)alloc(262144);
  short* WVOTb = (short*)alloc(65536);
  float* BVO  = alloc(512);
  float* BQK  = alloc(1024);
  float* MV   = alloc(65536);
  float* WTS  = alloc(1280);
  int*   DLY  = (int*)alloc(1280);
  float* PE   = alloc(16384);
  float* FIN  = alloc(49152);
  float* O1   = alloc(16384);
  float* O2   = alloc(16384);
  float* WVO  = BUF0;   // scratch, dead before conv1 writes BUF0

  const int M = 65536;
  dim3 blk(256);

  prep_weights<<<1024, blk, 0, stream>>>(conv2_w, Wq, Wk, Wff1, Wff2, bq, bk,
                                         CB2Tb, QKTH, QKTL, WFF1b, WFF2b, BQK);
  for (int i = 0; i < 2; i++)
    gemm(stream, Wv + (size_t)i * 65536, Wo + (size_t)i * 65536,
         WVO + (size_t)i * 65536, 256, 256, 256, 0, nullptr, nullptr, 0);
  vo_finish<<<516, blk, 0, stream>>>(WVO, Wo, bv, bo, WVOTb, BVO);

  // --- CNN frontend ---
  conv1_direct<<<dim3(16, 64), blk, 0, stream>>>(x_enc, conv1_w, conv1_b, (short*)BUF0);
  gemm_bf16_bt<<<dim3(512, 2), blk, 0, stream>>>(
      BUF0, CB2Tb, BUF1, nullptr, conv2_b, M, 256, 768, 256,
      FLAG_ABF16 | FLAG_RELU, 1);
  fixup_conv_b<<<128, blk, 0, stream>>>(BUF1, (const short*)BUF0, conv2_w, conv2_b);
  ln_rows4<<<16384, blk, 0, stream>>>(BUF1, BUF2, cnn_g, cnn_b, 0, 256, 0);

  // --- encoder layers (enc fp32 in BUF2) ---
  for (int i = 0; i < 2; i++) {
    short* QKH = (short*)BUF0;
    short* QKL = (short*)BUF1;
    gemm_qk<<<dim3(512, 4), blk, 0, stream>>>(
        BUF2, QKTH + (size_t)i * 131072, QKTL + (size_t)i * 131072,
        QKH, QKL, BQK + i * 512, M, 512, 256);
    hipMemsetAsync(MV, 0, 64 * 1024 * sizeof(float), stream);
    corr_mfma2<<<dim3(4096), blk, 0, stream>>>(QKH, QKL, MV);
    topk_softmax_wave<<<64, dim3(64), 0, stream>>>(MV, WTS, DLY);
    // fused v+o: x = enc + agg(enc) @ W_vo + b_vo  (x stored bf16)
    agg4e<<<dim3(16384), blk, 0, stream>>>(BUF2, WTS, DLY, (short*)BUF0);
    gemm_bf16_bt<<<dim3(512, 2), blk, 0, stream>>>(
        BUF0, WVOTb + (size_t)i * 65536, BUF1, BUF2, BVO + i * 256,
        M, 256, 256, 256, FLAG_ABF16 | FLAG_OBF16, 0);
    decomp4b<<<16384, blk, 0, stream>>>((const short*)BUF1, (short*)BUF0); // xd bf16
    // FFN: 2 chunks of 32768 rows; hidden bf16 in BUF2 (enc dead); out fp32 BUF1
    for (int c = 0; c < 2; c++) {
      const short* xd = (const short*)BUF0 + (size_t)c * 32768 * 256;
      gemm_bf16_bt<<<dim3(256, 8), blk, 0, stream>>>(
          xd, WFF1b + (size_t)i * 262144, BUF2, nullptr, nullptr,
          32768, 1024, 256, 256, FLAG_ABF16 | FLAG_GELU | FLAG_OBF16, 0);
      gemm_bf16_bt<<<dim3(256, 2), blk, 0, stream>>>(
          BUF2, WFF2b + (size_t)i * 262144, BUF1 + (size_t)c * 32768 * 256,
          (const float*)xd, nullptr,
          32768, 256, 1024, 1024, FLAG_ABF16 | FLAG_RESB16, 0);
    }
    decomp4<<<16384, blk, 0, stream>>>(BUF1, BUF2, FIN, i * 256); // enc + FIN row
  }

  // --- head (fp32, exact) ---
  init_bias<<<64, blk, 0, stream>>>(PE, proj_b);
  gemm(stream, x_enc, proj_w, PE, 64, 256, 16384, 0, nullptr, nullptr, 0, 32);
  ln_rows4<<<16, blk, 0, stream>>>(PE, FIN, pln_g, pln_b, 1, 768, 512);
  init_bias<<<64, blk, 0, stream>>>(O1, rp1_b);
  gemm(stream, FIN, rp1_w, O1, 64, 256, 768, 0, nullptr, nullptr, 0, 4);
  ln_rows4<<<16, blk, 0, stream>>>(O1, O2, rln_g, rln_b, 1, 256, 0);
  rp2_kernel<<<64, blk, 0, stream>>>(O2, rp2_w, rp2_b, (float*)d_out);
}

// Round 15
// 1709.253 us; speedup vs baseline: 1.1831x; 1.0256x over previous
//
#include <hip/hip_runtime.h>
#include <math.h>

#define FLAG_ACC     1
#define FLAG_RELU    2
#define FLAG_GELU    4
#define FLAG_ABF16   8
#define FLAG_OBF16  16
#define FLAG_RESB16 32

typedef __attribute__((ext_vector_type(8))) short short8;
typedef __attribute__((ext_vector_type(4))) short short4v;
typedef __attribute__((ext_vector_type(4))) float f32x4;

__device__ __forceinline__ short f2bf(float f) {
  unsigned u = __builtin_bit_cast(unsigned, f);
  unsigned r = u + 0x7fffu + ((u >> 16) & 1u);
  return (short)(r >> 16);
}
__device__ __forceinline__ float bf2f(short s) {
  unsigned u = ((unsigned)(unsigned short)s) << 16;
  return __builtin_bit_cast(float, u);
}
__device__ __forceinline__ void load_lds16(const void* g, void* lds) {
  __builtin_amdgcn_global_load_lds(
      (const __attribute__((address_space(1))) void*)g,
      (__attribute__((address_space(3))) void*)lds, 16, 0, 0);
}

// ---------------- generic fp32 tiled GEMM (head + W_vo prep) ----------------
__global__ __launch_bounds__(256) void gemm_f32(
    const float* __restrict__ A, const float* __restrict__ B, float* __restrict__ C,
    int M, int N, int K, int a_shift,
    const float* __restrict__ bias, const float* __restrict__ residual, int flags)
{
  __shared__ float As[16][65];
  __shared__ float Bs[16][64];
  const int tid = threadIdx.x;
  const int tx = tid & 15, ty = tid >> 4;
  const int row0 = blockIdx.y * 64;
  const int col0 = blockIdx.x * 64;
  int kbeg = 0, kend = K;
  if ((int)gridDim.z > 1) {
    int kchunk = ((K + (int)gridDim.z - 1) / (int)gridDim.z + 15) & ~15;
    kbeg = (int)blockIdx.z * kchunk;
    kend = min(K, kbeg + kchunk);
  }
  float acc[4][4] = {};
  const int a_m = tid >> 2;
  const int a_k = (tid & 3) << 2;
  const int b_n = (tid & 15) << 2;
  const int b_k = tid >> 4;
  for (int k0 = kbeg; k0 < kend; k0 += 16) {
    int srow = row0 + a_m + a_shift;
    float4 av = make_float4(0.f, 0.f, 0.f, 0.f);
    if (srow >= 0 && srow < M)
      av = *reinterpret_cast<const float4*>(A + (long long)srow * K + (k0 + a_k));
    As[a_k + 0][a_m] = av.x; As[a_k + 1][a_m] = av.y;
    As[a_k + 2][a_m] = av.z; As[a_k + 3][a_m] = av.w;
    float4 bv = make_float4(0.f, 0.f, 0.f, 0.f);
    int brow = k0 + b_k;
    if (brow < K)
      bv = *reinterpret_cast<const float4*>(B + (long long)brow * N + (col0 + b_n));
    Bs[b_k][b_n + 0] = bv.x; Bs[b_k][b_n + 1] = bv.y;
    Bs[b_k][b_n + 2] = bv.z; Bs[b_k][b_n + 3] = bv.w;
    __syncthreads();
#pragma unroll
    for (int kk = 0; kk < 16; kk++) {
      float ar[4], br[4];
#pragma unroll
      for (int i = 0; i < 4; i++) ar[i] = As[kk][ty * 4 + i];
#pragma unroll
      for (int j = 0; j < 4; j++) br[j] = Bs[kk][tx * 4 + j];
#pragma unroll
      for (int i = 0; i < 4; i++)
#pragma unroll
        for (int j = 0; j < 4; j++)
          acc[i][j] += ar[i] * br[j];
    }
    __syncthreads();
  }
  if ((int)gridDim.z > 1) {
#pragma unroll
    for (int i = 0; i < 4; i++) {
      int r = row0 + ty * 4 + i; if (r >= M) continue;
#pragma unroll
      for (int j = 0; j < 4; j++) {
        int c = col0 + tx * 4 + j; if (c >= N) continue;
        atomicAdd(&C[(long long)r * N + c], acc[i][j]);
      }
    }
    return;
  }
#pragma unroll
  for (int i = 0; i < 4; i++) {
    int r = row0 + ty * 4 + i; if (r >= M) continue;
#pragma unroll
    for (int j = 0; j < 4; j++) {
      int c = col0 + tx * 4 + j; if (c >= N) continue;
      float v = acc[i][j];
      if (bias)     v += bias[c];
      if (residual) v += residual[(long long)r * N + c];
      if (flags & FLAG_ACC)  v += C[(long long)r * N + c];
      if (flags & FLAG_RELU) v = fmaxf(v, 0.f);
      if (flags & FLAG_GELU) v = 0.5f * v * (1.f + erff(v * 0.70710678118654752f));
      C[(long long)r * N + c] = v;
    }
  }
}

// ---------------- bf16 MFMA GEMM: C[M,N] = A[M,K] @ Btb[N,K]^T (B pre-bf16) --------
__global__ __launch_bounds__(256) void gemm_bf16_bt(
    const void* __restrict__ Av, const short* __restrict__ Btb, void* __restrict__ Cv,
    const float* __restrict__ residual, const float* __restrict__ bias,
    int M, int N, int K, int lda, int flags, int tapped)
{
  __shared__ __align__(16) short Asl[4096];
  __shared__ __align__(16) short Bsl[4096];
  const int tid = threadIdx.x;
  const int row0 = blockIdx.x * 128;
  const int col0 = blockIdx.y * 128;
  const int lane = tid & 63;
  const int wave = tid >> 6;
  const int wm = (wave >> 1) * 64;
  const int wn = (wave & 1) * 64;
  const int fm = lane & 15;
  const int k8c = lane >> 4;
  const int mr = tid >> 1;
  const int mkc = (tid & 1) * 2;
  const int msw = (mr >> 1) & 3;
  const bool a_dma = (flags & FLAG_ABF16) && !tapped;

  f32x4 acc[4][4] = {};
  for (int k0 = 0; k0 < K; k0 += 32) {
    __syncthreads();
#pragma unroll
    for (int u = 0; u < 2; u++) {
      int p = (wave + u * 4) * 64 + lane;
      int r = p >> 2;
      int kc = (p & 3) ^ ((r >> 1) & 3);
      load_lds16(Btb + (long long)(col0 + r) * K + k0 + kc * 8,
                 (char*)Bsl + (wave + u * 4) * 1024);
    }
    if (a_dma) {
      const short* Ab = (const short*)Av;
#pragma unroll
      for (int u = 0; u < 2; u++) {
        int p = (wave + u * 4) * 64 + lane;
        int r = p >> 2;
        int kc = (p & 3) ^ ((r >> 1) & 3);
        load_lds16(Ab + (long long)(row0 + r) * lda + k0 + kc * 8,
                   (char*)Asl + (wave + u * 4) * 1024);
      }
    } else {
      int arow = row0 + mr + (tapped ? (k0 >> 8) - 1 : 0);
      int acol = tapped ? (k0 & 255) : k0;
      bool ok = (arow >= 0 && arow < M);
      short8 v0, v1;
      if (flags & FLAG_ABF16) {
        const short* ga = (const short*)Av + (long long)arow * lda + acol + mkc * 8;
        short8 z;
#pragma unroll
        for (int u = 0; u < 8; u++) z[u] = 0;
        v0 = ok ? *(const short8*)(ga) : z;
        v1 = ok ? *(const short8*)(ga + 8) : z;
      } else {
        const float* ga = (const float*)Av + (long long)arow * lda + acol + mkc * 8;
        float4 f0 = make_float4(0.f,0.f,0.f,0.f), f1 = f0, f2 = f0, f3 = f0;
        if (ok) {
          f0 = *(const float4*)(ga);     f1 = *(const float4*)(ga + 4);
          f2 = *(const float4*)(ga + 8); f3 = *(const float4*)(ga + 12);
        }
        v0[0]=f2bf(f0.x); v0[1]=f2bf(f0.y); v0[2]=f2bf(f0.z); v0[3]=f2bf(f0.w);
        v0[4]=f2bf(f1.x); v0[5]=f2bf(f1.y); v0[6]=f2bf(f1.z); v0[7]=f2bf(f1.w);
        v1[0]=f2bf(f2.x); v1[1]=f2bf(f2.y); v1[2]=f2bf(f2.z); v1[3]=f2bf(f2.w);
        v1[4]=f2bf(f3.x); v1[5]=f2bf(f3.y); v1[6]=f2bf(f3.z); v1[7]=f2bf(f3.w);
      }
      *(short8*)&Asl[(mr * 4 + (mkc ^ msw)) * 8] = v0;
      *(short8*)&Asl[(mr * 4 + ((mkc + 1) ^ msw)) * 8] = v1;
    }
    __syncthreads();
    short8 af[4], bf[4];
#pragma unroll
    for (int i = 0; i < 4; i++) {
      int r = wm + i * 16 + fm;
      af[i] = *(short8*)&Asl[(r * 4 + (k8c ^ ((r >> 1) & 3))) * 8];
    }
#pragma unroll
    for (int j = 0; j < 4; j++) {
      int r = wn + j * 16 + fm;
      bf[j] = *(short8*)&Bsl[(r * 4 + (k8c ^ ((r >> 1) & 3))) * 8];
    }
#pragma unroll
    for (int i = 0; i < 4; i++)
#pragma unroll
      for (int j = 0; j < 4; j++)
        acc[i][j] = __builtin_amdgcn_mfma_f32_16x16x32_bf16(af[i], bf[j], acc[i][j], 0, 0, 0);
  }
#pragma unroll
  for (int i = 0; i < 4; i++) {
    const int mbase = row0 + wm + i * 16 + (lane >> 4) * 4;
#pragma unroll
    for (int j = 0; j < 4; j++) {
      const int n = col0 + wn + j * 16 + fm;
      const float bs = bias ? bias[n] : 0.f;
#pragma unroll
      for (int r = 0; r < 4; r++) {
        long long idx = (long long)(mbase + r) * N + n;
        float v = acc[i][j][r] + bs;
        if (residual) {
          if (flags & FLAG_RESB16) v += bf2f(((const short*)residual)[idx]);
          else                     v += residual[idx];
        }
        if (flags & FLAG_ACC)  v += ((const float*)Cv)[idx];
        if (flags & FLAG_RELU) v = fmaxf(v, 0.f);
        if (flags & FLAG_GELU) v = 0.5f * v * (1.f + erff(v * 0.70710678118654752f));
        if (flags & FLAG_OBF16) ((short*)Cv)[idx] = f2bf(v);
        else                    ((float*)Cv)[idx] = v;
      }
    }
  }
}

// ---------------- q+k fused bf16x3 GEMM, B pre-split+DMA, split-bf16 output --------
__global__ __launch_bounds__(256) void gemm_qk(
    const float* __restrict__ A, const short* __restrict__ Bth,
    const short* __restrict__ Btl,
    short* __restrict__ Ch, short* __restrict__ Cl,
    const float* __restrict__ bias, int M, int N, int K)
{
  __shared__ __align__(16) char smem[32768];
  short* Ahi = (short*)smem;
  short* Alo = (short*)(smem + 8192);
  short* Bhi = (short*)(smem + 16384);
  short* Blo = (short*)(smem + 24576);
  const int tid = threadIdx.x;
  const int row0 = blockIdx.x * 128;
  const int col0 = blockIdx.y * 128;
  const int lane = tid & 63;
  const int wave = tid >> 6;
  const int wm = (wave >> 1) * 64;
  const int wn = (wave & 1) * 64;
  const int fm = lane & 15;
  const int k8c = lane >> 4;
  const int mr = tid >> 1;
  const int mkc = (tid & 1) * 2;
  const int msw = (mr >> 1) & 3;

  f32x4 acc[4][4] = {};
  for (int k0 = 0; k0 < K; k0 += 32) {
    __syncthreads();
#pragma unroll
    for (int u = 0; u < 2; u++) {
      int p = (wave + u * 4) * 64 + lane;
      int r = p >> 2;
      int kc = (p & 3) ^ ((r >> 1) & 3);
      long long go = (long long)(col0 + r) * K + k0 + kc * 8;
      int lo = (wave + u * 4) * 1024;
      load_lds16(Bth + go, (char*)Bhi + lo);
      load_lds16(Btl + go, (char*)Blo + lo);
    }
    {
      const float* ga = A + (long long)(row0 + mr) * K + k0 + mkc * 8;
      float4 f0 = *(const float4*)(ga),     f1 = *(const float4*)(ga + 4);
      float4 f2 = *(const float4*)(ga + 8), f3 = *(const float4*)(ga + 12);
      short8 h0, l0, h1, l1;
      h0[0]=f2bf(f0.x); h0[1]=f2bf(f0.y); h0[2]=f2bf(f0.z); h0[3]=f2bf(f0.w);
      h0[4]=f2bf(f1.x); h0[5]=f2bf(f1.y); h0[6]=f2bf(f1.z); h0[7]=f2bf(f1.w);
      l0[0]=f2bf(f0.x-bf2f(h0[0])); l0[1]=f2bf(f0.y-bf2f(h0[1]));
      l0[2]=f2bf(f0.z-bf2f(h0[2])); l0[3]=f2bf(f0.w-bf2f(h0[3]));
      l0[4]=f2bf(f1.x-bf2f(h0[4])); l0[5]=f2bf(f1.y-bf2f(h0[5]));
      l0[6]=f2bf(f1.z-bf2f(h0[6])); l0[7]=f2bf(f1.w-bf2f(h0[7]));
      h1[0]=f2bf(f2.x); h1[1]=f2bf(f2.y); h1[2]=f2bf(f2.z); h1[3]=f2bf(f2.w);
      h1[4]=f2bf(f3.x); h1[5]=f2bf(f3.y); h1[6]=f2bf(f3.z); h1[7]=f2bf(f3.w);
      l1[0]=f2bf(f2.x-bf2f(h1[0])); l1[1]=f2bf(f2.y-bf2f(h1[1]));
      l1[2]=f2bf(f2.z-bf2f(h1[2])); l1[3]=f2bf(f2.w-bf2f(h1[3]));
      l1[4]=f2bf(f3.x-bf2f(h1[4])); l1[5]=f2bf(f3.y-bf2f(h1[5]));
      l1[6]=f2bf(f3.z-bf2f(h1[6])); l1[7]=f2bf(f3.w-bf2f(h1[7]));
      int p0 = (mr * 4 + (mkc ^ msw)) * 8;
      int p1 = (mr * 4 + ((mkc + 1) ^ msw)) * 8;
      *(short8*)&Ahi[p0] = h0; *(short8*)&Ahi[p1] = h1;
      *(short8*)&Alo[p0] = l0; *(short8*)&Alo[p1] = l1;
    }
    __syncthreads();
    short8 ah[4], al[4], bh[4], bl[4];
#pragma unroll
    for (int i = 0; i < 4; i++) {
      int r = wm + i * 16 + fm;
      int p = (r * 4 + (k8c ^ ((r >> 1) & 3))) * 8;
      ah[i] = *(short8*)&Ahi[p];
      al[i] = *(short8*)&Alo[p];
    }
#pragma unroll
    for (int j = 0; j < 4; j++) {
      int r = wn + j * 16 + fm;
      int p = (r * 4 + (k8c ^ ((r >> 1) & 3))) * 8;
      bh[j] = *(short8*)&Bhi[p];
      bl[j] = *(short8*)&Blo[p];
    }
#pragma unroll
    for (int i = 0; i < 4; i++)
#pragma unroll
      for (int j = 0; j < 4; j++) {
        acc[i][j] = __builtin_amdgcn_mfma_f32_16x16x32_bf16(ah[i], bh[j], acc[i][j], 0, 0, 0);
        acc[i][j] = __builtin_amdgcn_mfma_f32_16x16x32_bf16(ah[i], bl[j], acc[i][j], 0, 0, 0);
        acc[i][j] = __builtin_amdgcn_mfma_f32_16x16x32_bf16(al[i], bh[j], acc[i][j], 0, 0, 0);
      }
  }
#pragma unroll
  for (int i = 0; i < 4; i++) {
    const int mbase = row0 + wm + i * 16 + (lane >> 4) * 4;
#pragma unroll
    for (int j = 0; j < 4; j++) {
      const int n = col0 + wn + j * 16 + fm;
      const float bs = bias ? bias[n] : 0.f;
#pragma unroll
      for (int r = 0; r < 4; r++) {
        long long idx = (long long)(mbase + r) * N + n;
        float v = acc[i][j][r] + bs;
        short h = f2bf(v);
        short l = f2bf(v - bf2f(h));
        Ch[idx] = h; Cl[idx] = l;
      }
    }
  }
}

// ------------- circular-correlation mean: BK=64 staging (4 rounds), 64 KB LDS ------
// Staging arrays 128 rows x 8 chunks x 8 shorts = 16 KB each (4 arrays = 64 KB);
// Sf overlays same 64 KB after MFMA phase. Swizzle: phys = kc ^ (r & 7).
__global__ __launch_bounds__(256) void corr_mfma3(
    const short* __restrict__ qkh, const short* __restrict__ qkl, float* __restrict__ mv)
{
  __shared__ __align__(16) char smem[65536];
  short* Ahi = (short*)smem;
  short* Alo = (short*)(smem + 16384);
  short* Bhi = (short*)(smem + 32768);
  short* Blo = (short*)(smem + 49152);
  float* Sf = (float*)smem;

  const int id = blockIdx.x;
  const int b  = (id & 7) + 8 * (id >> 9);
  const int tile = (id >> 3) & 63;
  const int t0 = (tile >> 3) * 128;
  const int s0 = (tile & 7) * 128;
  const int tid = threadIdx.x;
  const int lane = tid & 63;
  const int wave = tid >> 6;
  const int wm = (wave >> 1) * 64;
  const int wn = (wave & 1) * 64;
  const int fm = lane & 15;
  const int k8c = lane >> 4;
  const long long bb = (long long)b * 524288;

  f32x4 acc[4][4] = {};
  for (int k0 = 0; k0 < 256; k0 += 64) {
    __syncthreads();
#pragma unroll
    for (int u = 0; u < 4; u++) {
      int p = (wave * 4 + u) * 64 + lane;
      int r = p >> 3;
      int kc = (p & 7) ^ (r & 7);
      long long qo = bb + (long long)(t0 + r) * 512 + k0 + kc * 8;
      long long ko = bb + (long long)(s0 + r) * 512 + 256 + k0 + kc * 8;
      int lo = (wave * 4 + u) * 1024;
      load_lds16(qkh + qo, (char*)Ahi + lo);
      load_lds16(qkl + qo, (char*)Alo + lo);
      load_lds16(qkh + ko, (char*)Bhi + lo);
      load_lds16(qkl + ko, (char*)Blo + lo);
    }
    __syncthreads();
#pragma unroll
    for (int kk8 = 0; kk8 < 8; kk8 += 4) {
      short8 ah[4], al[4], bh[4], bl[4];
#pragma unroll
      for (int i = 0; i < 4; i++) {
        int r = wm + i * 16 + fm;
        int p = (r * 8 + ((kk8 + k8c) ^ (r & 7))) * 8;
        ah[i] = *(short8*)&Ahi[p];
        al[i] = *(short8*)&Alo[p];
      }
#pragma unroll
      for (int j = 0; j < 4; j++) {
        int r = wn + j * 16 + fm;
        int p = (r * 8 + ((kk8 + k8c) ^ (r & 7))) * 8;
        bh[j] = *(short8*)&Bhi[p];
        bl[j] = *(short8*)&Blo[p];
      }
#pragma unroll
      for (int i = 0; i < 4; i++)
#pragma unroll
        for (int j = 0; j < 4; j++) {
          acc[i][j] = __builtin_amdgcn_mfma_f32_16x16x32_bf16(ah[i], bh[j], acc[i][j], 0, 0, 0);
          acc[i][j] = __builtin_amdgcn_mfma_f32_16x16x32_bf16(ah[i], bl[j], acc[i][j], 0, 0, 0);
          acc[i][j] = __builtin_amdgcn_mfma_f32_16x16x32_bf16(al[i], bh[j], acc[i][j], 0, 0, 0);
        }
    }
  }
  __syncthreads();   // staging reads done; reuse LDS as skewed S
#pragma unroll
  for (int i = 0; i < 4; i++) {
    const int row = wm + i * 16 + (lane >> 4) * 4;
#pragma unroll
    for (int j = 0; j < 4; j++) {
      const int col = wn + j * 16 + fm;
#pragma unroll
      for (int r = 0; r < 4; r++)
        Sf[(row + r) * 128 + ((2 * (row + r) - col) & 127)] =
            acc[i][j][r] * (1.f / 256.f);
    }
  }
  __syncthreads();
  {
    const int dd = tid & 127;
    const int mb = (tid >> 7) * 64;
    float s_ge = 0.f, s_lt = 0.f;
    for (int mm = 0; mm < 64; mm++) {
      int m = mb + mm;
      float v = Sf[m * 128 + ((dd + m) & 127)];
      if (m >= dd) s_ge += v; else s_lt += v;
    }
    atomicAdd(&mv[b * 1024 + ((t0 - s0 + dd) & 1023)], s_ge);
    atomicAdd(&mv[b * 1024 + ((t0 - s0 + dd - 128) & 1023)], s_lt);
  }
}

// ------------- one-shot weight prep -------------
__global__ void prep_weights(
    const float* __restrict__ conv2_w, const float* __restrict__ Wq,
    const float* __restrict__ Wk, const float* __restrict__ Wff1,
    const float* __restrict__ Wff2,
    const float* __restrict__ bq, const float* __restrict__ bk,
    short* __restrict__ CB2Tb, short* __restrict__ QKTH, short* __restrict__ QKTL,
    short* __restrict__ WFF1b, short* __restrict__ WFF2b, float* __restrict__ BQK)
{
  const int total = 196608 + 262144 + 524288 + 524288 + 1024;
  for (int idx = blockIdx.x * 256 + threadIdx.x; idx < total;
       idx += gridDim.x * 256) {
    int t = idx;
    if (t < 196608) {
      int o = t / 768, rem = t % 768, kk = rem >> 8, i = rem & 255;
      CB2Tb[t] = f2bf(conv2_w[(o * 256 + i) * 3 + kk]);
    } else if ((t -= 196608) < 262144) {
      int L = t >> 17, rem = t & 131071, r = rem >> 8, k = rem & 255;
      float val = (r < 256) ? Wq[L * 65536 + k * 256 + r]
                            : Wk[L * 65536 + k * 256 + (r - 256)];
      short h = f2bf(val);
      QKTH[t] = h;
      QKTL[t] = f2bf(val - bf2f(h));
    } else if ((t -= 262144) < 524288) {
      WFF1b[t] = f2bf(Wff1[t]);
    } else if ((t -= 524288) < 524288) {
      WFF2b[t] = f2bf(Wff2[t]);
    } else {
      t -= 524288;
      int L = t >> 9, j = t & 511;
      BQK[t] = (j < 256) ? bq[L * 256 + j] : bk[L * 256 + (j - 256)];
    }
  }
}

// ------------- W_vo finish -------------
__global__ void vo_finish(const float* __restrict__ WVO, const float* __restrict__ Wo,
                          const float* __restrict__ bv, const float* __restrict__ bo,
                          short* __restrict__ WVOTb, float* __restrict__ BVO)
{
  const int total = 131072 + 512;
  for (int idx = blockIdx.x * 256 + threadIdx.x; idx < total;
       idx += gridDim.x * 256) {
    if (idx < 131072) {
      int L = idx >> 16, rem = idx & 65535, n = rem >> 8, k = rem & 255;
      WVOTb[idx] = f2bf(WVO[L * 65536 + k * 256 + n]);
    } else {
      int j = idx - 131072;
      int L = j >> 8, n = j & 255;
      float acc = bo[L * 256 + n];
      for (int k = 0; k < 256; k++)
        acc += bv[L * 256 + k] * Wo[(long long)L * 65536 + k * 256 + n];
      BVO[j] = acc;
    }
  }
}

// ------------- conv1 direct -> bf16 out -------------
__global__ __launch_bounds__(256) void conv1_direct(
    const float* __restrict__ x, const float* __restrict__ w,
    const float* __restrict__ bias, short* __restrict__ out)
{
  __shared__ float xs[66][16];
  const int b = blockIdx.y, lg = blockIdx.x, tid = threadIdx.x;
  const int l0 = lg * 64;
  for (int idx = tid; idx < 1056; idx += 256) {
    int r = idx >> 4, c = idx & 15;
    int l = l0 + r - 1;
    xs[r][c] = (l >= 0 && l < 1024) ? x[((long long)b * 1024 + l) * 16 + c] : 0.f;
  }
  float wr[48];
#pragma unroll
  for (int u = 0; u < 48; u++) wr[u] = w[tid * 48 + u];
  const float bs = bias[tid];
  __syncthreads();
  for (int r = 0; r < 64; r++) {
    float acc = bs;
#pragma unroll
    for (int i = 0; i < 16; i++) {
      acc += xs[r + 0][i] * wr[i * 3 + 0];
      acc += xs[r + 1][i] * wr[i * 3 + 1];
      acc += xs[r + 2][i] * wr[i * 3 + 2];
    }
    out[((long long)b * 1024 + l0 + r) * 256 + tid] = f2bf(fmaxf(acc, 0.f));
  }
}

// ------------- conv2 batch-edge fixup (bf16 src rows) -------------
__global__ void fixup_conv_b(float* __restrict__ h, const short* __restrict__ src,
                             const float* __restrict__ w, const float* __restrict__ bias)
{
  int b = blockIdx.x >> 1;
  int l = (blockIdx.x & 1) ? 1023 : 0;
  int o = threadIdx.x;
  float acc = bias[o];
  for (int kk = 0; kk < 3; kk++) {
    int t = l + kk - 1;
    if (t < 0 || t > 1023) continue;
    const short* srow = src + ((long long)b * 1024 + t) * 256;
    const float* wrow = w + (long long)o * 256 * 3 + kk;
    for (int i = 0; i < 256; i++) acc += bf2f(srow[i]) * wrow[(long long)i * 3];
  }
  h[((long long)b * 1024 + l) * 256 + o] = fmaxf(acc, 0.f);
}

// ------------- LayerNorm, one wave per row, float4 -------------
__global__ __launch_bounds__(256) void ln_rows4(
    const float* __restrict__ in, float* __restrict__ out,
    const float* __restrict__ g, const float* __restrict__ b,
    int prerelu, int out_stride, int out_off)
{
  const int row = blockIdx.x * 4 + (threadIdx.x >> 6);
  const int lane = threadIdx.x & 63;
  float4 x = ((const float4*)(in + (long long)row * 256))[lane];
  if (prerelu) {
    x.x = fmaxf(x.x, 0.f); x.y = fmaxf(x.y, 0.f);
    x.z = fmaxf(x.z, 0.f); x.w = fmaxf(x.w, 0.f);
  }
  float s = x.x + x.y + x.z + x.w;
#pragma unroll
  for (int o = 32; o > 0; o >>= 1) s += __shfl_xor(s, o, 64);
  float mean = s * (1.f / 256.f);
  float4 d = make_float4(x.x - mean, x.y - mean, x.z - mean, x.w - mean);
  float s2 = d.x * d.x + d.y * d.y + d.z * d.z + d.w * d.w;
#pragma unroll
  for (int o = 32; o > 0; o >>= 1) s2 += __shfl_xor(s2, o, 64);
  float rsd = rsqrtf(s2 * (1.f / 256.f) + 1e-5f);
  float4 gg = ((const float4*)g)[lane];
  float4 bb = ((const float4*)b)[lane];
  float4 o4 = make_float4(d.x * rsd * gg.x + bb.x, d.y * rsd * gg.y + bb.y,
                          d.z * rsd * gg.z + bb.z, d.w * rsd * gg.w + bb.w);
  ((float4*)(out + (long long)row * out_stride + out_off))[lane] = o4;
}

// ------------- series_decomp fp32->fp32 (+FIN pool row), XCD-clustered -------------
__global__ void decomp4(const float* __restrict__ in, float* __restrict__ out,
                        float* __restrict__ fin, int finoff)
{
  const int id = blockIdx.x;
  const int c = id & 7;
  const int s = id >> 3;
  const int b = c + 8 * (s >> 8);
  const int lg = s & 255;
  const int l = lg * 4 + (threadIdx.x >> 6);
  const int c4 = threadIdx.x & 63;
  const float4* base = (const float4*)(in + (long long)b * 262144);
  float4 acc = make_float4(0.f, 0.f, 0.f, 0.f);
#pragma unroll
  for (int j = -12; j <= 12; j++) {
    int t = l + j;
    t = t < 0 ? 0 : (t > 1023 ? 1023 : t);
    float4 x = base[t * 64 + c4];
    acc.x += x.x; acc.y += x.y; acc.z += x.z; acc.w += x.w;
  }
  float4 x0 = base[l * 64 + c4];
  float4 o = make_float4(x0.x - acc.x * (1.f / 25.f), x0.y - acc.y * (1.f / 25.f),
                         x0.z - acc.z * (1.f / 25.f), x0.w - acc.w * (1.f / 25.f));
  ((float4*)(out + (long long)b * 262144))[l * 64 + c4] = o;
  if (fin && l == 1023) {
    float* f = fin + (long long)b * 768 + finoff + c4 * 4;
    f[0] = o.x; f[1] = o.y; f[2] = o.z; f[3] = o.w;
  }
}

// ------------- series_decomp bf16->bf16, XCD-clustered -------------
__global__ void decomp4b(const short* __restrict__ in, short* __restrict__ out)
{
  const int id = blockIdx.x;
  const int c = id & 7;
  const int s = id >> 3;
  const int b = c + 8 * (s >> 8);
  const int lg = s & 255;
  const int l = lg * 4 + (threadIdx.x >> 6);
  const int c4 = threadIdx.x & 63;
  const short4v* base = (const short4v*)(in + (long long)b * 262144);
  float4 acc = make_float4(0.f, 0.f, 0.f, 0.f);
#pragma unroll
  for (int j = -12; j <= 12; j++) {
    int t = l + j;
    t = t < 0 ? 0 : (t > 1023 ? 1023 : t);
    short4v x = base[t * 64 + c4];
    acc.x += bf2f(x[0]); acc.y += bf2f(x[1]);
    acc.z += bf2f(x[2]); acc.w += bf2f(x[3]);
  }
  short4v x0 = base[l * 64 + c4];
  short4v o;
  o[0] = f2bf(bf2f(x0[0]) - acc.x * (1.f / 25.f));
  o[1] = f2bf(bf2f(x0[1]) - acc.y * (1.f / 25.f));
  o[2] = f2bf(bf2f(x0[2]) - acc.z * (1.f / 25.f));
  o[3] = f2bf(bf2f(x0[3]) - acc.w * (1.f / 25.f));
  ((short4v*)(out + (long long)b * 262144))[l * 64 + c4] = o;
}

// ------------- top-20 + softmax, one wave per batch -------------
__global__ __launch_bounds__(64) void topk_softmax_wave(
    const float* __restrict__ mv, float* __restrict__ wts, int* __restrict__ dly)
{
  const int b = blockIdx.x, lane = threadIdx.x;
  float v[16];
#pragma unroll
  for (int j = 0; j < 16; j++) v[j] = mv[b * 1024 + lane + 64 * j];
  float selv = 0.f; int seli = 0;
  for (int it = 0; it < 20; it++) {
    float bv = -1e30f; int bi = 0x7fffffff;
#pragma unroll
    for (int j = 0; j < 16; j++) {
      float x = v[j]; int idx = lane + 64 * j;
      if (x > bv || (x == bv && idx < bi)) { bv = x; bi = idx; }
    }
#pragma unroll
    for (int off = 32; off > 0; off >>= 1) {
      float ov = __shfl_xor(bv, off, 64);
      int   oi = __shfl_xor(bi, off, 64);
      if (ov > bv || (ov == bv && oi < bi)) { bv = ov; bi = oi; }
    }
    if (lane == it) { selv = bv; seli = bi; }
    if ((bi & 63) == lane) v[bi >> 6] = -1e30f;
  }
  const float w0 = __shfl(selv, 0, 64);
  float e = (lane < 20) ? __expf(selv - w0) : 0.f;
  float s = e;
#pragma unroll
  for (int off = 32; off > 0; off >>= 1) s += __shfl_xor(s, off, 64);
  if (lane < 20) {
    wts[b * 20 + lane] = e / s;
    dly[b * 20 + lane] = seli;
  }
}

// ------------- delay aggregation on enc (fp32 in, bf16 out), XCD-clustered ---------
__global__ void agg4e(const float* __restrict__ enc, const float* __restrict__ wts,
                      const int* __restrict__ dly, short* __restrict__ out)
{
  const int id = blockIdx.x;
  const int c = id & 7;
  const int s = id >> 3;
  const int b = c + 8 * (s >> 8);
  const int lg = s & 255;
  const int l = lg * 4 + (threadIdx.x >> 6);
  const int c4 = threadIdx.x & 63;
  const float4* vb = (const float4*)(enc + (long long)b * 262144);
  float4 acc = make_float4(0.f, 0.f, 0.f, 0.f);
  for (int kk = 0; kk < 20; kk++) {
    int d = dly[b * 20 + kk];
    float w = wts[b * 20 + kk];
    float4 x = vb[((l + d) & 1023) * 64 + c4];
    acc.x += w * x.x; acc.y += w * x.y; acc.z += w * x.z; acc.w += w * x.w;
  }
  short4v o;
  o[0] = f2bf(acc.x); o[1] = f2bf(acc.y); o[2] = f2bf(acc.z); o[3] = f2bf(acc.w);
  ((short4v*)(out + (long long)b * 262144))[l * 64 + c4] = o;
}

// ------------- small helpers -------------
__global__ void init_bias(float* __restrict__ C, const float* __restrict__ bias)
{
  C[(long long)blockIdx.x * 256 + threadIdx.x] = bias[threadIdx.x];
}

__global__ void rp2_kernel(const float* __restrict__ x, const float* __restrict__ w,
                           const float* __restrict__ bias, float* __restrict__ out)
{
  __shared__ float red[4];
  int b = blockIdx.x, tid = threadIdx.x;
  float p = x[b * 256 + tid] * w[tid];
#pragma unroll
  for (int o = 32; o > 0; o >>= 1) p += __shfl_down(p, o, 64);
  if ((tid & 63) == 0) red[tid >> 6] = p;
  __syncthreads();
  if (tid == 0) out[b] = red[0] + red[1] + red[2] + red[3] + bias[0];
}

// =========================== host launch ===========================
static inline void gemm(hipStream_t s, const float* A, const float* B, float* C,
                        int M, int N, int K, int shift, const float* bias,
                        const float* res, int flags, int splitz = 1)
{
  dim3 g((N + 63) / 64, (M + 63) / 64, splitz);
  gemm_f32<<<g, dim3(256), 0, s>>>(A, B, C, M, N, K, shift, bias, res, flags);
}

extern "C" void kernel_launch(void* const* d_in, const int* in_sizes, int n_in,
                              void* d_out, int out_size, void* d_ws, size_t ws_size,
                              hipStream_t stream)
{
  const float* x_enc  = (const float*)d_in[0];
  const float* conv1_w= (const float*)d_in[1];
  const float* conv1_b= (const float*)d_in[2];
  const float* conv2_w= (const float*)d_in[3];
  const float* conv2_b= (const float*)d_in[4];
  const float* cnn_g  = (const float*)d_in[5];
  const float* cnn_b  = (const float*)d_in[6];
  const float* proj_w = (const float*)d_in[7];
  const float* proj_b = (const float*)d_in[8];
  const float* pln_g  = (const float*)d_in[9];
  const float* pln_b  = (const float*)d_in[10];
  const float* Wq     = (const float*)d_in[11];
  const float* bq     = (const float*)d_in[12];
  const float* Wk     = (const float*)d_in[13];
  const float* bk     = (const float*)d_in[14];
  const float* Wv     = (const float*)d_in[15];
  const float* bv     = (const float*)d_in[16];
  const float* Wo     = (const float*)d_in[17];
  const float* bo     = (const float*)d_in[18];
  const float* Wff1   = (const float*)d_in[19];
  const float* Wff2   = (const float*)d_in[20];
  const float* rp1_w  = (const float*)d_in[21];
  const float* rp1_b  = (const float*)d_in[22];
  const float* rln_g  = (const float*)d_in[23];
  const float* rln_b  = (const float*)d_in[24];
  const float* rp2_w  = (const float*)d_in[25];
  const float* rp2_b  = (const float*)d_in[26];
  (void)in_sizes; (void)n_in;

  const size_t BLD = 64ull * 1024 * 256;
  size_t need;
  {
    size_t o = 3 * BLD
             + 98304 + 131072 + 131072 + 262144 + 262144
             + 65536 + 512 + 1024
             + 65536 + 1280 + 1280 + 16384 + 49152 + 16384 + 16384;
    need = o * sizeof(float);
  }
  if (ws_size < need) {
    hipMemsetAsync(d_out, 0, (size_t)out_size * sizeof(float), stream);
    return;
  }

  float* ws = (float*)d_ws;
  size_t off = 0;
  auto alloc = [&](size_t n) { float* p = ws + off; off += n; return p; };
  float* BUF0 = alloc(BLD);   // conv1(bf16)/QKH/agg(bf16)/xd(bf16); WVO scratch
  float* BUF1 = alloc(BLD);   // conv2(fp32)/QKL/x(bf16)/ffn out(fp32)
  float* BUF2 = alloc(BLD);   // enc(fp32) / ffn hidden (bf16)
  short* CB2Tb = (short*)alloc(98304);
  short* QKTH  = (short*)alloc(131072);
  short* QKTL  = (short*)alloc(131072);
  short* WFF1b = (short*)alloc(262144);
  short* WFF2b = (short*)alloc(262144);
  short* WVOTb = (short*)alloc(65536);
  float* BVO  = alloc(512);
  float* BQK  = alloc(1024);
  float* MV   = alloc(65536);
  float* WTS  = alloc(1280);
  int*   DLY  = (int*)alloc(1280);
  float* PE   = alloc(16384);
  float* FIN  = alloc(49152);
  float* O1   = alloc(16384);
  float* O2   = alloc(16384);
  float* WVO  = BUF0;   // scratch, dead before conv1 writes BUF0

  const int M = 65536;
  dim3 blk(256);

  prep_weights<<<1024, blk, 0, stream>>>(conv2_w, Wq, Wk, Wff1, Wff2, bq, bk,
                                         CB2Tb, QKTH, QKTL, WFF1b, WFF2b, BQK);
  for (int i = 0; i < 2; i++)
    gemm(stream, Wv + (size_t)i * 65536, Wo + (size_t)i * 65536,
         WVO + (size_t)i * 65536, 256, 256, 256, 0, nullptr, nullptr, 0);
  vo_finish<<<516, blk, 0, stream>>>(WVO, Wo, bv, bo, WVOTb, BVO);

  // --- CNN frontend ---
  conv1_direct<<<dim3(16, 64), blk, 0, stream>>>(x_enc, conv1_w, conv1_b, (short*)BUF0);
  gemm_bf16_bt<<<dim3(512, 2), blk, 0, stream>>>(
      BUF0, CB2Tb, BUF1, nullptr, conv2_b, M, 256, 768, 256,
      FLAG_ABF16 | FLAG_RELU, 1);
  fixup_conv_b<<<128, blk, 0, stream>>>(BUF1, (const short*)BUF0, conv2_w, conv2_b);
  ln_rows4<<<16384, blk, 0, stream>>>(BUF1, BUF2, cnn_g, cnn_b, 0, 256, 0);

  // --- encoder layers (enc fp32 in BUF2) ---
  for (int i = 0; i < 2; i++) {
    short* QKH = (short*)BUF0;
    short* QKL = (short*)BUF1;
    gemm_qk<<<dim3(512, 4), blk, 0, stream>>>(
        BUF2, QKTH + (size_t)i * 131072, QKTL + (size_t)i * 131072,
        QKH, QKL, BQK + i * 512, M, 512, 256);
    hipMemsetAsync(MV, 0, 64 * 1024 * sizeof(float), stream);
    corr_mfma3<<<dim3(4096), blk, 0, stream>>>(QKH, QKL, MV);
    topk_softmax_wave<<<64, dim3(64), 0, stream>>>(MV, WTS, DLY);
    // fused v+o: x = enc + agg(enc) @ W_vo + b_vo  (x stored bf16)
    agg4e<<<dim3(16384), blk, 0, stream>>>(BUF2, WTS, DLY, (short*)BUF0);
    gemm_bf16_bt<<<dim3(512, 2), blk, 0, stream>>>(
        BUF0, WVOTb + (size_t)i * 65536, BUF1, BUF2, BVO + i * 256,
        M, 256, 256, 256, FLAG_ABF16 | FLAG_OBF16, 0);
    decomp4b<<<16384, blk, 0, stream>>>((const short*)BUF1, (short*)BUF0); // xd bf16
    // FFN: 2 chunks of 32768 rows; hidden bf16 in BUF2 (enc dead); out fp32 BUF1
    for (int c = 0; c < 2; c++) {
      const short* xd = (const short*)BUF0 + (size_t)c * 32768 * 256;
      gemm_bf16_bt<<<dim3(256, 8), blk, 0, stream>>>(
          xd, WFF1b + (size_t)i * 262144, BUF2, nullptr, nullptr,
          32768, 1024, 256, 256, FLAG_ABF16 | FLAG_GELU | FLAG_OBF16, 0);
      gemm_bf16_bt<<<dim3(256, 2), blk, 0, stream>>>(
          BUF2, WFF2b + (size_t)i * 262144, BUF1 + (size_t)c * 32768 * 256,
          (const float*)xd, nullptr,
          32768, 256, 1024, 1024, FLAG_ABF16 | FLAG_RESB16, 0);
    }
    decomp4<<<16384, blk, 0, stream>>>(BUF1, BUF2, FIN, i * 256); // enc + FIN row
  }

  // --- head (fp32, exact) ---
  init_bias<<<64, blk, 0, stream>>>(PE, proj_b);
  gemm(stream, x_enc, proj_w, PE, 64, 256, 16384, 0, nullptr, nullptr, 0, 32);
  ln_rows4<<<16, blk, 0, stream>>>(PE, FIN, pln_g, pln_b, 1, 768, 512);
  init_bias<<<64, blk, 0, stream>>>(O1, rp1_b);
  gemm(stream, FIN, rp1_w, O1, 64, 256, 768, 0, nullptr, nullptr, 0, 4);
  ln_rows4<<<16, blk, 0, stream>>>(O1, O2, rln_g, rln_b, 1, 256, 0);
  rp2_kernel<<<64, blk, 0, stream>>>(O2, rp2_w, rp2_b, (float*)d_out);
}

// Round 16
// 1569.225 us; speedup vs baseline: 1.2887x; 1.0892x over previous
//
#include <hip/hip_runtime.h>
#include <math.h>

#define FLAG_ACC     1
#define FLAG_RELU    2
#define FLAG_GELU    4
#define FLAG_ABF16   8
#define FLAG_OBF16  16
#define FLAG_RESB16 32

typedef __attribute__((ext_vector_type(8))) short short8;
typedef __attribute__((ext_vector_type(4))) short short4v;
typedef __attribute__((ext_vector_type(4))) float f32x4;

__device__ __forceinline__ short f2bf(float f) {
  unsigned u = __builtin_bit_cast(unsigned, f);
  unsigned r = u + 0x7fffu + ((u >> 16) & 1u);
  return (short)(r >> 16);
}
__device__ __forceinline__ float bf2f(short s) {
  unsigned u = ((unsigned)(unsigned short)s) << 16;
  return __builtin_bit_cast(float, u);
}
__device__ __forceinline__ void load_lds16(const void* g, void* lds) {
  __builtin_amdgcn_global_load_lds(
      (const __attribute__((address_space(1))) void*)g,
      (__attribute__((address_space(3))) void*)lds, 16, 0, 0);
}

// ---------------- generic fp32 tiled GEMM (head + W_vo prep) ----------------
__global__ __launch_bounds__(256) void gemm_f32(
    const float* __restrict__ A, const float* __restrict__ B, float* __restrict__ C,
    int M, int N, int K, int a_shift,
    const float* __restrict__ bias, const float* __restrict__ residual, int flags)
{
  __shared__ float As[16][65];
  __shared__ float Bs[16][64];
  const int tid = threadIdx.x;
  const int tx = tid & 15, ty = tid >> 4;
  const int row0 = blockIdx.y * 64;
  const int col0 = blockIdx.x * 64;
  int kbeg = 0, kend = K;
  if ((int)gridDim.z > 1) {
    int kchunk = ((K + (int)gridDim.z - 1) / (int)gridDim.z + 15) & ~15;
    kbeg = (int)blockIdx.z * kchunk;
    kend = min(K, kbeg + kchunk);
  }
  float acc[4][4] = {};
  const int a_m = tid >> 2;
  const int a_k = (tid & 3) << 2;
  const int b_n = (tid & 15) << 2;
  const int b_k = tid >> 4;
  for (int k0 = kbeg; k0 < kend; k0 += 16) {
    int srow = row0 + a_m + a_shift;
    float4 av = make_float4(0.f, 0.f, 0.f, 0.f);
    if (srow >= 0 && srow < M)
      av = *reinterpret_cast<const float4*>(A + (long long)srow * K + (k0 + a_k));
    As[a_k + 0][a_m] = av.x; As[a_k + 1][a_m] = av.y;
    As[a_k + 2][a_m] = av.z; As[a_k + 3][a_m] = av.w;
    float4 bv = make_float4(0.f, 0.f, 0.f, 0.f);
    int brow = k0 + b_k;
    if (brow < K)
      bv = *reinterpret_cast<const float4*>(B + (long long)brow * N + (col0 + b_n));
    Bs[b_k][b_n + 0] = bv.x; Bs[b_k][b_n + 1] = bv.y;
    Bs[b_k][b_n + 2] = bv.z; Bs[b_k][b_n + 3] = bv.w;
    __syncthreads();
#pragma unroll
    for (int kk = 0; kk < 16; kk++) {
      float ar[4], br[4];
#pragma unroll
      for (int i = 0; i < 4; i++) ar[i] = As[kk][ty * 4 + i];
#pragma unroll
      for (int j = 0; j < 4; j++) br[j] = Bs[kk][tx * 4 + j];
#pragma unroll
      for (int i = 0; i < 4; i++)
#pragma unroll
        for (int j = 0; j < 4; j++)
          acc[i][j] += ar[i] * br[j];
    }
    __syncthreads();
  }
  if ((int)gridDim.z > 1) {
#pragma unroll
    for (int i = 0; i < 4; i++) {
      int r = row0 + ty * 4 + i; if (r >= M) continue;
#pragma unroll
      for (int j = 0; j < 4; j++) {
        int c = col0 + tx * 4 + j; if (c >= N) continue;
        atomicAdd(&C[(long long)r * N + c], acc[i][j]);
      }
    }
    return;
  }
#pragma unroll
  for (int i = 0; i < 4; i++) {
    int r = row0 + ty * 4 + i; if (r >= M) continue;
#pragma unroll
    for (int j = 0; j < 4; j++) {
      int c = col0 + tx * 4 + j; if (c >= N) continue;
      float v = acc[i][j];
      if (bias)     v += bias[c];
      if (residual) v += residual[(long long)r * N + c];
      if (flags & FLAG_ACC)  v += C[(long long)r * N + c];
      if (flags & FLAG_RELU) v = fmaxf(v, 0.f);
      if (flags & FLAG_GELU) v = 0.5f * v * (1.f + erff(v * 0.70710678118654752f));
      C[(long long)r * N + c] = v;
    }
  }
}

// ---------------- bf16 MFMA GEMM: C[M,N] = A[M,K] @ Btb[N,K]^T (B pre-bf16) --------
__global__ __launch_bounds__(256) void gemm_bf16_bt(
    const void* __restrict__ Av, const short* __restrict__ Btb, void* __restrict__ Cv,
    const float* __restrict__ residual, const float* __restrict__ bias,
    int M, int N, int K, int lda, int flags, int tapped)
{
  __shared__ __align__(16) short Asl[4096];
  __shared__ __align__(16) short Bsl[4096];
  const int tid = threadIdx.x;
  const int row0 = blockIdx.x * 128;
  const int col0 = blockIdx.y * 128;
  const int lane = tid & 63;
  const int wave = tid >> 6;
  const int wm = (wave >> 1) * 64;
  const int wn = (wave & 1) * 64;
  const int fm = lane & 15;
  const int k8c = lane >> 4;
  const int mr = tid >> 1;
  const int mkc = (tid & 1) * 2;
  const int msw = (mr >> 1) & 3;
  const bool a_dma = (flags & FLAG_ABF16) && !tapped;

  f32x4 acc[4][4] = {};
  for (int k0 = 0; k0 < K; k0 += 32) {
    __syncthreads();
#pragma unroll
    for (int u = 0; u < 2; u++) {
      int p = (wave + u * 4) * 64 + lane;
      int r = p >> 2;
      int kc = (p & 3) ^ ((r >> 1) & 3);
      load_lds16(Btb + (long long)(col0 + r) * K + k0 + kc * 8,
                 (char*)Bsl + (wave + u * 4) * 1024);
    }
    if (a_dma) {
      const short* Ab = (const short*)Av;
#pragma unroll
      for (int u = 0; u < 2; u++) {
        int p = (wave + u * 4) * 64 + lane;
        int r = p >> 2;
        int kc = (p & 3) ^ ((r >> 1) & 3);
        load_lds16(Ab + (long long)(row0 + r) * lda + k0 + kc * 8,
                   (char*)Asl + (wave + u * 4) * 1024);
      }
    } else {
      int arow = row0 + mr + (tapped ? (k0 >> 8) - 1 : 0);
      int acol = tapped ? (k0 & 255) : k0;
      bool ok = (arow >= 0 && arow < M);
      short8 v0, v1;
      if (flags & FLAG_ABF16) {
        const short* ga = (const short*)Av + (long long)arow * lda + acol + mkc * 8;
        short8 z;
#pragma unroll
        for (int u = 0; u < 8; u++) z[u] = 0;
        v0 = ok ? *(const short8*)(ga) : z;
        v1 = ok ? *(const short8*)(ga + 8) : z;
      } else {
        const float* ga = (const float*)Av + (long long)arow * lda + acol + mkc * 8;
        float4 f0 = make_float4(0.f,0.f,0.f,0.f), f1 = f0, f2 = f0, f3 = f0;
        if (ok) {
          f0 = *(const float4*)(ga);     f1 = *(const float4*)(ga + 4);
          f2 = *(const float4*)(ga + 8); f3 = *(const float4*)(ga + 12);
        }
        v0[0]=f2bf(f0.x); v0[1]=f2bf(f0.y); v0[2]=f2bf(f0.z); v0[3]=f2bf(f0.w);
        v0[4]=f2bf(f1.x); v0[5]=f2bf(f1.y); v0[6]=f2bf(f1.z); v0[7]=f2bf(f1.w);
        v1[0]=f2bf(f2.x); v1[1]=f2bf(f2.y); v1[2]=f2bf(f2.z); v1[3]=f2bf(f2.w);
        v1[4]=f2bf(f3.x); v1[5]=f2bf(f3.y); v1[6]=f2bf(f3.z); v1[7]=f2bf(f3.w);
      }
      *(short8*)&Asl[(mr * 4 + (mkc ^ msw)) * 8] = v0;
      *(short8*)&Asl[(mr * 4 + ((mkc + 1) ^ msw)) * 8] = v1;
    }
    __syncthreads();
    short8 af[4], bf[4];
#pragma unroll
    for (int i = 0; i < 4; i++) {
      int r = wm + i * 16 + fm;
      af[i] = *(short8*)&Asl[(r * 4 + (k8c ^ ((r >> 1) & 3))) * 8];
    }
#pragma unroll
    for (int j = 0; j < 4; j++) {
      int r = wn + j * 16 + fm;
      bf[j] = *(short8*)&Bsl[(r * 4 + (k8c ^ ((r >> 1) & 3))) * 8];
    }
#pragma unroll
    for (int i = 0; i < 4; i++)
#pragma unroll
      for (int j = 0; j < 4; j++)
        acc[i][j] = __builtin_amdgcn_mfma_f32_16x16x32_bf16(af[i], bf[j], acc[i][j], 0, 0, 0);
  }
#pragma unroll
  for (int i = 0; i < 4; i++) {
    const int mbase = row0 + wm + i * 16 + (lane >> 4) * 4;
#pragma unroll
    for (int j = 0; j < 4; j++) {
      const int n = col0 + wn + j * 16 + fm;
      const float bs = bias ? bias[n] : 0.f;
#pragma unroll
      for (int r = 0; r < 4; r++) {
        long long idx = (long long)(mbase + r) * N + n;
        float v = acc[i][j][r] + bs;
        if (residual) {
          if (flags & FLAG_RESB16) v += bf2f(((const short*)residual)[idx]);
          else                     v += residual[idx];
        }
        if (flags & FLAG_ACC)  v += ((const float*)Cv)[idx];
        if (flags & FLAG_RELU) v = fmaxf(v, 0.f);
        if (flags & FLAG_GELU) v = 0.5f * v * (1.f + erff(v * 0.70710678118654752f));
        if (flags & FLAG_OBF16) ((short*)Cv)[idx] = f2bf(v);
        else                    ((float*)Cv)[idx] = v;
      }
    }
  }
}

// ---------------- q+k GEMM: A single bf16 (DMA), B pre-split h/l (DMA), 2 MFMAs ----
// q error dominated by enc rounding; A-lo term dropped. Output split-bf16 pairs.
__global__ __launch_bounds__(256) void gemm_qk2(
    const short* __restrict__ Ab, const short* __restrict__ Bth,
    const short* __restrict__ Btl,
    short* __restrict__ Ch, short* __restrict__ Cl,
    const float* __restrict__ bias, int M, int N, int K)
{
  __shared__ __align__(16) char smem[24576];
  short* Asl = (short*)smem;
  short* Bhi = (short*)(smem + 8192);
  short* Blo = (short*)(smem + 16384);
  const int tid = threadIdx.x;
  const int row0 = blockIdx.x * 128;
  const int col0 = blockIdx.y * 128;
  const int lane = tid & 63;
  const int wave = tid >> 6;
  const int wm = (wave >> 1) * 64;
  const int wn = (wave & 1) * 64;
  const int fm = lane & 15;
  const int k8c = lane >> 4;

  f32x4 acc[4][4] = {};
  for (int k0 = 0; k0 < K; k0 += 32) {
    __syncthreads();
#pragma unroll
    for (int u = 0; u < 2; u++) {
      int p = (wave + u * 4) * 64 + lane;
      int r = p >> 2;
      int kc = (p & 3) ^ ((r >> 1) & 3);
      long long ao = (long long)(row0 + r) * 256 + k0 + kc * 8;
      long long go = (long long)(col0 + r) * K + k0 + kc * 8;
      int lo = (wave + u * 4) * 1024;
      load_lds16(Ab + ao, (char*)Asl + lo);
      load_lds16(Bth + go, (char*)Bhi + lo);
      load_lds16(Btl + go, (char*)Blo + lo);
    }
    __syncthreads();
    short8 af[4], bh[4], bl[4];
#pragma unroll
    for (int i = 0; i < 4; i++) {
      int r = wm + i * 16 + fm;
      af[i] = *(short8*)&Asl[(r * 4 + (k8c ^ ((r >> 1) & 3))) * 8];
    }
#pragma unroll
    for (int j = 0; j < 4; j++) {
      int r = wn + j * 16 + fm;
      int p = (r * 4 + (k8c ^ ((r >> 1) & 3))) * 8;
      bh[j] = *(short8*)&Bhi[p];
      bl[j] = *(short8*)&Blo[p];
    }
#pragma unroll
    for (int i = 0; i < 4; i++)
#pragma unroll
      for (int j = 0; j < 4; j++) {
        acc[i][j] = __builtin_amdgcn_mfma_f32_16x16x32_bf16(af[i], bh[j], acc[i][j], 0, 0, 0);
        acc[i][j] = __builtin_amdgcn_mfma_f32_16x16x32_bf16(af[i], bl[j], acc[i][j], 0, 0, 0);
      }
  }
#pragma unroll
  for (int i = 0; i < 4; i++) {
    const int mbase = row0 + wm + i * 16 + (lane >> 4) * 4;
#pragma unroll
    for (int j = 0; j < 4; j++) {
      const int n = col0 + wn + j * 16 + fm;
      const float bs = bias ? bias[n] : 0.f;
#pragma unroll
      for (int r = 0; r < 4; r++) {
        long long idx = (long long)(mbase + r) * N + n;
        float v = acc[i][j][r] + bs;
        short h = f2bf(v);
        short l = f2bf(v - bf2f(h));
        Ch[idx] = h; Cl[idx] = l;
      }
    }
  }
}

// ------------- circular-correlation mean: BK=64 staging (4 rounds), 64 KB LDS ------
__global__ __launch_bounds__(256) void corr_mfma3(
    const short* __restrict__ qkh, const short* __restrict__ qkl, float* __restrict__ mv)
{
  __shared__ __align__(16) char smem[65536];
  short* Ahi = (short*)smem;
  short* Alo = (short*)(smem + 16384);
  short* Bhi = (short*)(smem + 32768);
  short* Blo = (short*)(smem + 49152);
  float* Sf = (float*)smem;

  const int id = blockIdx.x;
  const int b  = (id & 7) + 8 * (id >> 9);
  const int tile = (id >> 3) & 63;
  const int t0 = (tile >> 3) * 128;
  const int s0 = (tile & 7) * 128;
  const int tid = threadIdx.x;
  const int lane = tid & 63;
  const int wave = tid >> 6;
  const int wm = (wave >> 1) * 64;
  const int wn = (wave & 1) * 64;
  const int fm = lane & 15;
  const int k8c = lane >> 4;
  const long long bb = (long long)b * 524288;

  f32x4 acc[4][4] = {};
  for (int k0 = 0; k0 < 256; k0 += 64) {
    __syncthreads();
#pragma unroll
    for (int u = 0; u < 4; u++) {
      int p = (wave * 4 + u) * 64 + lane;
      int r = p >> 3;
      int kc = (p & 7) ^ (r & 7);
      long long qo = bb + (long long)(t0 + r) * 512 + k0 + kc * 8;
      long long ko = bb + (long long)(s0 + r) * 512 + 256 + k0 + kc * 8;
      int lo = (wave * 4 + u) * 1024;
      load_lds16(qkh + qo, (char*)Ahi + lo);
      load_lds16(qkl + qo, (char*)Alo + lo);
      load_lds16(qkh + ko, (char*)Bhi + lo);
      load_lds16(qkl + ko, (char*)Blo + lo);
    }
    __syncthreads();
#pragma unroll
    for (int kk8 = 0; kk8 < 8; kk8 += 4) {
      short8 ah[4], al[4], bh[4], bl[4];
#pragma unroll
      for (int i = 0; i < 4; i++) {
        int r = wm + i * 16 + fm;
        int p = (r * 8 + ((kk8 + k8c) ^ (r & 7))) * 8;
        ah[i] = *(short8*)&Ahi[p];
        al[i] = *(short8*)&Alo[p];
      }
#pragma unroll
      for (int j = 0; j < 4; j++) {
        int r = wn + j * 16 + fm;
        int p = (r * 8 + ((kk8 + k8c) ^ (r & 7))) * 8;
        bh[j] = *(short8*)&Bhi[p];
        bl[j] = *(short8*)&Blo[p];
      }
#pragma unroll
      for (int i = 0; i < 4; i++)
#pragma unroll
        for (int j = 0; j < 4; j++) {
          acc[i][j] = __builtin_amdgcn_mfma_f32_16x16x32_bf16(ah[i], bh[j], acc[i][j], 0, 0, 0);
          acc[i][j] = __builtin_amdgcn_mfma_f32_16x16x32_bf16(ah[i], bl[j], acc[i][j], 0, 0, 0);
          acc[i][j] = __builtin_amdgcn_mfma_f32_16x16x32_bf16(al[i], bh[j], acc[i][j], 0, 0, 0);
        }
    }
  }
  __syncthreads();   // staging reads done; reuse LDS as skewed S
#pragma unroll
  for (int i = 0; i < 4; i++) {
    const int row = wm + i * 16 + (lane >> 4) * 4;
#pragma unroll
    for (int j = 0; j < 4; j++) {
      const int col = wn + j * 16 + fm;
#pragma unroll
      for (int r = 0; r < 4; r++)
        Sf[(row + r) * 128 + ((2 * (row + r) - col) & 127)] =
            acc[i][j][r] * (1.f / 256.f);
    }
  }
  __syncthreads();
  {
    const int dd = tid & 127;
    const int mb = (tid >> 7) * 64;
    float s_ge = 0.f, s_lt = 0.f;
    for (int mm = 0; mm < 64; mm++) {
      int m = mb + mm;
      float v = Sf[m * 128 + ((dd + m) & 127)];
      if (m >= dd) s_ge += v; else s_lt += v;
    }
    atomicAdd(&mv[b * 1024 + ((t0 - s0 + dd) & 1023)], s_ge);
    atomicAdd(&mv[b * 1024 + ((t0 - s0 + dd - 128) & 1023)], s_lt);
  }
}

// ------------- one-shot weight prep -------------
__global__ void prep_weights(
    const float* __restrict__ conv2_w, const float* __restrict__ Wq,
    const float* __restrict__ Wk, const float* __restrict__ Wff1,
    const float* __restrict__ Wff2,
    const float* __restrict__ bq, const float* __restrict__ bk,
    short* __restrict__ CB2Tb, short* __restrict__ QKTH, short* __restrict__ QKTL,
    short* __restrict__ WFF1b, short* __restrict__ WFF2b, float* __restrict__ BQK)
{
  const int total = 196608 + 262144 + 524288 + 524288 + 1024;
  for (int idx = blockIdx.x * 256 + threadIdx.x; idx < total;
       idx += gridDim.x * 256) {
    int t = idx;
    if (t < 196608) {
      int o = t / 768, rem = t % 768, kk = rem >> 8, i = rem & 255;
      CB2Tb[t] = f2bf(conv2_w[(o * 256 + i) * 3 + kk]);
    } else if ((t -= 196608) < 262144) {
      int L = t >> 17, rem = t & 131071, r = rem >> 8, k = rem & 255;
      float val = (r < 256) ? Wq[L * 65536 + k * 256 + r]
                            : Wk[L * 65536 + k * 256 + (r - 256)];
      short h = f2bf(val);
      QKTH[t] = h;
      QKTL[t] = f2bf(val - bf2f(h));
    } else if ((t -= 262144) < 524288) {
      WFF1b[t] = f2bf(Wff1[t]);
    } else if ((t -= 524288) < 524288) {
      WFF2b[t] = f2bf(Wff2[t]);
    } else {
      t -= 524288;
      int L = t >> 9, j = t & 511;
      BQK[t] = (j < 256) ? bq[L * 256 + j] : bk[L * 256 + (j - 256)];
    }
  }
}

// ------------- W_vo finish -------------
__global__ void vo_finish(const float* __restrict__ WVO, const float* __restrict__ Wo,
                          const float* __restrict__ bv, const float* __restrict__ bo,
                          short* __restrict__ WVOTb, float* __restrict__ BVO)
{
  const int total = 131072 + 512;
  for (int idx = blockIdx.x * 256 + threadIdx.x; idx < total;
       idx += gridDim.x * 256) {
    if (idx < 131072) {
      int L = idx >> 16, rem = idx & 65535, n = rem >> 8, k = rem & 255;
      WVOTb[idx] = f2bf(WVO[L * 65536 + k * 256 + n]);
    } else {
      int j = idx - 131072;
      int L = j >> 8, n = j & 255;
      float acc = bo[L * 256 + n];
      for (int k = 0; k < 256; k++)
        acc += bv[L * 256 + k] * Wo[(long long)L * 65536 + k * 256 + n];
      BVO[j] = acc;
    }
  }
}

// ------------- conv1 direct -> bf16 out -------------
__global__ __launch_bounds__(256) void conv1_direct(
    const float* __restrict__ x, const float* __restrict__ w,
    const float* __restrict__ bias, short* __restrict__ out)
{
  __shared__ float xs[66][16];
  const int b = blockIdx.y, lg = blockIdx.x, tid = threadIdx.x;
  const int l0 = lg * 64;
  for (int idx = tid; idx < 1056; idx += 256) {
    int r = idx >> 4, c = idx & 15;
    int l = l0 + r - 1;
    xs[r][c] = (l >= 0 && l < 1024) ? x[((long long)b * 1024 + l) * 16 + c] : 0.f;
  }
  float wr[48];
#pragma unroll
  for (int u = 0; u < 48; u++) wr[u] = w[tid * 48 + u];
  const float bs = bias[tid];
  __syncthreads();
  for (int r = 0; r < 64; r++) {
    float acc = bs;
#pragma unroll
    for (int i = 0; i < 16; i++) {
      acc += xs[r + 0][i] * wr[i * 3 + 0];
      acc += xs[r + 1][i] * wr[i * 3 + 1];
      acc += xs[r + 2][i] * wr[i * 3 + 2];
    }
    out[((long long)b * 1024 + l0 + r) * 256 + tid] = f2bf(fmaxf(acc, 0.f));
  }
}

// ------------- conv2 batch-edge fixup (bf16 src rows) -------------
__global__ void fixup_conv_b(float* __restrict__ h, const short* __restrict__ src,
                             const float* __restrict__ w, const float* __restrict__ bias)
{
  int b = blockIdx.x >> 1;
  int l = (blockIdx.x & 1) ? 1023 : 0;
  int o = threadIdx.x;
  float acc = bias[o];
  for (int kk = 0; kk < 3; kk++) {
    int t = l + kk - 1;
    if (t < 0 || t > 1023) continue;
    const short* srow = src + ((long long)b * 1024 + t) * 256;
    const float* wrow = w + (long long)o * 256 * 3 + kk;
    for (int i = 0; i < 256; i++) acc += bf2f(srow[i]) * wrow[(long long)i * 3];
  }
  h[((long long)b * 1024 + l) * 256 + o] = fmaxf(acc, 0.f);
}

// ------------- LayerNorm fp32 out (head path) -------------
__global__ __launch_bounds__(256) void ln_rows4(
    const float* __restrict__ in, float* __restrict__ out,
    const float* __restrict__ g, const float* __restrict__ b,
    int prerelu, int out_stride, int out_off)
{
  const int row = blockIdx.x * 4 + (threadIdx.x >> 6);
  const int lane = threadIdx.x & 63;
  float4 x = ((const float4*)(in + (long long)row * 256))[lane];
  if (prerelu) {
    x.x = fmaxf(x.x, 0.f); x.y = fmaxf(x.y, 0.f);
    x.z = fmaxf(x.z, 0.f); x.w = fmaxf(x.w, 0.f);
  }
  float s = x.x + x.y + x.z + x.w;
#pragma unroll
  for (int o = 32; o > 0; o >>= 1) s += __shfl_xor(s, o, 64);
  float mean = s * (1.f / 256.f);
  float4 d = make_float4(x.x - mean, x.y - mean, x.z - mean, x.w - mean);
  float s2 = d.x * d.x + d.y * d.y + d.z * d.z + d.w * d.w;
#pragma unroll
  for (int o = 32; o > 0; o >>= 1) s2 += __shfl_xor(s2, o, 64);
  float rsd = rsqrtf(s2 * (1.f / 256.f) + 1e-5f);
  float4 gg = ((const float4*)g)[lane];
  float4 bb = ((const float4*)b)[lane];
  float4 o4 = make_float4(d.x * rsd * gg.x + bb.x, d.y * rsd * gg.y + bb.y,
                          d.z * rsd * gg.z + bb.z, d.w * rsd * gg.w + bb.w);
  ((float4*)(out + (long long)row * out_stride + out_off))[lane] = o4;
}

// ------------- LayerNorm bf16 out (enc producer) -------------
__global__ __launch_bounds__(256) void ln_rows4b(
    const float* __restrict__ in, short* __restrict__ out,
    const float* __restrict__ g, const float* __restrict__ b)
{
  const int row = blockIdx.x * 4 + (threadIdx.x >> 6);
  const int lane = threadIdx.x & 63;
  float4 x = ((const float4*)(in + (long long)row * 256))[lane];
  float s = x.x + x.y + x.z + x.w;
#pragma unroll
  for (int o = 32; o > 0; o >>= 1) s += __shfl_xor(s, o, 64);
  float mean = s * (1.f / 256.f);
  float4 d = make_float4(x.x - mean, x.y - mean, x.z - mean, x.w - mean);
  float s2 = d.x * d.x + d.y * d.y + d.z * d.z + d.w * d.w;
#pragma unroll
  for (int o = 32; o > 0; o >>= 1) s2 += __shfl_xor(s2, o, 64);
  float rsd = rsqrtf(s2 * (1.f / 256.f) + 1e-5f);
  float4 gg = ((const float4*)g)[lane];
  float4 bb = ((const float4*)b)[lane];
  short4v o4;
  o4[0] = f2bf(d.x * rsd * gg.x + bb.x);
  o4[1] = f2bf(d.y * rsd * gg.y + bb.y);
  o4[2] = f2bf(d.z * rsd * gg.z + bb.z);
  o4[3] = f2bf(d.w * rsd * gg.w + bb.w);
  ((short4v*)out)[(long long)row * 64 + lane] = o4;
}

// ------------- series_decomp fp32 -> bf16 enc (+fp32 FIN pool row), XCD-clustered --
__global__ void decomp4be(const float* __restrict__ in, short* __restrict__ out,
                          float* __restrict__ fin, int finoff)
{
  const int id = blockIdx.x;
  const int c = id & 7;
  const int s = id >> 3;
  const int b = c + 8 * (s >> 8);
  const int lg = s & 255;
  const int l = lg * 4 + (threadIdx.x >> 6);
  const int c4 = threadIdx.x & 63;
  const float4* base = (const float4*)(in + (long long)b * 262144);
  float4 acc = make_float4(0.f, 0.f, 0.f, 0.f);
#pragma unroll
  for (int j = -12; j <= 12; j++) {
    int t = l + j;
    t = t < 0 ? 0 : (t > 1023 ? 1023 : t);
    float4 x = base[t * 64 + c4];
    acc.x += x.x; acc.y += x.y; acc.z += x.z; acc.w += x.w;
  }
  float4 x0 = base[l * 64 + c4];
  float4 o = make_float4(x0.x - acc.x * (1.f / 25.f), x0.y - acc.y * (1.f / 25.f),
                         x0.z - acc.z * (1.f / 25.f), x0.w - acc.w * (1.f / 25.f));
  short4v ob;
  ob[0] = f2bf(o.x); ob[1] = f2bf(o.y); ob[2] = f2bf(o.z); ob[3] = f2bf(o.w);
  ((short4v*)out)[((long long)b * 1024 + l) * 64 + c4] = ob;
  if (l == 1023) {
    float* f = fin + (long long)b * 768 + finoff + c4 * 4;
    f[0] = o.x; f[1] = o.y; f[2] = o.z; f[3] = o.w;
  }
}

// ------------- series_decomp bf16->bf16, XCD-clustered -------------
__global__ void decomp4b(const short* __restrict__ in, short* __restrict__ out)
{
  const int id = blockIdx.x;
  const int c = id & 7;
  const int s = id >> 3;
  const int b = c + 8 * (s >> 8);
  const int lg = s & 255;
  const int l = lg * 4 + (threadIdx.x >> 6);
  const int c4 = threadIdx.x & 63;
  const short4v* base = (const short4v*)(in + (long long)b * 262144);
  float4 acc = make_float4(0.f, 0.f, 0.f, 0.f);
#pragma unroll
  for (int j = -12; j <= 12; j++) {
    int t = l + j;
    t = t < 0 ? 0 : (t > 1023 ? 1023 : t);
    short4v x = base[t * 64 + c4];
    acc.x += bf2f(x[0]); acc.y += bf2f(x[1]);
    acc.z += bf2f(x[2]); acc.w += bf2f(x[3]);
  }
  short4v x0 = base[l * 64 + c4];
  short4v o;
  o[0] = f2bf(bf2f(x0[0]) - acc.x * (1.f / 25.f));
  o[1] = f2bf(bf2f(x0[1]) - acc.y * (1.f / 25.f));
  o[2] = f2bf(bf2f(x0[2]) - acc.z * (1.f / 25.f));
  o[3] = f2bf(bf2f(x0[3]) - acc.w * (1.f / 25.f));
  ((short4v*)(out + (long long)b * 262144))[l * 64 + c4] = o;
}

// ------------- top-20 + softmax, one wave per batch -------------
__global__ __launch_bounds__(64) void topk_softmax_wave(
    const float* __restrict__ mv, float* __restrict__ wts, int* __restrict__ dly)
{
  const int b = blockIdx.x, lane = threadIdx.x;
  float v[16];
#pragma unroll
  for (int j = 0; j < 16; j++) v[j] = mv[b * 1024 + lane + 64 * j];
  float selv = 0.f; int seli = 0;
  for (int it = 0; it < 20; it++) {
    float bv = -1e30f; int bi = 0x7fffffff;
#pragma unroll
    for (int j = 0; j < 16; j++) {
      float x = v[j]; int idx = lane + 64 * j;
      if (x > bv || (x == bv && idx < bi)) { bv = x; bi = idx; }
    }
#pragma unroll
    for (int off = 32; off > 0; off >>= 1) {
      float ov = __shfl_xor(bv, off, 64);
      int   oi = __shfl_xor(bi, off, 64);
      if (ov > bv || (ov == bv && oi < bi)) { bv = ov; bi = oi; }
    }
    if (lane == it) { selv = bv; seli = bi; }
    if ((bi & 63) == lane) v[bi >> 6] = -1e30f;
  }
  const float w0 = __shfl(selv, 0, 64);
  float e = (lane < 20) ? __expf(selv - w0) : 0.f;
  float s = e;
#pragma unroll
  for (int off = 32; off > 0; off >>= 1) s += __shfl_xor(s, off, 64);
  if (lane < 20) {
    wts[b * 20 + lane] = e / s;
    dly[b * 20 + lane] = seli;
  }
}

// ------------- delay aggregation bf16 enc -> bf16 out, XCD-clustered ---------------
__global__ void agg4b(const short* __restrict__ enc, const float* __restrict__ wts,
                      const int* __restrict__ dly, short* __restrict__ out)
{
  const int id = blockIdx.x;
  const int c = id & 7;
  const int s = id >> 3;
  const int b = c + 8 * (s >> 8);
  const int lg = s & 255;
  const int l = lg * 4 + (threadIdx.x >> 6);
  const int c4 = threadIdx.x & 63;
  const short4v* vb = (const short4v*)(enc + (long long)b * 262144);
  float4 acc = make_float4(0.f, 0.f, 0.f, 0.f);
  for (int kk = 0; kk < 20; kk++) {
    int d = dly[b * 20 + kk];
    float w = wts[b * 20 + kk];
    short4v x = vb[((l + d) & 1023) * 64 + c4];
    acc.x += w * bf2f(x[0]); acc.y += w * bf2f(x[1]);
    acc.z += w * bf2f(x[2]); acc.w += w * bf2f(x[3]);
  }
  short4v o;
  o[0] = f2bf(acc.x); o[1] = f2bf(acc.y); o[2] = f2bf(acc.z); o[3] = f2bf(acc.w);
  ((short4v*)(out + (long long)b * 262144))[l * 64 + c4] = o;
}

// ------------- small helpers -------------
__global__ void init_bias(float* __restrict__ C, const float* __restrict__ bias)
{
  C[(long long)blockIdx.x * 256 + threadIdx.x] = bias[threadIdx.x];
}

__global__ void rp2_kernel(const float* __restrict__ x, const float* __restrict__ w,
                           const float* __restrict__ bias, float* __restrict__ out)
{
  __shared__ float red[4];
  int b = blockIdx.x, tid = threadIdx.x;
  float p = x[b * 256 + tid] * w[tid];
#pragma unroll
  for (int o = 32; o > 0; o >>= 1) p += __shfl_down(p, o, 64);
  if ((tid & 63) == 0) red[tid >> 6] = p;
  __syncthreads();
  if (tid == 0) out[b] = red[0] + red[1] + red[2] + red[3] + bias[0];
}

// =========================== host launch ===========================
static inline void gemm(hipStream_t s, const float* A, const float* B, float* C,
                        int M, int N, int K, int shift, const float* bias,
                        const float* res, int flags, int splitz = 1)
{
  dim3 g((N + 63) / 64, (M + 63) / 64, splitz);
  gemm_f32<<<g, dim3(256), 0, s>>>(A, B, C, M, N, K, shift, bias, res, flags);
}

extern "C" void kernel_launch(void* const* d_in, const int* in_sizes, int n_in,
                              void* d_out, int out_size, void* d_ws, size_t ws_size,
                              hipStream_t stream)
{
  const float* x_enc  = (const float*)d_in[0];
  const float* conv1_w= (const float*)d_in[1];
  const float* conv1_b= (const float*)d_in[2];
  const float* conv2_w= (const float*)d_in[3];
  const float* conv2_b= (const float*)d_in[4];
  const float* cnn_g  = (const float*)d_in[5];
  const float* cnn_b  = (const float*)d_in[6];
  const float* proj_w = (const float*)d_in[7];
  const float* proj_b = (const float*)d_in[8];
  const float* pln_g  = (const float*)d_in[9];
  const float* pln_b  = (const float*)d_in[10];
  const float* Wq     = (const float*)d_in[11];
  const float* bq     = (const float*)d_in[12];
  const float* Wk     = (const float*)d_in[13];
  const float* bk     = (const float*)d_in[14];
  const float* Wv     = (const float*)d_in[15];
  const float* bv     = (const float*)d_in[16];
  const float* Wo     = (const float*)d_in[17];
  const float* bo     = (const float*)d_in[18];
  const float* Wff1   = (const float*)d_in[19];
  const float* Wff2   = (const float*)d_in[20];
  const float* rp1_w  = (const float*)d_in[21];
  const float* rp1_b  = (const float*)d_in[22];
  const float* rln_g  = (const float*)d_in[23];
  const float* rln_b  = (const float*)d_in[24];
  const float* rp2_w  = (const float*)d_in[25];
  const float* rp2_b  = (const float*)d_in[26];
  (void)in_sizes; (void)n_in;

  const size_t BLD = 64ull * 1024 * 256;
  size_t need;
  {
    size_t o = 3 * BLD
             + 98304 + 131072 + 131072 + 262144 + 262144
             + 65536 + 512 + 1024
             + 65536 + 1280 + 1280 + 16384 + 49152 + 16384 + 16384;
    need = o * sizeof(float);
  }
  if (ws_size < need) {
    hipMemsetAsync(d_out, 0, (size_t)out_size * sizeof(float), stream);
    return;
  }

  float* ws = (float*)d_ws;
  size_t off = 0;
  auto alloc = [&](size_t n) { float* p = ws + off; off += n; return p; };
  float* BUF0 = alloc(BLD);   // conv1(bf16)/QKH/agg(bf16)/xd(bf16); WVO scratch
  float* BUF1 = alloc(BLD);   // conv2(fp32)/QKL/x(bf16)/ffn out(fp32)
  float* BUF2 = alloc(BLD);   // enc(bf16, first half) / ffn hidden (bf16, full)
  short* CB2Tb = (short*)alloc(98304);
  short* QKTH  = (short*)alloc(131072);
  short* QKTL  = (short*)alloc(131072);
  short* WFF1b = (short*)alloc(262144);
  short* WFF2b = (short*)alloc(262144);
  short* WVOTb = (short*)alloc(65536);
  float* BVO  = alloc(512);
  float* BQK  = alloc(1024);
  float* MV   = alloc(65536);
  float* WTS  = alloc(1280);
  int*   DLY  = (int*)alloc(1280);
  float* PE   = alloc(16384);
  float* FIN  = alloc(49152);
  float* O1   = alloc(16384);
  float* O2   = alloc(16384);
  float* WVO  = BUF0;   // scratch, dead before conv1 writes BUF0
  short* ENC  = (short*)BUF2;

  const int M = 65536;
  dim3 blk(256);

  prep_weights<<<1024, blk, 0, stream>>>(conv2_w, Wq, Wk, Wff1, Wff2, bq, bk,
                                         CB2Tb, QKTH, QKTL, WFF1b, WFF2b, BQK);
  for (int i = 0; i < 2; i++)
    gemm(stream, Wv + (size_t)i * 65536, Wo + (size_t)i * 65536,
         WVO + (size_t)i * 65536, 256, 256, 256, 0, nullptr, nullptr, 0);
  vo_finish<<<516, blk, 0, stream>>>(WVO, Wo, bv, bo, WVOTb, BVO);

  // --- CNN frontend ---
  conv1_direct<<<dim3(16, 64), blk, 0, stream>>>(x_enc, conv1_w, conv1_b, (short*)BUF0);
  gemm_bf16_bt<<<dim3(512, 2), blk, 0, stream>>>(
      BUF0, CB2Tb, BUF1, nullptr, conv2_b, M, 256, 768, 256,
      FLAG_ABF16 | FLAG_RELU, 1);
  fixup_conv_b<<<128, blk, 0, stream>>>(BUF1, (const short*)BUF0, conv2_w, conv2_b);
  ln_rows4b<<<16384, blk, 0, stream>>>(BUF1, ENC, cnn_g, cnn_b);

  // --- encoder layers (enc bf16 in BUF2) ---
  for (int i = 0; i < 2; i++) {
    short* QKH = (short*)BUF0;
    short* QKL = (short*)BUF1;
    gemm_qk2<<<dim3(512, 4), blk, 0, stream>>>(
        ENC, QKTH + (size_t)i * 131072, QKTL + (size_t)i * 131072,
        QKH, QKL, BQK + i * 512, M, 512, 256);
    hipMemsetAsync(MV, 0, 64 * 1024 * sizeof(float), stream);
    corr_mfma3<<<dim3(4096), blk, 0, stream>>>(QKH, QKL, MV);
    topk_softmax_wave<<<64, dim3(64), 0, stream>>>(MV, WTS, DLY);
    // fused v+o: x = enc + agg(enc) @ W_vo + b_vo  (x stored bf16)
    agg4b<<<dim3(16384), blk, 0, stream>>>(ENC, WTS, DLY, (short*)BUF0);
    gemm_bf16_bt<<<dim3(512, 2), blk, 0, stream>>>(
        BUF0, WVOTb + (size_t)i * 65536, BUF1, (const float*)ENC, BVO + i * 256,
        M, 256, 256, 256, FLAG_ABF16 | FLAG_OBF16 | FLAG_RESB16, 0);
    decomp4b<<<16384, blk, 0, stream>>>((const short*)BUF1, (short*)BUF0); // xd bf16
    // FFN: 2 chunks of 32768 rows; hidden bf16 in BUF2 (enc dead); out fp32 BUF1
    for (int c = 0; c < 2; c++) {
      const short* xd = (const short*)BUF0 + (size_t)c * 32768 * 256;
      gemm_bf16_bt<<<dim3(256, 8), blk, 0, stream>>>(
          xd, WFF1b + (size_t)i * 262144, BUF2, nullptr, nullptr,
          32768, 1024, 256, 256, FLAG_ABF16 | FLAG_GELU | FLAG_OBF16, 0);
      gemm_bf16_bt<<<dim3(256, 2), blk, 0, stream>>>(
          BUF2, WFF2b + (size_t)i * 262144, BUF1 + (size_t)c * 32768 * 256,
          (const float*)xd, nullptr,
          32768, 256, 1024, 1024, FLAG_ABF16 | FLAG_RESB16, 0);
    }
    decomp4be<<<16384, blk, 0, stream>>>(BUF1, ENC, FIN, i * 256); // enc bf16 + FIN
  }

  // --- head (fp32, exact) ---
  init_bias<<<64, blk, 0, stream>>>(PE, proj_b);
  gemm(stream, x_enc, proj_w, PE, 64, 256, 16384, 0, nullptr, nullptr, 0, 32);
  ln_rows4<<<16, blk, 0, stream>>>(PE, FIN, pln_g, pln_b, 1, 768, 512);
  init_bias<<<64, blk, 0, stream>>>(O1, rp1_b);
  gemm(stream, FIN, rp1_w, O1, 64, 256, 768, 0, nullptr, nullptr, 0, 4);
  ln_rows4<<<16, blk, 0, stream>>>(O1, O2, rln_g, rln_b, 1, 256, 0);
  rp2_kernel<<<64, blk, 0, stream>>>(O2, rp2_w, rp2_b, (float*)d_out);
}

// Round 17
// 1530.971 us; speedup vs baseline: 1.3209x; 1.0250x over previous
//
#include <hip/hip_runtime.h>
#include <math.h>

#define FLAG_ACC     1
#define FLAG_RELU    2
#define FLAG_GELU    4
#define FLAG_ABF16   8
#define FLAG_OBF16  16
#define FLAG_RESB16 32

typedef __attribute__((ext_vector_type(8))) short short8;
typedef __attribute__((ext_vector_type(4))) short short4v;
typedef __attribute__((ext_vector_type(4))) float f32x4;

__device__ __forceinline__ short f2bf(float f) {
  unsigned u = __builtin_bit_cast(unsigned, f);
  unsigned r = u + 0x7fffu + ((u >> 16) & 1u);
  return (short)(r >> 16);
}
__device__ __forceinline__ float bf2f(short s) {
  unsigned u = ((unsigned)(unsigned short)s) << 16;
  return __builtin_bit_cast(float, u);
}
__device__ __forceinline__ void load_lds16(const void* g, void* lds) {
  __builtin_amdgcn_global_load_lds(
      (const __attribute__((address_space(1))) void*)g,
      (__attribute__((address_space(3))) void*)lds, 16, 0, 0);
}

// ---------------- generic fp32 tiled GEMM (head + W_vo prep) ----------------
__global__ __launch_bounds__(256) void gemm_f32(
    const float* __restrict__ A, const float* __restrict__ B, float* __restrict__ C,
    int M, int N, int K, int a_shift,
    const float* __restrict__ bias, const float* __restrict__ residual, int flags)
{
  __shared__ float As[16][65];
  __shared__ float Bs[16][64];
  const int tid = threadIdx.x;
  const int tx = tid & 15, ty = tid >> 4;
  const int row0 = blockIdx.y * 64;
  const int col0 = blockIdx.x * 64;
  int kbeg = 0, kend = K;
  if ((int)gridDim.z > 1) {
    int kchunk = ((K + (int)gridDim.z - 1) / (int)gridDim.z + 15) & ~15;
    kbeg = (int)blockIdx.z * kchunk;
    kend = min(K, kbeg + kchunk);
  }
  float acc[4][4] = {};
  const int a_m = tid >> 2;
  const int a_k = (tid & 3) << 2;
  const int b_n = (tid & 15) << 2;
  const int b_k = tid >> 4;
  for (int k0 = kbeg; k0 < kend; k0 += 16) {
    int srow = row0 + a_m + a_shift;
    float4 av = make_float4(0.f, 0.f, 0.f, 0.f);
    if (srow >= 0 && srow < M)
      av = *reinterpret_cast<const float4*>(A + (long long)srow * K + (k0 + a_k));
    As[a_k + 0][a_m] = av.x; As[a_k + 1][a_m] = av.y;
    As[a_k + 2][a_m] = av.z; As[a_k + 3][a_m] = av.w;
    float4 bv = make_float4(0.f, 0.f, 0.f, 0.f);
    int brow = k0 + b_k;
    if (brow < K)
      bv = *reinterpret_cast<const float4*>(B + (long long)brow * N + (col0 + b_n));
    Bs[b_k][b_n + 0] = bv.x; Bs[b_k][b_n + 1] = bv.y;
    Bs[b_k][b_n + 2] = bv.z; Bs[b_k][b_n + 3] = bv.w;
    __syncthreads();
#pragma unroll
    for (int kk = 0; kk < 16; kk++) {
      float ar[4], br[4];
#pragma unroll
      for (int i = 0; i < 4; i++) ar[i] = As[kk][ty * 4 + i];
#pragma unroll
      for (int j = 0; j < 4; j++) br[j] = Bs[kk][tx * 4 + j];
#pragma unroll
      for (int i = 0; i < 4; i++)
#pragma unroll
        for (int j = 0; j < 4; j++)
          acc[i][j] += ar[i] * br[j];
    }
    __syncthreads();
  }
  if ((int)gridDim.z > 1) {
#pragma unroll
    for (int i = 0; i < 4; i++) {
      int r = row0 + ty * 4 + i; if (r >= M) continue;
#pragma unroll
      for (int j = 0; j < 4; j++) {
        int c = col0 + tx * 4 + j; if (c >= N) continue;
        atomicAdd(&C[(long long)r * N + c], acc[i][j]);
      }
    }
    return;
  }
#pragma unroll
  for (int i = 0; i < 4; i++) {
    int r = row0 + ty * 4 + i; if (r >= M) continue;
#pragma unroll
    for (int j = 0; j < 4; j++) {
      int c = col0 + tx * 4 + j; if (c >= N) continue;
      float v = acc[i][j];
      if (bias)     v += bias[c];
      if (residual) v += residual[(long long)r * N + c];
      if (flags & FLAG_ACC)  v += C[(long long)r * N + c];
      if (flags & FLAG_RELU) v = fmaxf(v, 0.f);
      if (flags & FLAG_GELU) v = 0.5f * v * (1.f + erff(v * 0.70710678118654752f));
      C[(long long)r * N + c] = v;
    }
  }
}

// ---------------- bf16 MFMA GEMM, BK=64: C[M,N] = A[M,K] @ Btb[N,K]^T --------------
// LDS 128 rows x 8 chunks x 8 shorts = 16 KB/array; swizzle phys = kc ^ (r&7).
// K % 64 == 0 required. Accumulation order identical to two BK=32 rounds.
__global__ __launch_bounds__(256) void gemm_bf16_bt(
    const void* __restrict__ Av, const short* __restrict__ Btb, void* __restrict__ Cv,
    const float* __restrict__ residual, const float* __restrict__ bias,
    int M, int N, int K, int lda, int flags, int tapped)
{
  __shared__ __align__(16) short Asl[8192];
  __shared__ __align__(16) short Bsl[8192];
  const int tid = threadIdx.x;
  const int row0 = blockIdx.x * 128;
  const int col0 = blockIdx.y * 128;
  const int lane = tid & 63;
  const int wave = tid >> 6;
  const int wm = (wave >> 1) * 64;
  const int wn = (wave & 1) * 64;
  const int fm = lane & 15;
  const int k8c = lane >> 4;
  const int mr = tid >> 1;
  const int mkc = (tid & 1) * 4;
  const int msw = mr & 7;
  const bool a_dma = (flags & FLAG_ABF16) && !tapped;

  f32x4 acc[4][4] = {};
  for (int k0 = 0; k0 < K; k0 += 64) {
    __syncthreads();
#pragma unroll
    for (int u = 0; u < 4; u++) {           // B via DMA
      int p = (wave * 4 + u) * 64 + lane;
      int r = p >> 3;
      int kc = (p & 7) ^ (r & 7);
      load_lds16(Btb + (long long)(col0 + r) * K + k0 + kc * 8,
                 (char*)Bsl + (wave * 4 + u) * 1024);
    }
    if (a_dma) {
      const short* Ab = (const short*)Av;
#pragma unroll
      for (int u = 0; u < 4; u++) {
        int p = (wave * 4 + u) * 64 + lane;
        int r = p >> 3;
        int kc = (p & 7) ^ (r & 7);
        load_lds16(Ab + (long long)(row0 + r) * lda + k0 + kc * 8,
                   (char*)Asl + (wave * 4 + u) * 1024);
      }
    } else {
      int arow = row0 + mr + (tapped ? (k0 >> 8) - 1 : 0);
      int acol = tapped ? (k0 & 255) : k0;
      bool ok = (arow >= 0 && arow < M);
      if (flags & FLAG_ABF16) {
        const short* ga = (const short*)Av + (long long)arow * lda + acol + mkc * 8;
        short8 z;
#pragma unroll
        for (int u = 0; u < 8; u++) z[u] = 0;
#pragma unroll
        for (int j = 0; j < 4; j++) {
          short8 v = ok ? *(const short8*)(ga + j * 8) : z;
          *(short8*)&Asl[(mr * 8 + ((mkc + j) ^ msw)) * 8] = v;
        }
      } else {
        const float* ga = (const float*)Av + (long long)arow * lda + acol + mkc * 8;
#pragma unroll
        for (int j = 0; j < 4; j++) {
          float4 f0 = make_float4(0.f,0.f,0.f,0.f), f1 = f0;
          if (ok) { f0 = *(const float4*)(ga + j * 8); f1 = *(const float4*)(ga + j * 8 + 4); }
          short8 v;
          v[0]=f2bf(f0.x); v[1]=f2bf(f0.y); v[2]=f2bf(f0.z); v[3]=f2bf(f0.w);
          v[4]=f2bf(f1.x); v[5]=f2bf(f1.y); v[6]=f2bf(f1.z); v[7]=f2bf(f1.w);
          *(short8*)&Asl[(mr * 8 + ((mkc + j) ^ msw)) * 8] = v;
        }
      }
    }
    __syncthreads();
#pragma unroll
    for (int kk8 = 0; kk8 < 8; kk8 += 4) {
      short8 af[4], bf[4];
#pragma unroll
      for (int i = 0; i < 4; i++) {
        int r = wm + i * 16 + fm;
        af[i] = *(short8*)&Asl[(r * 8 + ((kk8 + k8c) ^ (r & 7))) * 8];
      }
#pragma unroll
      for (int j = 0; j < 4; j++) {
        int r = wn + j * 16 + fm;
        bf[j] = *(short8*)&Bsl[(r * 8 + ((kk8 + k8c) ^ (r & 7))) * 8];
      }
#pragma unroll
      for (int i = 0; i < 4; i++)
#pragma unroll
        for (int j = 0; j < 4; j++)
          acc[i][j] = __builtin_amdgcn_mfma_f32_16x16x32_bf16(af[i], bf[j], acc[i][j], 0, 0, 0);
    }
  }
#pragma unroll
  for (int i = 0; i < 4; i++) {
    const int mbase = row0 + wm + i * 16 + (lane >> 4) * 4;
#pragma unroll
    for (int j = 0; j < 4; j++) {
      const int n = col0 + wn + j * 16 + fm;
      const float bs = bias ? bias[n] : 0.f;
#pragma unroll
      for (int r = 0; r < 4; r++) {
        long long idx = (long long)(mbase + r) * N + n;
        float v = acc[i][j][r] + bs;
        if (residual) {
          if (flags & FLAG_RESB16) v += bf2f(((const short*)residual)[idx]);
          else                     v += residual[idx];
        }
        if (flags & FLAG_ACC)  v += ((const float*)Cv)[idx];
        if (flags & FLAG_RELU) v = fmaxf(v, 0.f);
        if (flags & FLAG_GELU) v = 0.5f * v * (1.f + erff(v * 0.70710678118654752f));
        if (flags & FLAG_OBF16) ((short*)Cv)[idx] = f2bf(v);
        else                    ((float*)Cv)[idx] = v;
      }
    }
  }
}

// ---------------- q+k GEMM: A single bf16 (DMA), B pre-split h/l (DMA), 2 MFMAs ----
__global__ __launch_bounds__(256) void gemm_qk2(
    const short* __restrict__ Ab, const short* __restrict__ Bth,
    const short* __restrict__ Btl,
    short* __restrict__ Ch, short* __restrict__ Cl,
    const float* __restrict__ bias, int M, int N, int K)
{
  __shared__ __align__(16) char smem[24576];
  short* Asl = (short*)smem;
  short* Bhi = (short*)(smem + 8192);
  short* Blo = (short*)(smem + 16384);
  const int tid = threadIdx.x;
  const int row0 = blockIdx.x * 128;
  const int col0 = blockIdx.y * 128;
  const int lane = tid & 63;
  const int wave = tid >> 6;
  const int wm = (wave >> 1) * 64;
  const int wn = (wave & 1) * 64;
  const int fm = lane & 15;
  const int k8c = lane >> 4;

  f32x4 acc[4][4] = {};
  for (int k0 = 0; k0 < K; k0 += 32) {
    __syncthreads();
#pragma unroll
    for (int u = 0; u < 2; u++) {
      int p = (wave + u * 4) * 64 + lane;
      int r = p >> 2;
      int kc = (p & 3) ^ ((r >> 1) & 3);
      long long ao = (long long)(row0 + r) * 256 + k0 + kc * 8;
      long long go = (long long)(col0 + r) * K + k0 + kc * 8;
      int lo = (wave + u * 4) * 1024;
      load_lds16(Ab + ao, (char*)Asl + lo);
      load_lds16(Bth + go, (char*)Bhi + lo);
      load_lds16(Btl + go, (char*)Blo + lo);
    }
    __syncthreads();
    short8 af[4], bh[4], bl[4];
#pragma unroll
    for (int i = 0; i < 4; i++) {
      int r = wm + i * 16 + fm;
      af[i] = *(short8*)&Asl[(r * 4 + (k8c ^ ((r >> 1) & 3))) * 8];
    }
#pragma unroll
    for (int j = 0; j < 4; j++) {
      int r = wn + j * 16 + fm;
      int p = (r * 4 + (k8c ^ ((r >> 1) & 3))) * 8;
      bh[j] = *(short8*)&Bhi[p];
      bl[j] = *(short8*)&Blo[p];
    }
#pragma unroll
    for (int i = 0; i < 4; i++)
#pragma unroll
      for (int j = 0; j < 4; j++) {
        acc[i][j] = __builtin_amdgcn_mfma_f32_16x16x32_bf16(af[i], bh[j], acc[i][j], 0, 0, 0);
        acc[i][j] = __builtin_amdgcn_mfma_f32_16x16x32_bf16(af[i], bl[j], acc[i][j], 0, 0, 0);
      }
  }
#pragma unroll
  for (int i = 0; i < 4; i++) {
    const int mbase = row0 + wm + i * 16 + (lane >> 4) * 4;
#pragma unroll
    for (int j = 0; j < 4; j++) {
      const int n = col0 + wn + j * 16 + fm;
      const float bs = bias ? bias[n] : 0.f;
#pragma unroll
      for (int r = 0; r < 4; r++) {
        long long idx = (long long)(mbase + r) * N + n;
        float v = acc[i][j][r] + bs;
        short h = f2bf(v);
        short l = f2bf(v - bf2f(h));
        Ch[idx] = h; Cl[idx] = l;
      }
    }
  }
}

// ------------- circular-correlation mean: BK=64 staging (4 rounds), 64 KB LDS ------
__global__ __launch_bounds__(256) void corr_mfma3(
    const short* __restrict__ qkh, const short* __restrict__ qkl, float* __restrict__ mv)
{
  __shared__ __align__(16) char smem[65536];
  short* Ahi = (short*)smem;
  short* Alo = (short*)(smem + 16384);
  short* Bhi = (short*)(smem + 32768);
  short* Blo = (short*)(smem + 49152);
  float* Sf = (float*)smem;

  const int id = blockIdx.x;
  const int b  = (id & 7) + 8 * (id >> 9);
  const int tile = (id >> 3) & 63;
  const int t0 = (tile >> 3) * 128;
  const int s0 = (tile & 7) * 128;
  const int tid = threadIdx.x;
  const int lane = tid & 63;
  const int wave = tid >> 6;
  const int wm = (wave >> 1) * 64;
  const int wn = (wave & 1) * 64;
  const int fm = lane & 15;
  const int k8c = lane >> 4;
  const long long bb = (long long)b * 524288;

  f32x4 acc[4][4] = {};
  for (int k0 = 0; k0 < 256; k0 += 64) {
    __syncthreads();
#pragma unroll
    for (int u = 0; u < 4; u++) {
      int p = (wave * 4 + u) * 64 + lane;
      int r = p >> 3;
      int kc = (p & 7) ^ (r & 7);
      long long qo = bb + (long long)(t0 + r) * 512 + k0 + kc * 8;
      long long ko = bb + (long long)(s0 + r) * 512 + 256 + k0 + kc * 8;
      int lo = (wave * 4 + u) * 1024;
      load_lds16(qkh + qo, (char*)Ahi + lo);
      load_lds16(qkl + qo, (char*)Alo + lo);
      load_lds16(qkh + ko, (char*)Bhi + lo);
      load_lds16(qkl + ko, (char*)Blo + lo);
    }
    __syncthreads();
#pragma unroll
    for (int kk8 = 0; kk8 < 8; kk8 += 4) {
      short8 ah[4], al[4], bh[4], bl[4];
#pragma unroll
      for (int i = 0; i < 4; i++) {
        int r = wm + i * 16 + fm;
        int p = (r * 8 + ((kk8 + k8c) ^ (r & 7))) * 8;
        ah[i] = *(short8*)&Ahi[p];
        al[i] = *(short8*)&Alo[p];
      }
#pragma unroll
      for (int j = 0; j < 4; j++) {
        int r = wn + j * 16 + fm;
        int p = (r * 8 + ((kk8 + k8c) ^ (r & 7))) * 8;
        bh[j] = *(short8*)&Bhi[p];
        bl[j] = *(short8*)&Blo[p];
      }
#pragma unroll
      for (int i = 0; i < 4; i++)
#pragma unroll
        for (int j = 0; j < 4; j++) {
          acc[i][j] = __builtin_amdgcn_mfma_f32_16x16x32_bf16(ah[i], bh[j], acc[i][j], 0, 0, 0);
          acc[i][j] = __builtin_amdgcn_mfma_f32_16x16x32_bf16(ah[i], bl[j], acc[i][j], 0, 0, 0);
          acc[i][j] = __builtin_amdgcn_mfma_f32_16x16x32_bf16(al[i], bh[j], acc[i][j], 0, 0, 0);
        }
    }
  }
  __syncthreads();   // staging reads done; reuse LDS as skewed S
#pragma unroll
  for (int i = 0; i < 4; i++) {
    const int row = wm + i * 16 + (lane >> 4) * 4;
#pragma unroll
    for (int j = 0; j < 4; j++) {
      const int col = wn + j * 16 + fm;
#pragma unroll
      for (int r = 0; r < 4; r++)
        Sf[(row + r) * 128 + ((2 * (row + r) - col) & 127)] =
            acc[i][j][r] * (1.f / 256.f);
    }
  }
  __syncthreads();
  {
    const int dd = tid & 127;
    const int mb = (tid >> 7) * 64;
    float s_ge = 0.f, s_lt = 0.f;
    for (int mm = 0; mm < 64; mm++) {
      int m = mb + mm;
      float v = Sf[m * 128 + ((dd + m) & 127)];
      if (m >= dd) s_ge += v; else s_lt += v;
    }
    atomicAdd(&mv[b * 1024 + ((t0 - s0 + dd) & 1023)], s_ge);
    atomicAdd(&mv[b * 1024 + ((t0 - s0 + dd - 128) & 1023)], s_lt);
  }
}

// ------------- one-shot weight prep -------------
__global__ void prep_weights(
    const float* __restrict__ conv2_w, const float* __restrict__ Wq,
    const float* __restrict__ Wk, const float* __restrict__ Wff1,
    const float* __restrict__ Wff2,
    const float* __restrict__ bq, const float* __restrict__ bk,
    short* __restrict__ CB2Tb, short* __restrict__ QKTH, short* __restrict__ QKTL,
    short* __restrict__ WFF1b, short* __restrict__ WFF2b, float* __restrict__ BQK)
{
  const int total = 196608 + 262144 + 524288 + 524288 + 1024;
  for (int idx = blockIdx.x * 256 + threadIdx.x; idx < total;
       idx += gridDim.x * 256) {
    int t = idx;
    if (t < 196608) {
      int o = t / 768, rem = t % 768, kk = rem >> 8, i = rem & 255;
      CB2Tb[t] = f2bf(conv2_w[(o * 256 + i) * 3 + kk]);
    } else if ((t -= 196608) < 262144) {
      int L = t >> 17, rem = t & 131071, r = rem >> 8, k = rem & 255;
      float val = (r < 256) ? Wq[L * 65536 + k * 256 + r]
                            : Wk[L * 65536 + k * 256 + (r - 256)];
      short h = f2bf(val);
      QKTH[t] = h;
      QKTL[t] = f2bf(val - bf2f(h));
    } else if ((t -= 262144) < 524288) {
      WFF1b[t] = f2bf(Wff1[t]);
    } else if ((t -= 524288) < 524288) {
      WFF2b[t] = f2bf(Wff2[t]);
    } else {
      t -= 524288;
      int L = t >> 9, j = t & 511;
      BQK[t] = (j < 256) ? bq[L * 256 + j] : bk[L * 256 + (j - 256)];
    }
  }
}

// ------------- W_vo finish -------------
__global__ void vo_finish(const float* __restrict__ WVO, const float* __restrict__ Wo,
                          const float* __restrict__ bv, const float* __restrict__ bo,
                          short* __restrict__ WVOTb, float* __restrict__ BVO)
{
  const int total = 131072 + 512;
  for (int idx = blockIdx.x * 256 + threadIdx.x; idx < total;
       idx += gridDim.x * 256) {
    if (idx < 131072) {
      int L = idx >> 16, rem = idx & 65535, n = rem >> 8, k = rem & 255;
      WVOTb[idx] = f2bf(WVO[L * 65536 + k * 256 + n]);
    } else {
      int j = idx - 131072;
      int L = j >> 8, n = j & 255;
      float acc = bo[L * 256 + n];
      for (int k = 0; k < 256; k++)
        acc += bv[L * 256 + k] * Wo[(long long)L * 65536 + k * 256 + n];
      BVO[j] = acc;
    }
  }
}

// ------------- conv1 direct -> bf16 out -------------
__global__ __launch_bounds__(256) void conv1_direct(
    const float* __restrict__ x, const float* __restrict__ w,
    const float* __restrict__ bias, short* __restrict__ out)
{
  __shared__ float xs[66][16];
  const int b = blockIdx.y, lg = blockIdx.x, tid = threadIdx.x;
  const int l0 = lg * 64;
  for (int idx = tid; idx < 1056; idx += 256) {
    int r = idx >> 4, c = idx & 15;
    int l = l0 + r - 1;
    xs[r][c] = (l >= 0 && l < 1024) ? x[((long long)b * 1024 + l) * 16 + c] : 0.f;
  }
  float wr[48];
#pragma unroll
  for (int u = 0; u < 48; u++) wr[u] = w[tid * 48 + u];
  const float bs = bias[tid];
  __syncthreads();
  for (int r = 0; r < 64; r++) {
    float acc = bs;
#pragma unroll
    for (int i = 0; i < 16; i++) {
      acc += xs[r + 0][i] * wr[i * 3 + 0];
      acc += xs[r + 1][i] * wr[i * 3 + 1];
      acc += xs[r + 2][i] * wr[i * 3 + 2];
    }
    out[((long long)b * 1024 + l0 + r) * 256 + tid] = f2bf(fmaxf(acc, 0.f));
  }
}

// ------------- conv2 batch-edge fixup (bf16 src rows) -------------
__global__ void fixup_conv_b(float* __restrict__ h, const short* __restrict__ src,
                             const float* __restrict__ w, const float* __restrict__ bias)
{
  int b = blockIdx.x >> 1;
  int l = (blockIdx.x & 1) ? 1023 : 0;
  int o = threadIdx.x;
  float acc = bias[o];
  for (int kk = 0; kk < 3; kk++) {
    int t = l + kk - 1;
    if (t < 0 || t > 1023) continue;
    const short* srow = src + ((long long)b * 1024 + t) * 256;
    const float* wrow = w + (long long)o * 256 * 3 + kk;
    for (int i = 0; i < 256; i++) acc += bf2f(srow[i]) * wrow[(long long)i * 3];
  }
  h[((long long)b * 1024 + l) * 256 + o] = fmaxf(acc, 0.f);
}

// ------------- LayerNorm fp32 out (head path) -------------
__global__ __launch_bounds__(256) void ln_rows4(
    const float* __restrict__ in, float* __restrict__ out,
    const float* __restrict__ g, const float* __restrict__ b,
    int prerelu, int out_stride, int out_off)
{
  const int row = blockIdx.x * 4 + (threadIdx.x >> 6);
  const int lane = threadIdx.x & 63;
  float4 x = ((const float4*)(in + (long long)row * 256))[lane];
  if (prerelu) {
    x.x = fmaxf(x.x, 0.f); x.y = fmaxf(x.y, 0.f);
    x.z = fmaxf(x.z, 0.f); x.w = fmaxf(x.w, 0.f);
  }
  float s = x.x + x.y + x.z + x.w;
#pragma unroll
  for (int o = 32; o > 0; o >>= 1) s += __shfl_xor(s, o, 64);
  float mean = s * (1.f / 256.f);
  float4 d = make_float4(x.x - mean, x.y - mean, x.z - mean, x.w - mean);
  float s2 = d.x * d.x + d.y * d.y + d.z * d.z + d.w * d.w;
#pragma unroll
  for (int o = 32; o > 0; o >>= 1) s2 += __shfl_xor(s2, o, 64);
  float rsd = rsqrtf(s2 * (1.f / 256.f) + 1e-5f);
  float4 gg = ((const float4*)g)[lane];
  float4 bb = ((const float4*)b)[lane];
  float4 o4 = make_float4(d.x * rsd * gg.x + bb.x, d.y * rsd * gg.y + bb.y,
                          d.z * rsd * gg.z + bb.z, d.w * rsd * gg.w + bb.w);
  ((float4*)(out + (long long)row * out_stride + out_off))[lane] = o4;
}

// ------------- LayerNorm bf16 out (enc producer) -------------
__global__ __launch_bounds__(256) void ln_rows4b(
    const float* __restrict__ in, short* __restrict__ out,
    const float* __restrict__ g, const float* __restrict__ b)
{
  const int row = blockIdx.x * 4 + (threadIdx.x >> 6);
  const int lane = threadIdx.x & 63;
  float4 x = ((const float4*)(in + (long long)row * 256))[lane];
  float s = x.x + x.y + x.z + x.w;
#pragma unroll
  for (int o = 32; o > 0; o >>= 1) s += __shfl_xor(s, o, 64);
  float mean = s * (1.f / 256.f);
  float4 d = make_float4(x.x - mean, x.y - mean, x.z - mean, x.w - mean);
  float s2 = d.x * d.x + d.y * d.y + d.z * d.z + d.w * d.w;
#pragma unroll
  for (int o = 32; o > 0; o >>= 1) s2 += __shfl_xor(s2, o, 64);
  float rsd = rsqrtf(s2 * (1.f / 256.f) + 1e-5f);
  float4 gg = ((const float4*)g)[lane];
  float4 bb = ((const float4*)b)[lane];
  short4v o4;
  o4[0] = f2bf(d.x * rsd * gg.x + bb.x);
  o4[1] = f2bf(d.y * rsd * gg.y + bb.y);
  o4[2] = f2bf(d.z * rsd * gg.z + bb.z);
  o4[3] = f2bf(d.w * rsd * gg.w + bb.w);
  ((short4v*)out)[(long long)row * 64 + lane] = o4;
}

// ------------- series_decomp fp32 -> bf16 enc (+fp32 FIN pool row), XCD-clustered --
__global__ void decomp4be(const float* __restrict__ in, short* __restrict__ out,
                          float* __restrict__ fin, int finoff)
{
  const int id = blockIdx.x;
  const int c = id & 7;
  const int s = id >> 3;
  const int b = c + 8 * (s >> 8);
  const int lg = s & 255;
  const int l = lg * 4 + (threadIdx.x >> 6);
  const int c4 = threadIdx.x & 63;
  const float4* base = (const float4*)(in + (long long)b * 262144);
  float4 acc = make_float4(0.f, 0.f, 0.f, 0.f);
#pragma unroll
  for (int j = -12; j <= 12; j++) {
    int t = l + j;
    t = t < 0 ? 0 : (t > 1023 ? 1023 : t);
    float4 x = base[t * 64 + c4];
    acc.x += x.x; acc.y += x.y; acc.z += x.z; acc.w += x.w;
  }
  float4 x0 = base[l * 64 + c4];
  float4 o = make_float4(x0.x - acc.x * (1.f / 25.f), x0.y - acc.y * (1.f / 25.f),
                         x0.z - acc.z * (1.f / 25.f), x0.w - acc.w * (1.f / 25.f));
  short4v ob;
  ob[0] = f2bf(o.x); ob[1] = f2bf(o.y); ob[2] = f2bf(o.z); ob[3] = f2bf(o.w);
  ((short4v*)out)[((long long)b * 1024 + l) * 64 + c4] = ob;
  if (l == 1023) {
    float* f = fin + (long long)b * 768 + finoff + c4 * 4;
    f[0] = o.x; f[1] = o.y; f[2] = o.z; f[3] = o.w;
  }
}

// ------------- series_decomp bf16->bf16, XCD-clustered -------------
__global__ void decomp4b(const short* __restrict__ in, short* __restrict__ out)
{
  const int id = blockIdx.x;
  const int c = id & 7;
  const int s = id >> 3;
  const int b = c + 8 * (s >> 8);
  const int lg = s & 255;
  const int l = lg * 4 + (threadIdx.x >> 6);
  const int c4 = threadIdx.x & 63;
  const short4v* base = (const short4v*)(in + (long long)b * 262144);
  float4 acc = make_float4(0.f, 0.f, 0.f, 0.f);
#pragma unroll
  for (int j = -12; j <= 12; j++) {
    int t = l + j;
    t = t < 0 ? 0 : (t > 1023 ? 1023 : t);
    short4v x = base[t * 64 + c4];
    acc.x += bf2f(x[0]); acc.y += bf2f(x[1]);
    acc.z += bf2f(x[2]); acc.w += bf2f(x[3]);
  }
  short4v x0 = base[l * 64 + c4];
  short4v o;
  o[0] = f2bf(bf2f(x0[0]) - acc.x * (1.f / 25.f));
  o[1] = f2bf(bf2f(x0[1]) - acc.y * (1.f / 25.f));
  o[2] = f2bf(bf2f(x0[2]) - acc.z * (1.f / 25.f));
  o[3] = f2bf(bf2f(x0[3]) - acc.w * (1.f / 25.f));
  ((short4v*)(out + (long long)b * 262144))[l * 64 + c4] = o;
}

// ------------- top-20 + softmax, one wave per batch -------------
__global__ __launch_bounds__(64) void topk_softmax_wave(
    const float* __restrict__ mv, float* __restrict__ wts, int* __restrict__ dly)
{
  const int b = blockIdx.x, lane = threadIdx.x;
  float v[16];
#pragma unroll
  for (int j = 0; j < 16; j++) v[j] = mv[b * 1024 + lane + 64 * j];
  float selv = 0.f; int seli = 0;
  for (int it = 0; it < 20; it++) {
    float bv = -1e30f; int bi = 0x7fffffff;
#pragma unroll
    for (int j = 0; j < 16; j++) {
      float x = v[j]; int idx = lane + 64 * j;
      if (x > bv || (x == bv && idx < bi)) { bv = x; bi = idx; }
    }
#pragma unroll
    for (int off = 32; off > 0; off >>= 1) {
      float ov = __shfl_xor(bv, off, 64);
      int   oi = __shfl_xor(bi, off, 64);
      if (ov > bv || (ov == bv && oi < bi)) { bv = ov; bi = oi; }
    }
    if (lane == it) { selv = bv; seli = bi; }
    if ((bi & 63) == lane) v[bi >> 6] = -1e30f;
  }
  const float w0 = __shfl(selv, 0, 64);
  float e = (lane < 20) ? __expf(selv - w0) : 0.f;
  float s = e;
#pragma unroll
  for (int off = 32; off > 0; off >>= 1) s += __shfl_xor(s, off, 64);
  if (lane < 20) {
    wts[b * 20 + lane] = e / s;
    dly[b * 20 + lane] = seli;
  }
}

// ------------- delay aggregation bf16 enc -> bf16 out, XCD-clustered ---------------
__global__ void agg4b(const short* __restrict__ enc, const float* __restrict__ wts,
                      const int* __restrict__ dly, short* __restrict__ out)
{
  const int id = blockIdx.x;
  const int c = id & 7;
  const int s = id >> 3;
  const int b = c + 8 * (s >> 8);
  const int lg = s & 255;
  const int l = lg * 4 + (threadIdx.x >> 6);
  const int c4 = threadIdx.x & 63;
  const short4v* vb = (const short4v*)(enc + (long long)b * 262144);
  float4 acc = make_float4(0.f, 0.f, 0.f, 0.f);
  for (int kk = 0; kk < 20; kk++) {
    int d = dly[b * 20 + kk];
    float w = wts[b * 20 + kk];
    short4v x = vb[((l + d) & 1023) * 64 + c4];
    acc.x += w * bf2f(x[0]); acc.y += w * bf2f(x[1]);
    acc.z += w * bf2f(x[2]); acc.w += w * bf2f(x[3]);
  }
  short4v o;
  o[0] = f2bf(acc.x); o[1] = f2bf(acc.y); o[2] = f2bf(acc.z); o[3] = f2bf(acc.w);
  ((short4v*)(out + (long long)b * 262144))[l * 64 + c4] = o;
}

// ------------- small helpers -------------
__global__ void init_bias(float* __restrict__ C, const float* __restrict__ bias)
{
  C[(long long)blockIdx.x * 256 + threadIdx.x] = bias[threadIdx.x];
}

__global__ void rp2_kernel(const float* __restrict__ x, const float* __restrict__ w,
                           const float* __restrict__ bias, float* __restrict__ out)
{
  __shared__ float red[4];
  int b = blockIdx.x, tid = threadIdx.x;
  float p = x[b * 256 + tid] * w[tid];
#pragma unroll
  for (int o = 32; o > 0; o >>= 1) p += __shfl_down(p, o, 64);
  if ((tid & 63) == 0) red[tid >> 6] = p;
  __syncthreads();
  if (tid == 0) out[b] = red[0] + red[1] + red[2] + red[3] + bias[0];
}

// =========================== host launch ===========================
static inline void gemm(hipStream_t s, const float* A, const float* B, float* C,
                        int M, int N, int K, int shift, const float* bias,
                        const float* res, int flags, int splitz = 1)
{
  dim3 g((N + 63) / 64, (M + 63) / 64, splitz);
  gemm_f32<<<g, dim3(256), 0, s>>>(A, B, C, M, N, K, shift, bias, res, flags);
}

extern "C" void kernel_launch(void* const* d_in, const int* in_sizes, int n_in,
                              void* d_out, int out_size, void* d_ws, size_t ws_size,
                              hipStream_t stream)
{
  const float* x_enc  = (const float*)d_in[0];
  const float* conv1_w= (const float*)d_in[1];
  const float* conv1_b= (const float*)d_in[2];
  const float* conv2_w= (const float*)d_in[3];
  const float* conv2_b= (const float*)d_in[4];
  const float* cnn_g  = (const float*)d_in[5];
  const float* cnn_b  = (const float*)d_in[6];
  const float* proj_w = (const float*)d_in[7];
  const float* proj_b = (const float*)d_in[8];
  const float* pln_g  = (const float*)d_in[9];
  const float* pln_b  = (const float*)d_in[10];
  const float* Wq     = (const float*)d_in[11];
  const float* bq     = (const float*)d_in[12];
  const float* Wk     = (const float*)d_in[13];
  const float* bk     = (const float*)d_in[14];
  const float* Wv     = (const float*)d_in[15];
  const float* bv     = (const float*)d_in[16];
  const float* Wo     = (const float*)d_in[17];
  const float* bo     = (const float*)d_in[18];
  const float* Wff1   = (const float*)d_in[19];
  const float* Wff2   = (const float*)d_in[20];
  const float* rp1_w  = (const float*)d_in[21];
  const float* rp1_b  = (const float*)d_in[22];
  const float* rln_g  = (const float*)d_in[23];
  const float* rln_b  = (const float*)d_in[24];
  const float* rp2_w  = (const float*)d_in[25];
  const float* rp2_b  = (const float*)d_in[26];
  (void)in_sizes; (void)n_in;

  const size_t BLD = 64ull * 1024 * 256;
  size_t need;
  {
    size_t o = 3 * BLD
             + 98304 + 131072 + 131072 + 262144 + 262144
             + 65536 + 512 + 1024
             + 65536 + 1280 + 1280 + 16384 + 49152 + 16384 + 16384;
    need = o * sizeof(float);
  }
  if (ws_size < need) {
    hipMemsetAsync(d_out, 0, (size_t)out_size * sizeof(float), stream);
    return;
  }

  float* ws = (float*)d_ws;
  size_t off = 0;
  auto alloc = [&](size_t n) { float* p = ws + off; off += n; return p; };
  float* BUF0 = alloc(BLD);   // conv1(bf16)/QKH/agg(bf16)/xd(bf16); WVO scratch
  float* BUF1 = alloc(BLD);   // conv2(fp32)/QKL/x(bf16)/ffn out(fp32)
  float* BUF2 = alloc(BLD);   // enc(bf16, first half) / ffn hidden (bf16, full)
  short* CB2Tb = (short*)alloc(98304);
  short* QKTH  = (short*)alloc(131072);
  short* QKTL  = (short*)alloc(131072);
  short* WFF1b = (short*)alloc(262144);
  short* WFF2b = (short*)alloc(262144);
  short* WVOTb = (short*)alloc(65536);
  float* BVO  = alloc(512);
  float* BQK  = alloc(1024);
  float* MV   = alloc(65536);
  float* WTS  = alloc(1280);
  int*   DLY  = (int*)alloc(1280);
  float* PE   = alloc(16384);
  float* FIN  = alloc(49152);
  float* O1   = alloc(16384);
  float* O2   = alloc(16384);
  float* WVO  = BUF0;   // scratch, dead before conv1 writes BUF0
  short* ENC  = (short*)BUF2;

  const int M = 65536;
  dim3 blk(256);

  prep_weights<<<1024, blk, 0, stream>>>(conv2_w, Wq, Wk, Wff1, Wff2, bq, bk,
                                         CB2Tb, QKTH, QKTL, WFF1b, WFF2b, BQK);
  for (int i = 0; i < 2; i++)
    gemm(stream, Wv + (size_t)i * 65536, Wo + (size_t)i * 65536,
         WVO + (size_t)i * 65536, 256, 256, 256, 0, nullptr, nullptr, 0);
  vo_finish<<<516, blk, 0, stream>>>(WVO, Wo, bv, bo, WVOTb, BVO);

  // --- CNN frontend ---
  conv1_direct<<<dim3(16, 64), blk, 0, stream>>>(x_enc, conv1_w, conv1_b, (short*)BUF0);
  gemm_bf16_bt<<<dim3(512, 2), blk, 0, stream>>>(
      BUF0, CB2Tb, BUF1, nullptr, conv2_b, M, 256, 768, 256,
      FLAG_ABF16 | FLAG_RELU, 1);
  fixup_conv_b<<<128, blk, 0, stream>>>(BUF1, (const short*)BUF0, conv2_w, conv2_b);
  ln_rows4b<<<16384, blk, 0, stream>>>(BUF1, ENC, cnn_g, cnn_b);

  // --- encoder layers (enc bf16 in BUF2) ---
  for (int i = 0; i < 2; i++) {
    short* QKH = (short*)BUF0;
    short* QKL = (short*)BUF1;
    gemm_qk2<<<dim3(512, 4), blk, 0, stream>>>(
        ENC, QKTH + (size_t)i * 131072, QKTL + (size_t)i * 131072,
        QKH, QKL, BQK + i * 512, M, 512, 256);
    hipMemsetAsync(MV, 0, 64 * 1024 * sizeof(float), stream);
    corr_mfma3<<<dim3(4096), blk, 0, stream>>>(QKH, QKL, MV);
    topk_softmax_wave<<<64, dim3(64), 0, stream>>>(MV, WTS, DLY);
    // fused v+o: x = enc + agg(enc) @ W_vo + b_vo  (x stored bf16)
    agg4b<<<dim3(16384), blk, 0, stream>>>(ENC, WTS, DLY, (short*)BUF0);
    gemm_bf16_bt<<<dim3(512, 2), blk, 0, stream>>>(
        BUF0, WVOTb + (size_t)i * 65536, BUF1, (const float*)ENC, BVO + i * 256,
        M, 256, 256, 256, FLAG_ABF16 | FLAG_OBF16 | FLAG_RESB16, 0);
    decomp4b<<<16384, blk, 0, stream>>>((const short*)BUF1, (short*)BUF0); // xd bf16
    // FFN: 2 chunks of 32768 rows; hidden bf16 in BUF2 (enc dead); out fp32 BUF1
    for (int c = 0; c < 2; c++) {
      const short* xd = (const short*)BUF0 + (size_t)c * 32768 * 256;
      gemm_bf16_bt<<<dim3(256, 8), blk, 0, stream>>>(
          xd, WFF1b + (size_t)i * 262144, BUF2, nullptr, nullptr,
          32768, 1024, 256, 256, FLAG_ABF16 | FLAG_GELU | FLAG_OBF16, 0);
      gemm_bf16_bt<<<dim3(256, 2), blk, 0, stream>>>(
          BUF2, WFF2b + (size_t)i * 262144, BUF1 + (size_t)c * 32768 * 256,
          (const float*)xd, nullptr,
          32768, 256, 1024, 1024, FLAG_ABF16 | FLAG_RESB16, 0);
    }
    decomp4be<<<16384, blk, 0, stream>>>(BUF1, ENC, FIN, i * 256); // enc bf16 + FIN
  }

  // --- head (fp32, exact) ---
  init_bias<<<64, blk, 0, stream>>>(PE, proj_b);
  gemm(stream, x_enc, proj_w, PE, 64, 256, 16384, 0, nullptr, nullptr, 0, 32);
  ln_rows4<<<16, blk, 0, stream>>>(PE, FIN, pln_g, pln_b, 1, 768, 512);
  init_bias<<<64, blk, 0, stream>>>(O1, rp1_b);
  gemm(stream, FIN, rp1_w, O1, 64, 256, 768, 0, nullptr, nullptr, 0, 4);
  ln_rows4<<<16, blk, 0, stream>>>(O1, O2, rln_g, rln_b, 1, 256, 0);
  rp2_kernel<<<64, blk, 0, stream>>>(O2, rp2_w, rp2_b, (float*)d_out);
}

// Round 18
// 1518.577 us; speedup vs baseline: 1.3317x; 1.0082x over previous
//
#include <hip/hip_runtime.h>
#include <math.h>

#define FLAG_ACC     1
#define FLAG_RELU    2
#define FLAG_GELU    4
#define FLAG_ABF16   8
#define FLAG_OBF16  16
#define FLAG_RESB16 32

typedef __attribute__((ext_vector_type(8))) short short8;
typedef __attribute__((ext_vector_type(4))) short short4v;
typedef __attribute__((ext_vector_type(4))) float f32x4;

__device__ __forceinline__ short f2bf(float f) {
  unsigned u = __builtin_bit_cast(unsigned, f);
  unsigned r = u + 0x7fffu + ((u >> 16) & 1u);
  return (short)(r >> 16);
}
__device__ __forceinline__ float bf2f(short s) {
  unsigned u = ((unsigned)(unsigned short)s) << 16;
  return __builtin_bit_cast(float, u);
}
__device__ __forceinline__ void load_lds16(const void* g, void* lds) {
  __builtin_amdgcn_global_load_lds(
      (const __attribute__((address_space(1))) void*)g,
      (__attribute__((address_space(3))) void*)lds, 16, 0, 0);
}

// ---------------- generic fp32 tiled GEMM (head + W_vo prep) ----------------
__global__ __launch_bounds__(256) void gemm_f32(
    const float* __restrict__ A, const float* __restrict__ B, float* __restrict__ C,
    int M, int N, int K, int a_shift,
    const float* __restrict__ bias, const float* __restrict__ residual, int flags)
{
  __shared__ float As[16][65];
  __shared__ float Bs[16][64];
  const int tid = threadIdx.x;
  const int tx = tid & 15, ty = tid >> 4;
  const int row0 = blockIdx.y * 64;
  const int col0 = blockIdx.x * 64;
  int kbeg = 0, kend = K;
  if ((int)gridDim.z > 1) {
    int kchunk = ((K + (int)gridDim.z - 1) / (int)gridDim.z + 15) & ~15;
    kbeg = (int)blockIdx.z * kchunk;
    kend = min(K, kbeg + kchunk);
  }
  float acc[4][4] = {};
  const int a_m = tid >> 2;
  const int a_k = (tid & 3) << 2;
  const int b_n = (tid & 15) << 2;
  const int b_k = tid >> 4;
  for (int k0 = kbeg; k0 < kend; k0 += 16) {
    int srow = row0 + a_m + a_shift;
    float4 av = make_float4(0.f, 0.f, 0.f, 0.f);
    if (srow >= 0 && srow < M)
      av = *reinterpret_cast<const float4*>(A + (long long)srow * K + (k0 + a_k));
    As[a_k + 0][a_m] = av.x; As[a_k + 1][a_m] = av.y;
    As[a_k + 2][a_m] = av.z; As[a_k + 3][a_m] = av.w;
    float4 bv = make_float4(0.f, 0.f, 0.f, 0.f);
    int brow = k0 + b_k;
    if (brow < K)
      bv = *reinterpret_cast<const float4*>(B + (long long)brow * N + (col0 + b_n));
    Bs[b_k][b_n + 0] = bv.x; Bs[b_k][b_n + 1] = bv.y;
    Bs[b_k][b_n + 2] = bv.z; Bs[b_k][b_n + 3] = bv.w;
    __syncthreads();
#pragma unroll
    for (int kk = 0; kk < 16; kk++) {
      float ar[4], br[4];
#pragma unroll
      for (int i = 0; i < 4; i++) ar[i] = As[kk][ty * 4 + i];
#pragma unroll
      for (int j = 0; j < 4; j++) br[j] = Bs[kk][tx * 4 + j];
#pragma unroll
      for (int i = 0; i < 4; i++)
#pragma unroll
        for (int j = 0; j < 4; j++)
          acc[i][j] += ar[i] * br[j];
    }
    __syncthreads();
  }
  if ((int)gridDim.z > 1) {
#pragma unroll
    for (int i = 0; i < 4; i++) {
      int r = row0 + ty * 4 + i; if (r >= M) continue;
#pragma unroll
      for (int j = 0; j < 4; j++) {
        int c = col0 + tx * 4 + j; if (c >= N) continue;
        atomicAdd(&C[(long long)r * N + c], acc[i][j]);
      }
    }
    return;
  }
#pragma unroll
  for (int i = 0; i < 4; i++) {
    int r = row0 + ty * 4 + i; if (r >= M) continue;
#pragma unroll
    for (int j = 0; j < 4; j++) {
      int c = col0 + tx * 4 + j; if (c >= N) continue;
      float v = acc[i][j];
      if (bias)     v += bias[c];
      if (residual) v += residual[(long long)r * N + c];
      if (flags & FLAG_ACC)  v += C[(long long)r * N + c];
      if (flags & FLAG_RELU) v = fmaxf(v, 0.f);
      if (flags & FLAG_GELU) v = 0.5f * v * (1.f + erff(v * 0.70710678118654752f));
      C[(long long)r * N + c] = v;
    }
  }
}

// ---------------- bf16 MFMA GEMM, BK=64: C[M,N] = A[M,K] @ Btb[N,K]^T --------------
__global__ __launch_bounds__(256) void gemm_bf16_bt(
    const void* __restrict__ Av, const short* __restrict__ Btb, void* __restrict__ Cv,
    const float* __restrict__ residual, const float* __restrict__ bias,
    int M, int N, int K, int lda, int flags, int tapped)
{
  __shared__ __align__(16) short Asl[8192];
  __shared__ __align__(16) short Bsl[8192];
  const int tid = threadIdx.x;
  const int row0 = blockIdx.x * 128;
  const int col0 = blockIdx.y * 128;
  const int lane = tid & 63;
  const int wave = tid >> 6;
  const int wm = (wave >> 1) * 64;
  const int wn = (wave & 1) * 64;
  const int fm = lane & 15;
  const int k8c = lane >> 4;
  const int mr = tid >> 1;
  const int mkc = (tid & 1) * 4;
  const int msw = mr & 7;
  const bool a_dma = (flags & FLAG_ABF16) && !tapped;

  f32x4 acc[4][4] = {};
  for (int k0 = 0; k0 < K; k0 += 64) {
    __syncthreads();
#pragma unroll
    for (int u = 0; u < 4; u++) {           // B via DMA
      int p = (wave * 4 + u) * 64 + lane;
      int r = p >> 3;
      int kc = (p & 7) ^ (r & 7);
      load_lds16(Btb + (long long)(col0 + r) * K + k0 + kc * 8,
                 (char*)Bsl + (wave * 4 + u) * 1024);
    }
    if (a_dma) {
      const short* Ab = (const short*)Av;
#pragma unroll
      for (int u = 0; u < 4; u++) {
        int p = (wave * 4 + u) * 64 + lane;
        int r = p >> 3;
        int kc = (p & 7) ^ (r & 7);
        load_lds16(Ab + (long long)(row0 + r) * lda + k0 + kc * 8,
                   (char*)Asl + (wave * 4 + u) * 1024);
      }
    } else {
      int arow = row0 + mr + (tapped ? (k0 >> 8) - 1 : 0);
      int acol = tapped ? (k0 & 255) : k0;
      bool ok = (arow >= 0 && arow < M);
      if (flags & FLAG_ABF16) {
        const short* ga = (const short*)Av + (long long)arow * lda + acol + mkc * 8;
        short8 z;
#pragma unroll
        for (int u = 0; u < 8; u++) z[u] = 0;
#pragma unroll
        for (int j = 0; j < 4; j++) {
          short8 v = ok ? *(const short8*)(ga + j * 8) : z;
          *(short8*)&Asl[(mr * 8 + ((mkc + j) ^ msw)) * 8] = v;
        }
      } else {
        const float* ga = (const float*)Av + (long long)arow * lda + acol + mkc * 8;
#pragma unroll
        for (int j = 0; j < 4; j++) {
          float4 f0 = make_float4(0.f,0.f,0.f,0.f), f1 = f0;
          if (ok) { f0 = *(const float4*)(ga + j * 8); f1 = *(const float4*)(ga + j * 8 + 4); }
          short8 v;
          v[0]=f2bf(f0.x); v[1]=f2bf(f0.y); v[2]=f2bf(f0.z); v[3]=f2bf(f0.w);
          v[4]=f2bf(f1.x); v[5]=f2bf(f1.y); v[6]=f2bf(f1.z); v[7]=f2bf(f1.w);
          *(short8*)&Asl[(mr * 8 + ((mkc + j) ^ msw)) * 8] = v;
        }
      }
    }
    __syncthreads();
#pragma unroll
    for (int kk8 = 0; kk8 < 8; kk8 += 4) {
      short8 af[4], bf[4];
#pragma unroll
      for (int i = 0; i < 4; i++) {
        int r = wm + i * 16 + fm;
        af[i] = *(short8*)&Asl[(r * 8 + ((kk8 + k8c) ^ (r & 7))) * 8];
      }
#pragma unroll
      for (int j = 0; j < 4; j++) {
        int r = wn + j * 16 + fm;
        bf[j] = *(short8*)&Bsl[(r * 8 + ((kk8 + k8c) ^ (r & 7))) * 8];
      }
#pragma unroll
      for (int i = 0; i < 4; i++)
#pragma unroll
        for (int j = 0; j < 4; j++)
          acc[i][j] = __builtin_amdgcn_mfma_f32_16x16x32_bf16(af[i], bf[j], acc[i][j], 0, 0, 0);
    }
  }
#pragma unroll
  for (int i = 0; i < 4; i++) {
    const int mbase = row0 + wm + i * 16 + (lane >> 4) * 4;
#pragma unroll
    for (int j = 0; j < 4; j++) {
      const int n = col0 + wn + j * 16 + fm;
      const float bs = bias ? bias[n] : 0.f;
#pragma unroll
      for (int r = 0; r < 4; r++) {
        long long idx = (long long)(mbase + r) * N + n;
        float v = acc[i][j][r] + bs;
        if (residual) {
          if (flags & FLAG_RESB16) v += bf2f(((const short*)residual)[idx]);
          else                     v += residual[idx];
        }
        if (flags & FLAG_ACC)  v += ((const float*)Cv)[idx];
        if (flags & FLAG_RELU) v = fmaxf(v, 0.f);
        if (flags & FLAG_GELU) v = 0.5f * v * (1.f + erff(v * 0.70710678118654752f));
        if (flags & FLAG_OBF16) ((short*)Cv)[idx] = f2bf(v);
        else                    ((float*)Cv)[idx] = v;
      }
    }
  }
}

// ---------------- q+k GEMM: A single bf16 (DMA), B pre-split h/l (DMA), 2 MFMAs ----
__global__ __launch_bounds__(256) void gemm_qk2(
    const short* __restrict__ Ab, const short* __restrict__ Bth,
    const short* __restrict__ Btl,
    short* __restrict__ Ch, short* __restrict__ Cl,
    const float* __restrict__ bias, int M, int N, int K)
{
  __shared__ __align__(16) char smem[24576];
  short* Asl = (short*)smem;
  short* Bhi = (short*)(smem + 8192);
  short* Blo = (short*)(smem + 16384);
  const int tid = threadIdx.x;
  const int row0 = blockIdx.x * 128;
  const int col0 = blockIdx.y * 128;
  const int lane = tid & 63;
  const int wave = tid >> 6;
  const int wm = (wave >> 1) * 64;
  const int wn = (wave & 1) * 64;
  const int fm = lane & 15;
  const int k8c = lane >> 4;

  f32x4 acc[4][4] = {};
  for (int k0 = 0; k0 < K; k0 += 32) {
    __syncthreads();
#pragma unroll
    for (int u = 0; u < 2; u++) {
      int p = (wave + u * 4) * 64 + lane;
      int r = p >> 2;
      int kc = (p & 3) ^ ((r >> 1) & 3);
      long long ao = (long long)(row0 + r) * 256 + k0 + kc * 8;
      long long go = (long long)(col0 + r) * K + k0 + kc * 8;
      int lo = (wave + u * 4) * 1024;
      load_lds16(Ab + ao, (char*)Asl + lo);
      load_lds16(Bth + go, (char*)Bhi + lo);
      load_lds16(Btl + go, (char*)Blo + lo);
    }
    __syncthreads();
    short8 af[4], bh[4], bl[4];
#pragma unroll
    for (int i = 0; i < 4; i++) {
      int r = wm + i * 16 + fm;
      af[i] = *(short8*)&Asl[(r * 4 + (k8c ^ ((r >> 1) & 3))) * 8];
    }
#pragma unroll
    for (int j = 0; j < 4; j++) {
      int r = wn + j * 16 + fm;
      int p = (r * 4 + (k8c ^ ((r >> 1) & 3))) * 8;
      bh[j] = *(short8*)&Bhi[p];
      bl[j] = *(short8*)&Blo[p];
    }
#pragma unroll
    for (int i = 0; i < 4; i++)
#pragma unroll
      for (int j = 0; j < 4; j++) {
        acc[i][j] = __builtin_amdgcn_mfma_f32_16x16x32_bf16(af[i], bh[j], acc[i][j], 0, 0, 0);
        acc[i][j] = __builtin_amdgcn_mfma_f32_16x16x32_bf16(af[i], bl[j], acc[i][j], 0, 0, 0);
      }
  }
#pragma unroll
  for (int i = 0; i < 4; i++) {
    const int mbase = row0 + wm + i * 16 + (lane >> 4) * 4;
#pragma unroll
    for (int j = 0; j < 4; j++) {
      const int n = col0 + wn + j * 16 + fm;
      const float bs = bias ? bias[n] : 0.f;
#pragma unroll
      for (int r = 0; r < 4; r++) {
        long long idx = (long long)(mbase + r) * N + n;
        float v = acc[i][j][r] + bs;
        short h = f2bf(v);
        short l = f2bf(v - bf2f(h));
        Ch[idx] = h; Cl[idx] = l;
      }
    }
  }
}

// ------------- circular-correlation mean: BK=64 staging, slab output (no atomics) --
// 16 slabs: sl = t0>>7 for delta>=0 windows, 8+(t0>>7) for delta<0 windows; each
// slab's 8 windows tile the 1024-circle exactly once -> every entry written once.
__global__ __launch_bounds__(256) void corr_mfma3(
    const short* __restrict__ qkh, const short* __restrict__ qkl, float* __restrict__ mv16)
{
  __shared__ __align__(16) char smem[65536];
  short* Ahi = (short*)smem;
  short* Alo = (short*)(smem + 16384);
  short* Bhi = (short*)(smem + 32768);
  short* Blo = (short*)(smem + 49152);
  float* Sf = (float*)smem;

  const int id = blockIdx.x;
  const int b  = (id & 7) + 8 * (id >> 9);
  const int tile = (id >> 3) & 63;
  const int t0 = (tile >> 3) * 128;
  const int s0 = (tile & 7) * 128;
  const int tid = threadIdx.x;
  const int lane = tid & 63;
  const int wave = tid >> 6;
  const int wm = (wave >> 1) * 64;
  const int wn = (wave & 1) * 64;
  const int fm = lane & 15;
  const int k8c = lane >> 4;
  const long long bb = (long long)b * 524288;

  f32x4 acc[4][4] = {};
  for (int k0 = 0; k0 < 256; k0 += 64) {
    __syncthreads();
#pragma unroll
    for (int u = 0; u < 4; u++) {
      int p = (wave * 4 + u) * 64 + lane;
      int r = p >> 3;
      int kc = (p & 7) ^ (r & 7);
      long long qo = bb + (long long)(t0 + r) * 512 + k0 + kc * 8;
      long long ko = bb + (long long)(s0 + r) * 512 + 256 + k0 + kc * 8;
      int lo = (wave * 4 + u) * 1024;
      load_lds16(qkh + qo, (char*)Ahi + lo);
      load_lds16(qkl + qo, (char*)Alo + lo);
      load_lds16(qkh + ko, (char*)Bhi + lo);
      load_lds16(qkl + ko, (char*)Blo + lo);
    }
    __syncthreads();
#pragma unroll
    for (int kk8 = 0; kk8 < 8; kk8 += 4) {
      short8 ah[4], al[4], bh[4], bl[4];
#pragma unroll
      for (int i = 0; i < 4; i++) {
        int r = wm + i * 16 + fm;
        int p = (r * 8 + ((kk8 + k8c) ^ (r & 7))) * 8;
        ah[i] = *(short8*)&Ahi[p];
        al[i] = *(short8*)&Alo[p];
      }
#pragma unroll
      for (int j = 0; j < 4; j++) {
        int r = wn + j * 16 + fm;
        int p = (r * 8 + ((kk8 + k8c) ^ (r & 7))) * 8;
        bh[j] = *(short8*)&Bhi[p];
        bl[j] = *(short8*)&Blo[p];
      }
#pragma unroll
      for (int i = 0; i < 4; i++)
#pragma unroll
        for (int j = 0; j < 4; j++) {
          acc[i][j] = __builtin_amdgcn_mfma_f32_16x16x32_bf16(ah[i], bh[j], acc[i][j], 0, 0, 0);
          acc[i][j] = __builtin_amdgcn_mfma_f32_16x16x32_bf16(ah[i], bl[j], acc[i][j], 0, 0, 0);
          acc[i][j] = __builtin_amdgcn_mfma_f32_16x16x32_bf16(al[i], bh[j], acc[i][j], 0, 0, 0);
        }
    }
  }
  __syncthreads();   // staging reads done; reuse LDS as skewed S
#pragma unroll
  for (int i = 0; i < 4; i++) {
    const int row = wm + i * 16 + (lane >> 4) * 4;
#pragma unroll
    for (int j = 0; j < 4; j++) {
      const int col = wn + j * 16 + fm;
#pragma unroll
      for (int r = 0; r < 4; r++)
        Sf[(row + r) * 128 + ((2 * (row + r) - col) & 127)] =
            acc[i][j][r] * (1.f / 256.f);
    }
  }
  __syncthreads();
  {
    const int dd = tid & 127;
    const int mb = (tid >> 7) * 64;
    float s_ge = 0.f, s_lt = 0.f;
    for (int mm = 0; mm < 64; mm++) {
      int m = mb + mm;
      float v = Sf[m * 128 + ((dd + m) & 127)];
      if (m >= dd) s_ge += v; else s_lt += v;
    }
    // cross-half combine: lanes tid and tid^128 hold partial ge/lt for same dd
    __syncthreads();
    Sf[tid] = s_ge;
    Sf[256 + tid] = s_lt;
    __syncthreads();
    if (tid < 128) {
      float ge = Sf[tid] + Sf[tid + 128];
      float lt = Sf[256 + tid] + Sf[256 + tid + 128];
      const int sl = t0 >> 7;
      mv16[((long long)sl * 64 + b) * 1024 + ((t0 - s0 + tid) & 1023)] = ge;
      mv16[((long long)(8 + sl) * 64 + b) * 1024 + ((t0 - s0 + tid - 128) & 1023)] = lt;
    }
  }
}

// ------------- one-shot weight prep -------------
__global__ void prep_weights(
    const float* __restrict__ conv2_w, const float* __restrict__ Wq,
    const float* __restrict__ Wk, const float* __restrict__ Wff1,
    const float* __restrict__ Wff2,
    const float* __restrict__ bq, const float* __restrict__ bk,
    short* __restrict__ CB2Tb, short* __restrict__ QKTH, short* __restrict__ QKTL,
    short* __restrict__ WFF1b, short* __restrict__ WFF2b, float* __restrict__ BQK)
{
  const int total = 196608 + 262144 + 524288 + 524288 + 1024;
  for (int idx = blockIdx.x * 256 + threadIdx.x; idx < total;
       idx += gridDim.x * 256) {
    int t = idx;
    if (t < 196608) {
      int o = t / 768, rem = t % 768, kk = rem >> 8, i = rem & 255;
      CB2Tb[t] = f2bf(conv2_w[(o * 256 + i) * 3 + kk]);
    } else if ((t -= 196608) < 262144) {
      int L = t >> 17, rem = t & 131071, r = rem >> 8, k = rem & 255;
      float val = (r < 256) ? Wq[L * 65536 + k * 256 + r]
                            : Wk[L * 65536 + k * 256 + (r - 256)];
      short h = f2bf(val);
      QKTH[t] = h;
      QKTL[t] = f2bf(val - bf2f(h));
    } else if ((t -= 262144) < 524288) {
      WFF1b[t] = f2bf(Wff1[t]);
    } else if ((t -= 524288) < 524288) {
      WFF2b[t] = f2bf(Wff2[t]);
    } else {
      t -= 524288;
      int L = t >> 9, j = t & 511;
      BQK[t] = (j < 256) ? bq[L * 256 + j] : bk[L * 256 + (j - 256)];
    }
  }
}

// ------------- W_vo finish -------------
__global__ void vo_finish(const float* __restrict__ WVO, const float* __restrict__ Wo,
                          const float* __restrict__ bv, const float* __restrict__ bo,
                          short* __restrict__ WVOTb, float* __restrict__ BVO)
{
  const int total = 131072 + 512;
  for (int idx = blockIdx.x * 256 + threadIdx.x; idx < total;
       idx += gridDim.x * 256) {
    if (idx < 131072) {
      int L = idx >> 16, rem = idx & 65535, n = rem >> 8, k = rem & 255;
      WVOTb[idx] = f2bf(WVO[L * 65536 + k * 256 + n]);
    } else {
      int j = idx - 131072;
      int L = j >> 8, n = j & 255;
      float acc = bo[L * 256 + n];
      for (int k = 0; k < 256; k++)
        acc += bv[L * 256 + k] * Wo[(long long)L * 65536 + k * 256 + n];
      BVO[j] = acc;
    }
  }
}

// ------------- conv1 direct -> bf16 out -------------
__global__ __launch_bounds__(256) void conv1_direct(
    const float* __restrict__ x, const float* __restrict__ w,
    const float* __restrict__ bias, short* __restrict__ out)
{
  __shared__ float xs[66][16];
  const int b = blockIdx.y, lg = blockIdx.x, tid = threadIdx.x;
  const int l0 = lg * 64;
  for (int idx = tid; idx < 1056; idx += 256) {
    int r = idx >> 4, c = idx & 15;
    int l = l0 + r - 1;
    xs[r][c] = (l >= 0 && l < 1024) ? x[((long long)b * 1024 + l) * 16 + c] : 0.f;
  }
  float wr[48];
#pragma unroll
  for (int u = 0; u < 48; u++) wr[u] = w[tid * 48 + u];
  const float bs = bias[tid];
  __syncthreads();
  for (int r = 0; r < 64; r++) {
    float acc = bs;
#pragma unroll
    for (int i = 0; i < 16; i++) {
      acc += xs[r + 0][i] * wr[i * 3 + 0];
      acc += xs[r + 1][i] * wr[i * 3 + 1];
      acc += xs[r + 2][i] * wr[i * 3 + 2];
    }
    out[((long long)b * 1024 + l0 + r) * 256 + tid] = f2bf(fmaxf(acc, 0.f));
  }
}

// ------------- conv2 batch-edge fixup (bf16 src rows, bf16 out) -------------
__global__ void fixup_conv_b(short* __restrict__ h, const short* __restrict__ src,
                             const float* __restrict__ w, const float* __restrict__ bias)
{
  int b = blockIdx.x >> 1;
  int l = (blockIdx.x & 1) ? 1023 : 0;
  int o = threadIdx.x;
  float acc = bias[o];
  for (int kk = 0; kk < 3; kk++) {
    int t = l + kk - 1;
    if (t < 0 || t > 1023) continue;
    const short* srow = src + ((long long)b * 1024 + t) * 256;
    const float* wrow = w + (long long)o * 256 * 3 + kk;
    for (int i = 0; i < 256; i++) acc += bf2f(srow[i]) * wrow[(long long)i * 3];
  }
  h[((long long)b * 1024 + l) * 256 + o] = f2bf(fmaxf(acc, 0.f));
}

// ------------- LayerNorm fp32 out (head path) -------------
__global__ __launch_bounds__(256) void ln_rows4(
    const float* __restrict__ in, float* __restrict__ out,
    const float* __restrict__ g, const float* __restrict__ b,
    int prerelu, int out_stride, int out_off)
{
  const int row = blockIdx.x * 4 + (threadIdx.x >> 6);
  const int lane = threadIdx.x & 63;
  float4 x = ((const float4*)(in + (long long)row * 256))[lane];
  if (prerelu) {
    x.x = fmaxf(x.x, 0.f); x.y = fmaxf(x.y, 0.f);
    x.z = fmaxf(x.z, 0.f); x.w = fmaxf(x.w, 0.f);
  }
  float s = x.x + x.y + x.z + x.w;
#pragma unroll
  for (int o = 32; o > 0; o >>= 1) s += __shfl_xor(s, o, 64);
  float mean = s * (1.f / 256.f);
  float4 d = make_float4(x.x - mean, x.y - mean, x.z - mean, x.w - mean);
  float s2 = d.x * d.x + d.y * d.y + d.z * d.z + d.w * d.w;
#pragma unroll
  for (int o = 32; o > 0; o >>= 1) s2 += __shfl_xor(s2, o, 64);
  float rsd = rsqrtf(s2 * (1.f / 256.f) + 1e-5f);
  float4 gg = ((const float4*)g)[lane];
  float4 bb = ((const float4*)b)[lane];
  float4 o4 = make_float4(d.x * rsd * gg.x + bb.x, d.y * rsd * gg.y + bb.y,
                          d.z * rsd * gg.z + bb.z, d.w * rsd * gg.w + bb.w);
  ((float4*)(out + (long long)row * out_stride + out_off))[lane] = o4;
}

// ------------- LayerNorm bf16 in -> bf16 out (enc producer) -------------
__global__ __launch_bounds__(256) void ln_rows4bb(
    const short* __restrict__ in, short* __restrict__ out,
    const float* __restrict__ g, const float* __restrict__ b)
{
  const int row = blockIdx.x * 4 + (threadIdx.x >> 6);
  const int lane = threadIdx.x & 63;
  short4v xb = ((const short4v*)in)[(long long)row * 64 + lane];
  float4 x = make_float4(bf2f(xb[0]), bf2f(xb[1]), bf2f(xb[2]), bf2f(xb[3]));
  float s = x.x + x.y + x.z + x.w;
#pragma unroll
  for (int o = 32; o > 0; o >>= 1) s += __shfl_xor(s, o, 64);
  float mean = s * (1.f / 256.f);
  float4 d = make_float4(x.x - mean, x.y - mean, x.z - mean, x.w - mean);
  float s2 = d.x * d.x + d.y * d.y + d.z * d.z + d.w * d.w;
#pragma unroll
  for (int o = 32; o > 0; o >>= 1) s2 += __shfl_xor(s2, o, 64);
  float rsd = rsqrtf(s2 * (1.f / 256.f) + 1e-5f);
  float4 gg = ((const float4*)g)[lane];
  float4 bb = ((const float4*)b)[lane];
  short4v o4;
  o4[0] = f2bf(d.x * rsd * gg.x + bb.x);
  o4[1] = f2bf(d.y * rsd * gg.y + bb.y);
  o4[2] = f2bf(d.z * rsd * gg.z + bb.z);
  o4[3] = f2bf(d.w * rsd * gg.w + bb.w);
  ((short4v*)out)[(long long)row * 64 + lane] = o4;
}

// ------------- series_decomp bf16 -> bf16 enc (+fp32 FIN pool row), XCD-clustered --
__global__ void decomp4bf(const short* __restrict__ in, short* __restrict__ out,
                          float* __restrict__ fin, int finoff)
{
  const int id = blockIdx.x;
  const int c = id & 7;
  const int s = id >> 3;
  const int b = c + 8 * (s >> 8);
  const int lg = s & 255;
  const int l = lg * 4 + (threadIdx.x >> 6);
  const int c4 = threadIdx.x & 63;
  const short4v* base = (const short4v*)(in + (long long)b * 262144);
  float4 acc = make_float4(0.f, 0.f, 0.f, 0.f);
#pragma unroll
  for (int j = -12; j <= 12; j++) {
    int t = l + j;
    t = t < 0 ? 0 : (t > 1023 ? 1023 : t);
    short4v x = base[t * 64 + c4];
    acc.x += bf2f(x[0]); acc.y += bf2f(x[1]);
    acc.z += bf2f(x[2]); acc.w += bf2f(x[3]);
  }
  short4v x0 = base[l * 64 + c4];
  float4 o = make_float4(bf2f(x0[0]) - acc.x * (1.f / 25.f),
                         bf2f(x0[1]) - acc.y * (1.f / 25.f),
                         bf2f(x0[2]) - acc.z * (1.f / 25.f),
                         bf2f(x0[3]) - acc.w * (1.f / 25.f));
  short4v ob;
  ob[0] = f2bf(o.x); ob[1] = f2bf(o.y); ob[2] = f2bf(o.z); ob[3] = f2bf(o.w);
  ((short4v*)out)[((long long)b * 1024 + l) * 64 + c4] = ob;
  if (l == 1023) {
    float* f = fin + (long long)b * 768 + finoff + c4 * 4;
    f[0] = o.x; f[1] = o.y; f[2] = o.z; f[3] = o.w;
  }
}

// ------------- series_decomp bf16->bf16, XCD-clustered -------------
__global__ void decomp4b(const short* __restrict__ in, short* __restrict__ out)
{
  const int id = blockIdx.x;
  const int c = id & 7;
  const int s = id >> 3;
  const int b = c + 8 * (s >> 8);
  const int lg = s & 255;
  const int l = lg * 4 + (threadIdx.x >> 6);
  const int c4 = threadIdx.x & 63;
  const short4v* base = (const short4v*)(in + (long long)b * 262144);
  float4 acc = make_float4(0.f, 0.f, 0.f, 0.f);
#pragma unroll
  for (int j = -12; j <= 12; j++) {
    int t = l + j;
    t = t < 0 ? 0 : (t > 1023 ? 1023 : t);
    short4v x = base[t * 64 + c4];
    acc.x += bf2f(x[0]); acc.y += bf2f(x[1]);
    acc.z += bf2f(x[2]); acc.w += bf2f(x[3]);
  }
  short4v x0 = base[l * 64 + c4];
  short4v o;
  o[0] = f2bf(bf2f(x0[0]) - acc.x * (1.f / 25.f));
  o[1] = f2bf(bf2f(x0[1]) - acc.y * (1.f / 25.f));
  o[2] = f2bf(bf2f(x0[2]) - acc.z * (1.f / 25.f));
  o[3] = f2bf(bf2f(x0[3]) - acc.w * (1.f / 25.f));
  ((short4v*)(out + (long long)b * 262144))[l * 64 + c4] = o;
}

// ------------- top-20 + softmax, one wave per batch (sums 16 slabs) -------------
__global__ __launch_bounds__(64) void topk_softmax_wave(
    const float* __restrict__ mv16, float* __restrict__ wts, int* __restrict__ dly)
{
  const int b = blockIdx.x, lane = threadIdx.x;
  float v[16];
#pragma unroll
  for (int j = 0; j < 16; j++) {
    float s = 0.f;
#pragma unroll
    for (int sl = 0; sl < 16; sl++)
      s += mv16[((long long)sl * 64 + b) * 1024 + lane + 64 * j];
    v[j] = s;
  }
  float selv = 0.f; int seli = 0;
  for (int it = 0; it < 20; it++) {
    float bv = -1e30f; int bi = 0x7fffffff;
#pragma unroll
    for (int j = 0; j < 16; j++) {
      float x = v[j]; int idx = lane + 64 * j;
      if (x > bv || (x == bv && idx < bi)) { bv = x; bi = idx; }
    }
#pragma unroll
    for (int off = 32; off > 0; off >>= 1) {
      float ov = __shfl_xor(bv, off, 64);
      int   oi = __shfl_xor(bi, off, 64);
      if (ov > bv || (ov == bv && oi < bi)) { bv = ov; bi = oi; }
    }
    if (lane == it) { selv = bv; seli = bi; }
    if ((bi & 63) == lane) v[bi >> 6] = -1e30f;
  }
  const float w0 = __shfl(selv, 0, 64);
  float e = (lane < 20) ? __expf(selv - w0) : 0.f;
  float s = e;
#pragma unroll
  for (int off = 32; off > 0; off >>= 1) s += __shfl_xor(s, off, 64);
  if (lane < 20) {
    wts[b * 20 + lane] = e / s;
    dly[b * 20 + lane] = seli;
  }
}

// ------------- delay aggregation bf16 enc -> bf16 out, XCD-clustered ---------------
__global__ void agg4b(const short* __restrict__ enc, const float* __restrict__ wts,
                      const int* __restrict__ dly, short* __restrict__ out)
{
  const int id = blockIdx.x;
  const int c = id & 7;
  const int s = id >> 3;
  const int b = c + 8 * (s >> 8);
  const int lg = s & 255;
  const int l = lg * 4 + (threadIdx.x >> 6);
  const int c4 = threadIdx.x & 63;
  const short4v* vb = (const short4v*)(enc + (long long)b * 262144);
  float4 acc = make_float4(0.f, 0.f, 0.f, 0.f);
  for (int kk = 0; kk < 20; kk++) {
    int d = dly[b * 20 + kk];
    float w = wts[b * 20 + kk];
    short4v x = vb[((l + d) & 1023) * 64 + c4];
    acc.x += w * bf2f(x[0]); acc.y += w * bf2f(x[1]);
    acc.z += w * bf2f(x[2]); acc.w += w * bf2f(x[3]);
  }
  short4v o;
  o[0] = f2bf(acc.x); o[1] = f2bf(acc.y); o[2] = f2bf(acc.z); o[3] = f2bf(acc.w);
  ((short4v*)(out + (long long)b * 262144))[l * 64 + c4] = o;
}

// ------------- small helpers -------------
__global__ void init_bias(float* __restrict__ C, const float* __restrict__ bias)
{
  C[(long long)blockIdx.x * 256 + threadIdx.x] = bias[threadIdx.x];
}

__global__ void rp2_kernel(const float* __restrict__ x, const float* __restrict__ w,
                           const float* __restrict__ bias, float* __restrict__ out)
{
  __shared__ float red[4];
  int b = blockIdx.x, tid = threadIdx.x;
  float p = x[b * 256 + tid] * w[tid];
#pragma unroll
  for (int o = 32; o > 0; o >>= 1) p += __shfl_down(p, o, 64);
  if ((tid & 63) == 0) red[tid >> 6] = p;
  __syncthreads();
  if (tid == 0) out[b] = red[0] + red[1] + red[2] + red[3] + bias[0];
}

// =========================== host launch ===========================
static inline void gemm(hipStream_t s, const float* A, const float* B, float* C,
                        int M, int N, int K, int shift, const float* bias,
                        const float* res, int flags, int splitz = 1)
{
  dim3 g((N + 63) / 64, (M + 63) / 64, splitz);
  gemm_f32<<<g, dim3(256), 0, s>>>(A, B, C, M, N, K, shift, bias, res, flags);
}

extern "C" void kernel_launch(void* const* d_in, const int* in_sizes, int n_in,
                              void* d_out, int out_size, void* d_ws, size_t ws_size,
                              hipStream_t stream)
{
  const float* x_enc  = (const float*)d_in[0];
  const float* conv1_w= (const float*)d_in[1];
  const float* conv1_b= (const float*)d_in[2];
  const float* conv2_w= (const float*)d_in[3];
  const float* conv2_b= (const float*)d_in[4];
  const float* cnn_g  = (const float*)d_in[5];
  const float* cnn_b  = (const float*)d_in[6];
  const float* proj_w = (const float*)d_in[7];
  const float* proj_b = (const float*)d_in[8];
  const float* pln_g  = (const float*)d_in[9];
  const float* pln_b  = (const float*)d_in[10];
  const float* Wq     = (const float*)d_in[11];
  const float* bq     = (const float*)d_in[12];
  const float* Wk     = (const float*)d_in[13];
  const float* bk     = (const float*)d_in[14];
  const float* Wv     = (const float*)d_in[15];
  const float* bv     = (const float*)d_in[16];
  const float* Wo     = (const float*)d_in[17];
  const float* bo     = (const float*)d_in[18];
  const float* Wff1   = (const float*)d_in[19];
  const float* Wff2   = (const float*)d_in[20];
  const float* rp1_w  = (const float*)d_in[21];
  const float* rp1_b  = (const float*)d_in[22];
  const float* rln_g  = (const float*)d_in[23];
  const float* rln_b  = (const float*)d_in[24];
  const float* rp2_w  = (const float*)d_in[25];
  const float* rp2_b  = (const float*)d_in[26];
  (void)in_sizes; (void)n_in;

  const size_t BLD = 64ull * 1024 * 256;
  size_t need;
  {
    size_t o = 3 * BLD
             + 98304 + 131072 + 131072 + 262144 + 262144
             + 65536 + 512 + 1024
             + 1048576 + 1280 + 1280 + 16384 + 49152 + 16384 + 16384;
    need = o * sizeof(float);
  }
  if (ws_size < need) {
    hipMemsetAsync(d_out, 0, (size_t)out_size * sizeof(float), stream);
    return;
  }

  float* ws = (float*)d_ws;
  size_t off = 0;
  auto alloc = [&](size_t n) { float* p = ws + off; off += n; return p; };
  float* BUF0 = alloc(BLD);   // conv1(bf16)/QKH/agg(bf16)/xd(bf16); WVO scratch
  float* BUF1 = alloc(BLD);   // conv2(bf16)/QKL/x(bf16)/ffn out(bf16)
  float* BUF2 = alloc(BLD);   // enc(bf16, first half) / ffn hidden (bf16, full)
  short* CB2Tb = (short*)alloc(98304);
  short* QKTH  = (short*)alloc(131072);
  short* QKTL  = (short*)alloc(131072);
  short* WFF1b = (short*)alloc(262144);
  short* WFF2b = (short*)alloc(262144);
  short* WVOTb = (short*)alloc(65536);
  float* BVO  = alloc(512);
  float* BQK  = alloc(1024);
  float* MV16 = alloc(1048576);   // 16 slabs x 64 b x 1024 tau
  float* WTS  = alloc(1280);
  int*   DLY  = (int*)alloc(1280);
  float* PE   = alloc(16384);
  float* FIN  = alloc(49152);
  float* O1   = alloc(16384);
  float* O2   = alloc(16384);
  float* WVO  = BUF0;   // scratch, dead before conv1 writes BUF0
  short* ENC  = (short*)BUF2;

  const int M = 65536;
  dim3 blk(256);

  prep_weights<<<1024, blk, 0, stream>>>(conv2_w, Wq, Wk, Wff1, Wff2, bq, bk,
                                         CB2Tb, QKTH, QKTL, WFF1b, WFF2b, BQK);
  for (int i = 0; i < 2; i++)
    gemm(stream, Wv + (size_t)i * 65536, Wo + (size_t)i * 65536,
         WVO + (size_t)i * 65536, 256, 256, 256, 0, nullptr, nullptr, 0);
  vo_finish<<<516, blk, 0, stream>>>(WVO, Wo, bv, bo, WVOTb, BVO);

  // --- CNN frontend (conv2 out bf16) ---
  conv1_direct<<<dim3(16, 64), blk, 0, stream>>>(x_enc, conv1_w, conv1_b, (short*)BUF0);
  gemm_bf16_bt<<<dim3(512, 2), blk, 0, stream>>>(
      BUF0, CB2Tb, BUF1, nullptr, conv2_b, M, 256, 768, 256,
      FLAG_ABF16 | FLAG_RELU | FLAG_OBF16, 1);
  fixup_conv_b<<<128, blk, 0, stream>>>((short*)BUF1, (const short*)BUF0,
                                        conv2_w, conv2_b);
  ln_rows4bb<<<16384, blk, 0, stream>>>((const short*)BUF1, ENC, cnn_g, cnn_b);

  // --- encoder layers (enc bf16 in BUF2) ---
  for (int i = 0; i < 2; i++) {
    short* QKH = (short*)BUF0;
    short* QKL = (short*)BUF1;
    gemm_qk2<<<dim3(512, 4), blk, 0, stream>>>(
        ENC, QKTH + (size_t)i * 131072, QKTL + (size_t)i * 131072,
        QKH, QKL, BQK + i * 512, M, 512, 256);
    corr_mfma3<<<dim3(4096), blk, 0, stream>>>(QKH, QKL, MV16);
    topk_softmax_wave<<<64, dim3(64), 0, stream>>>(MV16, WTS, DLY);
    // fused v+o: x = enc + agg(enc) @ W_vo + b_vo  (x stored bf16)
    agg4b<<<dim3(16384), blk, 0, stream>>>(ENC, WTS, DLY, (short*)BUF0);
    gemm_bf16_bt<<<dim3(512, 2), blk, 0, stream>>>(
        BUF0, WVOTb + (size_t)i * 65536, BUF1, (const float*)ENC, BVO + i * 256,
        M, 256, 256, 256, FLAG_ABF16 | FLAG_OBF16 | FLAG_RESB16, 0);
    decomp4b<<<16384, blk, 0, stream>>>((const short*)BUF1, (short*)BUF0); // xd bf16
    // FFN: 2 chunks of 32768 rows; hidden bf16 in BUF2 (enc dead); out bf16 BUF1
    for (int c = 0; c < 2; c++) {
      const short* xd = (const short*)BUF0 + (size_t)c * 32768 * 256;
      gemm_bf16_bt<<<dim3(256, 8), blk, 0, stream>>>(
          xd, WFF1b + (size_t)i * 262144, BUF2, nullptr, nullptr,
          32768, 1024, 256, 256, FLAG_ABF16 | FLAG_GELU | FLAG_OBF16, 0);
      gemm_bf16_bt<<<dim3(256, 2), blk, 0, stream>>>(
          BUF2, WFF2b + (size_t)i * 262144,
          (short*)BUF1 + (size_t)c * 32768 * 256,
          (const float*)xd, nullptr,
          32768, 256, 1024, 1024, FLAG_ABF16 | FLAG_RESB16 | FLAG_OBF16, 0);
    }
    decomp4bf<<<16384, blk, 0, stream>>>((const short*)BUF1, ENC, FIN, i * 256);
  }

  // --- head (fp32, exact) ---
  init_bias<<<64, blk, 0, stream>>>(PE, proj_b);
  gemm(stream, x_enc, proj_w, PE, 64, 256, 16384, 0, nullptr, nullptr, 0, 32);
  ln_rows4<<<16, blk, 0, stream>>>(PE, FIN, pln_g, pln_b, 1, 768, 512);
  init_bias<<<64, blk, 0, stream>>>(O1, rp1_b);
  gemm(stream, FIN, rp1_w, O1, 64, 256, 768, 0, nullptr, nullptr, 0, 4);
  ln_rows4<<<16, blk, 0, stream>>>(O1, O2, rln_g, rln_b, 1, 256, 0);
  rp2_kernel<<<64, blk, 0, stream>>>(O2, rp2_w, rp2_b, (float*)d_out);
}